// Round 4
// baseline (39999.756 us; speedup 1.0000x reference)
//
#include <hip/hip_runtime.h>
#include <hip/hip_bf16.h>

#define B_   1024
#define S_   79
#define E_   512
#define H_   8
#define D_   64
#define SUM_ 128
#define LDX  (S_*E_)      // 40448

__device__ __forceinline__ float silu_f(float s) {
    return s / (1.f + __expf(-s));
}

// ---------------------------------------------------------------------------
// fused_bh_k: one block per (b,h), 256 threads.  Never touches d_ws.
//   phase 1: Q,K,V head-slices (79x64 each) from x @ w into LDS
//   phase 2: full smolgen chain for batch b, head h -> hs_h[128] in LDS
//   phase 3: scores[t][T] = (QK^T)/8 + hs_h @ sproj  (into LDS)
//   phase 4: per-row softmax (wave per row)
//   phase 5: PV -> d_out[b, t, h*64+d]   (pre-output-projection)
// ---------------------------------------------------------------------------
__global__ __launch_bounds__(256) void fused_bh_k(
    const float* __restrict__ xq,  const float* __restrict__ xkv,
    const float* __restrict__ wq,  const float* __restrict__ wk,
    const float* __restrict__ wv,
    const float* __restrict__ sp_w, const float* __restrict__ sp_b,
    const float* __restrict__ c0w, const float* __restrict__ c0b,
    const float* __restrict__ c1w, const float* __restrict__ c1b,
    const float* __restrict__ g1w, const float* __restrict__ g1b,
    const float* __restrict__ g2w, const float* __restrict__ g2b,
    const float* __restrict__ sumw, const float* __restrict__ sumb,
    const float* __restrict__ headw, const float* __restrict__ headb,
    const float* __restrict__ sproj,
    float* __restrict__ outp)
{
    const int bh = blockIdx.x;
    const int b = bh >> 3, h = bh & 7;
    const int tid = threadIdx.x;

    __shared__ __attribute__((aligned(16))) float qS[79][64];
    __shared__ __attribute__((aligned(16))) float kS[79][65];
    __shared__ __attribute__((aligned(16))) float vS[79][64];
    __shared__ __attribute__((aligned(16))) float scLg[79][80];
    __shared__ __attribute__((aligned(16))) float h0[64][16];
    __shared__ __attribute__((aligned(16))) float out2[64][32];
    __shared__ float red[8][32];
    __shared__ float part[16][16];
    __shared__ float gpart[4][64];
    __shared__ float comb[80];
    __shared__ float psS[128];
    __shared__ float hsS[128];

    // ---------------- phase 1: Q, K, V head-slices -----------------
    {
        const float* xqb = xq  + (size_t)b * LDX;
        const float* xkb = xkv + (size_t)b * LDX;
        for (int idx = tid; idx < 79 * 64; idx += 256) {
            const int T = idx >> 6, d = idx & 63;
            const float* xr = xqb + (size_t)T * 512;
            const float* kr = xkb + (size_t)T * 512;
            float sq = 0.f, sk = 0.f, sv = 0.f;
            const int wc0 = h * 64 + d;
#pragma unroll 4
            for (int c = 0; c < 512; ++c) {
                const float xv = xr[c], kv = kr[c];
                const size_t wi = (size_t)c * 512 + wc0;
                sq = fmaf(xv, wq[wi], sq);
                sk = fmaf(kv, wk[wi], sk);
                sv = fmaf(kv, wv[wi], sv);
            }
            qS[T][d] = sq; kS[T][d] = sk; vS[T][d] = sv;
        }
    }

    // ---------------- phase 2: smolgen chain for (b,h) -------------
    const float* xb = xq + (size_t)b * LDX;

    // 2a special partials: out o = tid&15, chunk p = tid>>4 (32 c each)
    {
        const int o = tid & 15, p = tid >> 4;
        float s = 0.f;
        for (int c = p * 32; c < p * 32 + 32; ++c)
            s = fmaf(xb[c], sp_w[(size_t)c * 16 + o], s);
        part[p][o] = s;
    }

    // 2b conv0: board px -> h0[64][16]
    {
        const int px = tid >> 2, j = tid & 3;    // co = j*4..j*4+3
        const int py = px >> 3, pxx = px & 7;
        float acc[4];
#pragma unroll
        for (int i = 0; i < 4; ++i) acc[i] = c0b[j * 4 + i];
        for (int ky = 0; ky < 3; ++ky) {
            const int yy = py + ky - 1;
            if (yy < 0 || yy > 7) continue;
            for (int kx = 0; kx < 3; ++kx) {
                const int xx2 = pxx + kx - 1;
                if (xx2 < 0 || xx2 > 7) continue;
                const float* xr = xb + (size_t)(1 + yy * 8 + xx2) * 512;
                const float* wr = c0w + (size_t)(ky * 3 + kx) * 512 * 16 + j * 4;
                for (int c = 0; c < 512; ++c) {
                    const float xv = xr[c];
                    float4 wv4 = *(const float4*)(wr + (size_t)c * 16);
                    acc[0] = fmaf(xv, wv4.x, acc[0]);
                    acc[1] = fmaf(xv, wv4.y, acc[1]);
                    acc[2] = fmaf(xv, wv4.z, acc[2]);
                    acc[3] = fmaf(xv, wv4.w, acc[3]);
                }
            }
        }
#pragma unroll
        for (int i = 0; i < 4; ++i) h0[px][j * 4 + i] = fmaxf(acc[i], 0.f);
    }

    // 2c g1 partials: out o = tid&63, chunk p = tid>>6 (1792 each)
    {
        const int o = tid & 63, p = tid >> 6;
        const float* gx = xb + 65 * 512 + p * 1792;
        float s = 0.f;
        for (int gi = 0; gi < 1792; ++gi)
            s = fmaf(gx[gi], g1w[(size_t)(p * 1792 + gi) * 64 + o], s);
        gpart[p][o] = s;
    }
    __syncthreads();

    // special reduce -> comb[0..15]
    if (tid < 16) {
        float s = sp_b[tid];
#pragma unroll
        for (int p = 0; p < 16; ++p) s += part[p][tid];
        comb[tid] = fmaxf(s, 0.f);
    }

    // conv1: h0 -> out2[64][32]
    {
        const int px = tid >> 2, j = tid & 3;    // co = j*8..j*8+7
        const int py = px >> 3, pxx = px & 7;
        float acc[8];
#pragma unroll
        for (int i = 0; i < 8; ++i) acc[i] = c1b[j * 8 + i];
        for (int ky = 0; ky < 3; ++ky) {
            const int yy = py + ky - 1;
            if (yy < 0 || yy > 7) continue;
            for (int kx = 0; kx < 3; ++kx) {
                const int xx2 = pxx + kx - 1;
                if (xx2 < 0 || xx2 > 7) continue;
                const float* hr = &h0[yy * 8 + xx2][0];
                const float* wr = c1w + (size_t)(ky * 3 + kx) * 16 * 32 + j * 8;
#pragma unroll
                for (int c = 0; c < 16; ++c) {
                    const float hv = hr[c];
#pragma unroll
                    for (int i = 0; i < 8; ++i)
                        acc[i] = fmaf(hv, wr[c * 32 + i], acc[i]);
                }
            }
        }
#pragma unroll
        for (int i = 0; i < 8; ++i) out2[px][j * 8 + i] = fmaxf(acc[i], 0.f);
    }

    // g1 reduce (uses gpart written before barrier)
    __syncthreads();
    if (tid < 64) {
        float s = g1b[tid];
#pragma unroll
        for (int p = 0; p < 4; ++p) s += gpart[p][tid];
        gpart[0][tid] = fmaxf(s, 0.f);          // g1o lives in gpart[0]
    }

    // conv1 mean part 1: 8 px-chunks x 32 co
    {
        const int co = tid & 31, ch = tid >> 5;
        float s = 0.f;
#pragma unroll
        for (int p = ch * 8; p < ch * 8 + 8; ++p) s += out2[p][co];
        red[ch][co] = s;
    }
    __syncthreads();

    // conv1 mean part 2 -> comb[16..47]
    if (tid < 32) {
        float t = 0.f;
#pragma unroll
        for (int c2 = 0; c2 < 8; ++c2) t += red[c2][tid];
        comb[16 + tid] = t * (1.f / 64.f);
    }
    // g2 -> comb[48..79]
    if (tid >= 64 && tid < 96) {
        const int o = tid - 64;
        float s = g2b[o];
#pragma unroll
        for (int c = 0; c < 64; ++c)
            s = fmaf(gpart[0][c], g2w[c * 32 + o], s);
        comb[48 + o] = fmaxf(s, 0.f);
    }
    __syncthreads();

    // ps[128]
    if (tid < 128) {
        float s = sumb[tid];
#pragma unroll
        for (int c = 0; c < 80; ++c)
            s = fmaf(comb[c], sumw[(size_t)c * 128 + tid], s);
        psS[tid] = silu_f(s);
    }
    __syncthreads();

    // hs for this head only
    if (tid < 128) {
        float s = headb[h * 128 + tid];
        const float* wr = headw + (size_t)h * 128 * 128 + tid;
#pragma unroll
        for (int c = 0; c < 128; ++c)
            s = fmaf(psS[c], wr[(size_t)c * 128], s);
        hsS[tid] = silu_f(s);
    }
    __syncthreads();   // qS/kS/vS (phase 1) and hsS all ready

    // ---------------- phase 3: scores + logits ---------------------
    for (int idx = tid; idx < 6241; idx += 256) {
        const int t = idx / 79, T = idx - t * 79;
        float qk = 0.f;
#pragma unroll
        for (int d = 0; d < 64; ++d)
            qk = fmaf(qS[t][d], kS[T][d], qk);
        float lgv = 0.f;
#pragma unroll 4
        for (int s = 0; s < 128; ++s)
            lgv = fmaf(hsS[s], sproj[(size_t)s * 6241 + idx], lgv);
        scLg[t][T] = qk * 0.125f + lgv;
    }
    __syncthreads();

    // ---------------- phase 4: softmax per row (wave per row) ------
    {
        const int wv = tid >> 6, lane = tid & 63;
        for (int t = wv; t < 79; t += 4) {
            const float v1 = scLg[t][lane];
            const float v2 = (lane < 15) ? scLg[t][lane + 64] : -1e30f;
            float m = fmaxf(v1, v2);
#pragma unroll
            for (int off = 32; off; off >>= 1)
                m = fmaxf(m, __shfl_xor(m, off));
            float e1 = __expf(v1 - m);
            float e2 = (lane < 15) ? __expf(v2 - m) : 0.f;
            float z = e1 + e2;
#pragma unroll
            for (int off = 32; off; off >>= 1)
                z += __shfl_xor(z, off);
            const float rz = 1.f / z;
            scLg[t][lane] = e1 * rz;
            if (lane < 15) scLg[t][lane + 64] = e2 * rz;
        }
    }
    __syncthreads();

    // ---------------- phase 5: PV -> d_out -------------------------
    for (int idx = tid; idx < 79 * 64; idx += 256) {
        const int t = idx >> 6, d = idx & 63;
        float o = 0.f;
#pragma unroll
        for (int T = 0; T < 79; ++T)
            o = fmaf(scLg[t][T], vS[T][d], o);
        outp[((size_t)(b * 79 + t)) * 512 + h * 64 + d] = o;
    }
}

// ---------------------------------------------------------------------------
// outproj_k: in-place per-row output projection on d_out.
// One block per row r; row staged to LDS before overwrite (row-local => safe,
// and fused_bh_k rewrites all of d_out each call => replay-safe).
// ---------------------------------------------------------------------------
__global__ __launch_bounds__(256) void outproj_k(
    const float* __restrict__ wo, float* __restrict__ io)
{
    const int r = blockIdx.x, tid = threadIdx.x;
    __shared__ __attribute__((aligned(16))) float row[512];

    if (tid < 128)
        *(float4*)&row[tid * 4] = *(const float4*)&io[(size_t)r * 512 + tid * 4];
    __syncthreads();

    float o0 = 0.f, o1 = 0.f;
    const int e0 = tid, e1 = tid + 256;
#pragma unroll 4
    for (int c = 0; c < 512; ++c) {
        const float rv = row[c];
        o0 = fmaf(rv, wo[(size_t)c * 512 + e0], o0);
        o1 = fmaf(rv, wo[(size_t)c * 512 + e1], o1);
    }
    io[(size_t)r * 512 + e0] = o0;
    io[(size_t)r * 512 + e1] = o1;
}

// ---------------------------------------------------------------------------
extern "C" void kernel_launch(void* const* d_in, const int* in_sizes, int n_in,
                              void* d_out, int out_size, void* d_ws, size_t ws_size,
                              hipStream_t stream) {
    const float* xq    = (const float*)d_in[0];
    const float* xkv   = (const float*)d_in[1];
    const float* wq    = (const float*)d_in[2];
    const float* wk    = (const float*)d_in[3];
    const float* wv    = (const float*)d_in[4];
    const float* wo    = (const float*)d_in[5];
    const float* sp_w  = (const float*)d_in[6];
    const float* sp_b  = (const float*)d_in[7];
    const float* c0w   = (const float*)d_in[8];
    const float* c0b   = (const float*)d_in[9];
    const float* c1w   = (const float*)d_in[10];
    const float* c1b   = (const float*)d_in[11];
    const float* g1w   = (const float*)d_in[12];
    const float* g1b   = (const float*)d_in[13];
    const float* g2w   = (const float*)d_in[14];
    const float* g2b   = (const float*)d_in[15];
    const float* sumw  = (const float*)d_in[16];
    const float* sumb  = (const float*)d_in[17];
    const float* headw = (const float*)d_in[18];
    const float* headb = (const float*)d_in[19];
    const float* sproj = (const float*)d_in[20];
    float* out = (float*)d_out;

    // NOTE: d_ws is deliberately never used (diagnostic for ws-fault
    // hypothesis; this pipeline needs zero workspace).
    (void)d_ws; (void)ws_size; (void)in_sizes; (void)n_in; (void)out_size;

    fused_bh_k<<<B_ * H_, 256, 0, stream>>>(
        xq, xkv, wq, wk, wv,
        sp_w, sp_b, c0w, c0b, c1w, c1b, g1w, g1b, g2w, g2b,
        sumw, sumb, headw, headb, sproj, out);

    outproj_k<<<B_ * S_, 256, 0, stream>>>(wo, out);
}

// Round 5
// 9807.561 us; speedup vs baseline: 4.0785x; 4.0785x over previous
//
#include <hip/hip_runtime.h>
#include <hip/hip_bf16.h>

#define B_   1024
#define S_   79
#define E_   512
#define H_   8
#define D_   64
#define LDX  (S_*E_)      // 40448

__device__ __forceinline__ float silu_f(float s) {
    return s / (1.f + __expf(-s));
}

// ---------------------------------------------------------------------------
// smolgen_k: one block per batch b, 256 threads. Computes the full smolgen
// chain once per batch (special/conv0/conv1/g1/g2/ps/hs) and stashes
// hs[b,h][128] into d_out inside block (b,h)'s future output region:
//   outp[(b*79 + (i>>6))*512 + h*64 + (i&63)]   (rows t=0,1, head-h columns)
// Only attention block (b,h) reads that stash, before its own writes.
// ---------------------------------------------------------------------------
__global__ __launch_bounds__(256) void smolgen_k(
    const float* __restrict__ xq,
    const float* __restrict__ sp_w, const float* __restrict__ sp_b,
    const float* __restrict__ c0w, const float* __restrict__ c0b,
    const float* __restrict__ c1w, const float* __restrict__ c1b,
    const float* __restrict__ g1w, const float* __restrict__ g1b,
    const float* __restrict__ g2w, const float* __restrict__ g2b,
    const float* __restrict__ sumw, const float* __restrict__ sumb,
    const float* __restrict__ headw, const float* __restrict__ headb,
    float* __restrict__ outp)
{
    const int b = blockIdx.x, tid = threadIdx.x;
    __shared__ __attribute__((aligned(16))) float h0[64][16];
    __shared__ __attribute__((aligned(16))) float out2[64][32];
    __shared__ float red[8][32];
    __shared__ float part[16][16];
    __shared__ float gpart[4][64];
    __shared__ float comb[80];
    __shared__ float psS[128];

    const float* xb = xq + (size_t)b * LDX;

    // special partials
    {
        const int o = tid & 15, p = tid >> 4;
        float s = 0.f;
        for (int c = p * 32; c < p * 32 + 32; ++c)
            s = fmaf(xb[c], sp_w[(size_t)c * 16 + o], s);
        part[p][o] = s;
    }

    // conv0
    {
        const int px = tid >> 2, j = tid & 3;
        const int py = px >> 3, pxx = px & 7;
        float acc[4];
#pragma unroll
        for (int i = 0; i < 4; ++i) acc[i] = c0b[j * 4 + i];
        for (int ky = 0; ky < 3; ++ky) {
            const int yy = py + ky - 1;
            if (yy < 0 || yy > 7) continue;
            for (int kx = 0; kx < 3; ++kx) {
                const int xx2 = pxx + kx - 1;
                if (xx2 < 0 || xx2 > 7) continue;
                const float* xr = xb + (size_t)(1 + yy * 8 + xx2) * 512;
                const float* wr = c0w + (size_t)(ky * 3 + kx) * 512 * 16 + j * 4;
                for (int c = 0; c < 512; ++c) {
                    const float xv = xr[c];
                    float4 wv4 = *(const float4*)(wr + (size_t)c * 16);
                    acc[0] = fmaf(xv, wv4.x, acc[0]);
                    acc[1] = fmaf(xv, wv4.y, acc[1]);
                    acc[2] = fmaf(xv, wv4.z, acc[2]);
                    acc[3] = fmaf(xv, wv4.w, acc[3]);
                }
            }
        }
#pragma unroll
        for (int i = 0; i < 4; ++i) h0[px][j * 4 + i] = fmaxf(acc[i], 0.f);
    }

    // g1 partials
    {
        const int o = tid & 63, p = tid >> 6;
        const float* gx = xb + 65 * 512 + p * 1792;
        float s = 0.f;
        for (int gi = 0; gi < 1792; ++gi)
            s = fmaf(gx[gi], g1w[(size_t)(p * 1792 + gi) * 64 + o], s);
        gpart[p][o] = s;
    }
    __syncthreads();

    if (tid < 16) {
        float s = sp_b[tid];
#pragma unroll
        for (int p = 0; p < 16; ++p) s += part[p][tid];
        comb[tid] = fmaxf(s, 0.f);
    }

    // conv1
    {
        const int px = tid >> 2, j = tid & 3;
        const int py = px >> 3, pxx = px & 7;
        float acc[8];
#pragma unroll
        for (int i = 0; i < 8; ++i) acc[i] = c1b[j * 8 + i];
        for (int ky = 0; ky < 3; ++ky) {
            const int yy = py + ky - 1;
            if (yy < 0 || yy > 7) continue;
            for (int kx = 0; kx < 3; ++kx) {
                const int xx2 = pxx + kx - 1;
                if (xx2 < 0 || xx2 > 7) continue;
                const float* hr = &h0[yy * 8 + xx2][0];
                const float* wr = c1w + (size_t)(ky * 3 + kx) * 16 * 32 + j * 8;
#pragma unroll
                for (int c = 0; c < 16; ++c) {
                    const float hv = hr[c];
#pragma unroll
                    for (int i = 0; i < 8; ++i)
                        acc[i] = fmaf(hv, wr[c * 32 + i], acc[i]);
                }
            }
        }
#pragma unroll
        for (int i = 0; i < 8; ++i) out2[px][j * 8 + i] = fmaxf(acc[i], 0.f);
    }
    __syncthreads();

    if (tid < 64) {
        float s = g1b[tid];
#pragma unroll
        for (int p = 0; p < 4; ++p) s += gpart[p][tid];
        gpart[0][tid] = fmaxf(s, 0.f);
    }
    {
        const int co = tid & 31, ch = tid >> 5;
        float s = 0.f;
#pragma unroll
        for (int p = ch * 8; p < ch * 8 + 8; ++p) s += out2[p][co];
        red[ch][co] = s;
    }
    __syncthreads();

    if (tid < 32) {
        float t = 0.f;
#pragma unroll
        for (int c2 = 0; c2 < 8; ++c2) t += red[c2][tid];
        comb[16 + tid] = t * (1.f / 64.f);
    }
    if (tid >= 64 && tid < 96) {
        const int o = tid - 64;
        float s = g2b[o];
#pragma unroll
        for (int c = 0; c < 64; ++c)
            s = fmaf(gpart[0][c], g2w[c * 32 + o], s);
        comb[48 + o] = fmaxf(s, 0.f);
    }
    __syncthreads();

    if (tid < 128) {
        float s = sumb[tid];
#pragma unroll
        for (int c = 0; c < 80; ++c)
            s = fmaf(comb[c], sumw[(size_t)c * 128 + tid], s);
        psS[tid] = silu_f(s);
    }
    __syncthreads();

    // hs for all 8 heads -> stash into d_out
#pragma unroll
    for (int r = 0; r < 4; ++r) {
        const int o = tid + 256 * r;          // h*128 + i
        const int h = o >> 7, i = o & 127;
        float s = headb[o];
        const float* wr = headw + (size_t)h * 128 * 128 + i;
        float s0 = 0.f, s1 = 0.f, s2 = 0.f, s3 = 0.f;
#pragma unroll
        for (int c = 0; c < 128; c += 4) {
            s0 = fmaf(psS[c + 0], wr[(size_t)(c + 0) * 128], s0);
            s1 = fmaf(psS[c + 1], wr[(size_t)(c + 1) * 128], s1);
            s2 = fmaf(psS[c + 2], wr[(size_t)(c + 2) * 128], s2);
            s3 = fmaf(psS[c + 3], wr[(size_t)(c + 3) * 128], s3);
        }
        s += (s0 + s1) + (s2 + s3);
        outp[((size_t)b * 79 + (i >> 6)) * 512 + h * 64 + (i & 63)] = silu_f(s);
    }
}

// ---------------------------------------------------------------------------
// attn_fused_k: one block per (b,h), 512 threads (8 waves).
//   phase0: load hs stash (own region of outp) -> LDS
//   phase1: QKV head-slices via LDS-staged K-chunked projection
//   phase3: scores = QK^T/8 + hs@sproj -> scLg
//   phase4: per-row softmax
//   phase5: PV -> outp (own region; overwrites stash last)
// LDS ~89 KB -> 1 block/CU, 8 waves (2/SIMD).
// ---------------------------------------------------------------------------
__global__ __launch_bounds__(512) void attn_fused_k(
    const float* __restrict__ xq, const float* __restrict__ xkv,
    const float* __restrict__ wq, const float* __restrict__ wk,
    const float* __restrict__ wv, const float* __restrict__ sproj,
    float* __restrict__ outp)
{
    const int bh = blockIdx.x;
    const int b = bh >> 3, h = bh & 7;
    const int tid = threadIdx.x;
    const int lane = tid & 63, w = tid >> 6;

    __shared__ __attribute__((aligned(16))) float qS[79][64];
    __shared__ __attribute__((aligned(16))) float kS[79][68];   // padded
    __shared__ __attribute__((aligned(16))) float vST[64][84];  // transposed+pad
    __shared__ __attribute__((aligned(16))) float scLg[79][80]; // aliased as xS
    __shared__ float hsS[128];

    float (*xS)[64] = (float (*)[64]) & scLg[0][0];   // phase-1 staging alias

    // phase0: hs stash
    if (tid < 128) {
        const int t = tid >> 6, d = tid & 63;
        hsS[tid] = outp[((size_t)b * 79 + t) * 512 + h * 64 + d];
    }

    const float* xqb = xq + (size_t)b * LDX;
    const float* xkb = xkv + (size_t)b * LDX;
    const int wcol = h * 64 + lane;
    const bool w7ok = (w + 72) < 79;      // wave-uniform

    // ---------------- phase 1A: q ----------------
    float qacc[10];
#pragma unroll
    for (int k = 0; k < 10; ++k) qacc[k] = 0.f;

    for (int k0 = 0; k0 < 512; k0 += 64) {
        __syncthreads();
        for (int i = tid; i < 79 * 16; i += 512) {
            const int r = i >> 4, c4 = (i & 15) << 2;
            *(float4*)&xS[r][c4] = *(const float4*)&xqb[(size_t)r * 512 + k0 + c4];
        }
        __syncthreads();
        const float* wp = wq + (size_t)k0 * 512 + wcol;
#pragma unroll 4
        for (int c0 = 0; c0 < 64; c0 += 4) {
            const float w0 = wp[(size_t)(c0 + 0) * 512];
            const float w1 = wp[(size_t)(c0 + 1) * 512];
            const float w2 = wp[(size_t)(c0 + 2) * 512];
            const float w3 = wp[(size_t)(c0 + 3) * 512];
#pragma unroll
            for (int k = 0; k < 9; ++k) {
                const float4 xv = *(const float4*)&xS[w + 8 * k][c0];
                qacc[k] = fmaf(xv.x, w0, qacc[k]);
                qacc[k] = fmaf(xv.y, w1, qacc[k]);
                qacc[k] = fmaf(xv.z, w2, qacc[k]);
                qacc[k] = fmaf(xv.w, w3, qacc[k]);
            }
            if (w7ok) {
                const float4 xv = *(const float4*)&xS[w + 72][c0];
                qacc[9] = fmaf(xv.x, w0, qacc[9]);
                qacc[9] = fmaf(xv.y, w1, qacc[9]);
                qacc[9] = fmaf(xv.z, w2, qacc[9]);
                qacc[9] = fmaf(xv.w, w3, qacc[9]);
            }
        }
    }
#pragma unroll
    for (int k = 0; k < 9; ++k) qS[w + 8 * k][lane] = qacc[k];
    if (w7ok) qS[w + 72][lane] = qacc[9];

    // ---------------- phase 1B: k, v ----------------
    float kacc[10], vacc[10];
#pragma unroll
    for (int k = 0; k < 10; ++k) { kacc[k] = 0.f; vacc[k] = 0.f; }

    for (int k0 = 0; k0 < 512; k0 += 64) {
        __syncthreads();
        for (int i = tid; i < 79 * 16; i += 512) {
            const int r = i >> 4, c4 = (i & 15) << 2;
            *(float4*)&xS[r][c4] = *(const float4*)&xkb[(size_t)r * 512 + k0 + c4];
        }
        __syncthreads();
        const float* wpk = wk + (size_t)k0 * 512 + wcol;
        const float* wpv = wv + (size_t)k0 * 512 + wcol;
#pragma unroll 2
        for (int c0 = 0; c0 < 64; c0 += 4) {
            const float a0 = wpk[(size_t)(c0 + 0) * 512];
            const float a1 = wpk[(size_t)(c0 + 1) * 512];
            const float a2 = wpk[(size_t)(c0 + 2) * 512];
            const float a3 = wpk[(size_t)(c0 + 3) * 512];
            const float b0 = wpv[(size_t)(c0 + 0) * 512];
            const float b1 = wpv[(size_t)(c0 + 1) * 512];
            const float b2 = wpv[(size_t)(c0 + 2) * 512];
            const float b3 = wpv[(size_t)(c0 + 3) * 512];
#pragma unroll
            for (int k = 0; k < 9; ++k) {
                const float4 xv = *(const float4*)&xS[w + 8 * k][c0];
                kacc[k] = fmaf(xv.x, a0, kacc[k]);
                kacc[k] = fmaf(xv.y, a1, kacc[k]);
                kacc[k] = fmaf(xv.z, a2, kacc[k]);
                kacc[k] = fmaf(xv.w, a3, kacc[k]);
                vacc[k] = fmaf(xv.x, b0, vacc[k]);
                vacc[k] = fmaf(xv.y, b1, vacc[k]);
                vacc[k] = fmaf(xv.z, b2, vacc[k]);
                vacc[k] = fmaf(xv.w, b3, vacc[k]);
            }
            if (w7ok) {
                const float4 xv = *(const float4*)&xS[w + 72][c0];
                kacc[9] = fmaf(xv.x, a0, kacc[9]);
                kacc[9] = fmaf(xv.y, a1, kacc[9]);
                kacc[9] = fmaf(xv.z, a2, kacc[9]);
                kacc[9] = fmaf(xv.w, a3, kacc[9]);
                vacc[9] = fmaf(xv.x, b0, vacc[9]);
                vacc[9] = fmaf(xv.y, b1, vacc[9]);
                vacc[9] = fmaf(xv.z, b2, vacc[9]);
                vacc[9] = fmaf(xv.w, b3, vacc[9]);
            }
        }
    }
#pragma unroll
    for (int k = 0; k < 9; ++k) {
        kS[w + 8 * k][lane] = kacc[k];
        vST[lane][w + 8 * k] = vacc[k];
    }
    if (w7ok) {
        kS[w + 72][lane] = kacc[9];
        vST[lane][w + 72] = vacc[9];
    }
    __syncthreads();   // qS,kS,vST,hsS ready; xS (=scLg) now reusable

    // ---------------- phase 3: scores + logits ----------------
    for (int idx = tid; idx < 6241; idx += 512) {
        const int t = idx / 79, T = idx - t * 79;
        float qx = 0.f, qy = 0.f, qz = 0.f, qw2 = 0.f;
#pragma unroll
        for (int d4 = 0; d4 < 64; d4 += 4) {
            const float4 qv = *(const float4*)&qS[t][d4];
            const float4 kv = *(const float4*)&kS[T][d4];
            qx = fmaf(qv.x, kv.x, qx);
            qy = fmaf(qv.y, kv.y, qy);
            qz = fmaf(qv.z, kv.z, qz);
            qw2 = fmaf(qv.w, kv.w, qw2);
        }
        const float qk = (qx + qy) + (qz + qw2);
        const float* sp = sproj + idx;
        float l0 = 0.f, l1 = 0.f, l2 = 0.f, l3 = 0.f;
#pragma unroll 8
        for (int s = 0; s < 128; s += 4) {
            l0 = fmaf(hsS[s + 0], sp[(size_t)(s + 0) * 6241], l0);
            l1 = fmaf(hsS[s + 1], sp[(size_t)(s + 1) * 6241], l1);
            l2 = fmaf(hsS[s + 2], sp[(size_t)(s + 2) * 6241], l2);
            l3 = fmaf(hsS[s + 3], sp[(size_t)(s + 3) * 6241], l3);
        }
        scLg[t][T] = qk * 0.125f + (l0 + l1) + (l2 + l3);
    }
    __syncthreads();

    // ---------------- phase 4: softmax per row ----------------
    for (int t = w; t < 79; t += 8) {
        const float v1 = scLg[t][lane];
        const float v2 = (lane < 15) ? scLg[t][lane + 64] : -3.0e38f;
        float m = fmaxf(v1, v2);
#pragma unroll
        for (int off = 32; off; off >>= 1)
            m = fmaxf(m, __shfl_xor(m, off));
        float e1 = __expf(v1 - m);
        float e2 = (lane < 15) ? __expf(v2 - m) : 0.f;
        float z = e1 + e2;
#pragma unroll
        for (int off = 32; off; off >>= 1)
            z += __shfl_xor(z, off);
        const float rz = 1.f / z;
        scLg[t][lane] = e1 * rz;
        if (lane < 15) scLg[t][lane + 64] = e2 * rz;
    }
    __syncthreads();

    // ---------------- phase 5: PV -> outp ----------------
#pragma unroll
    for (int k = 0; k < 10; ++k) {
        const int t = w + 8 * k;
        if (t < 79) {
            float ox = 0.f, oy = 0.f, oz = 0.f, ow = 0.f;
#pragma unroll
            for (int T4 = 0; T4 < 76; T4 += 4) {
                const float4 p = *(const float4*)&scLg[t][T4];
                const float4 vv = *(const float4*)&vST[lane][T4];
                ox = fmaf(p.x, vv.x, ox);
                oy = fmaf(p.y, vv.y, oy);
                oz = fmaf(p.z, vv.z, oz);
                ow = fmaf(p.w, vv.w, ow);
            }
            float o = (ox + oy) + (oz + ow);
            o = fmaf(scLg[t][76], vST[lane][76], o);
            o = fmaf(scLg[t][77], vST[lane][77], o);
            o = fmaf(scLg[t][78], vST[lane][78], o);
            outp[((size_t)b * 79 + t) * 512 + h * 64 + lane] = o;
        }
    }
}

// ---------------------------------------------------------------------------
// outproj_k: in-place per-row output projection on d_out (proven in R4).
// ---------------------------------------------------------------------------
__global__ __launch_bounds__(256) void outproj_k(
    const float* __restrict__ wo, float* __restrict__ io)
{
    const int r = blockIdx.x, tid = threadIdx.x;
    __shared__ __attribute__((aligned(16))) float row[512];

    if (tid < 128)
        *(float4*)&row[tid * 4] = *(const float4*)&io[(size_t)r * 512 + tid * 4];
    __syncthreads();

    float o0 = 0.f, o1 = 0.f;
    const int e0 = tid, e1 = tid + 256;
#pragma unroll 4
    for (int c = 0; c < 512; ++c) {
        const float rv = row[c];
        o0 = fmaf(rv, wo[(size_t)c * 512 + e0], o0);
        o1 = fmaf(rv, wo[(size_t)c * 512 + e1], o1);
    }
    io[(size_t)r * 512 + e0] = o0;
    io[(size_t)r * 512 + e1] = o1;
}

// ---------------------------------------------------------------------------
extern "C" void kernel_launch(void* const* d_in, const int* in_sizes, int n_in,
                              void* d_out, int out_size, void* d_ws, size_t ws_size,
                              hipStream_t stream) {
    const float* xq    = (const float*)d_in[0];
    const float* xkv   = (const float*)d_in[1];
    const float* wq    = (const float*)d_in[2];
    const float* wk    = (const float*)d_in[3];
    const float* wv    = (const float*)d_in[4];
    const float* wo    = (const float*)d_in[5];
    const float* sp_w  = (const float*)d_in[6];
    const float* sp_b  = (const float*)d_in[7];
    const float* c0w   = (const float*)d_in[8];
    const float* c0b   = (const float*)d_in[9];
    const float* c1w   = (const float*)d_in[10];
    const float* c1b   = (const float*)d_in[11];
    const float* g1w   = (const float*)d_in[12];
    const float* g1b   = (const float*)d_in[13];
    const float* g2w   = (const float*)d_in[14];
    const float* g2b   = (const float*)d_in[15];
    const float* sumw  = (const float*)d_in[16];
    const float* sumb  = (const float*)d_in[17];
    const float* headw = (const float*)d_in[18];
    const float* headb = (const float*)d_in[19];
    const float* sproj = (const float*)d_in[20];
    float* out = (float*)d_out;

    // d_ws is unusable in this harness (R1-R3 all faulted on first touch;
    // R4 zero-workspace passed). All scratch lives in LDS / d_out.
    (void)d_ws; (void)ws_size; (void)in_sizes; (void)n_in; (void)out_size;

    smolgen_k<<<B_, 256, 0, stream>>>(xq, sp_w, sp_b, c0w, c0b, c1w, c1b,
                                      g1w, g1b, g2w, g2b, sumw, sumb,
                                      headw, headb, out);
    attn_fused_k<<<B_ * H_, 512, 0, stream>>>(xq, xkv, wq, wk, wv, sproj, out);
    outproj_k<<<B_ * S_, 256, 0, stream>>>(wo, out);
}

// Round 6
// 5217.904 us; speedup vs baseline: 7.6659x; 1.8796x over previous
//
#include <hip/hip_runtime.h>
#include <hip/hip_bf16.h>

#define B_   1024
#define S_   79
#define E_   512
#define H_   8
#define D_   64
#define LDX  (S_*E_)      // 40448

// d_out float layout (total 41,418,752 floats):
//   [0        : 20709376)  OUT_BF16: attn output, 80896x512 bf16 (exactly fills)
//   [20709376 : 33490944)  LG_BF16 : half-batch logits, 4096x6241 bf16
//   [33490944 : 34539520)  HS_F32  : smolgen hs, 8192x128 fp32
#define LG_OFF  20709376u
#define HS_OFF  33490944u

__device__ __forceinline__ float silu_f(float s) {
    return s / (1.f + __expf(-s));
}

// ---------------------------------------------------------------------------
// smolgen_k: one block per batch. Full smolgen chain -> hs[b*1024 + h*128+i]
// ---------------------------------------------------------------------------
__global__ __launch_bounds__(256) void smolgen_k(
    const float* __restrict__ xq,
    const float* __restrict__ sp_w, const float* __restrict__ sp_b,
    const float* __restrict__ c0w, const float* __restrict__ c0b,
    const float* __restrict__ c1w, const float* __restrict__ c1b,
    const float* __restrict__ g1w, const float* __restrict__ g1b,
    const float* __restrict__ g2w, const float* __restrict__ g2b,
    const float* __restrict__ sumw, const float* __restrict__ sumb,
    const float* __restrict__ headw, const float* __restrict__ headb,
    float* __restrict__ hsF)
{
    const int b = blockIdx.x, tid = threadIdx.x;
    __shared__ __attribute__((aligned(16))) float h0[64][16];
    __shared__ __attribute__((aligned(16))) float out2[64][32];
    __shared__ float red[8][32];
    __shared__ float part[16][16];
    __shared__ float gpart[4][64];
    __shared__ float comb[80];
    __shared__ float psS[128];

    const float* xb = xq + (size_t)b * LDX;

    {
        const int o = tid & 15, p = tid >> 4;
        float s = 0.f;
        for (int c = p * 32; c < p * 32 + 32; ++c)
            s = fmaf(xb[c], sp_w[(size_t)c * 16 + o], s);
        part[p][o] = s;
    }

    {
        const int px = tid >> 2, j = tid & 3;
        const int py = px >> 3, pxx = px & 7;
        float acc[4];
#pragma unroll
        for (int i = 0; i < 4; ++i) acc[i] = c0b[j * 4 + i];
        for (int ky = 0; ky < 3; ++ky) {
            const int yy = py + ky - 1;
            if (yy < 0 || yy > 7) continue;
            for (int kx = 0; kx < 3; ++kx) {
                const int xx2 = pxx + kx - 1;
                if (xx2 < 0 || xx2 > 7) continue;
                const float* xr = xb + (size_t)(1 + yy * 8 + xx2) * 512;
                const float* wr = c0w + (size_t)(ky * 3 + kx) * 512 * 16 + j * 4;
                for (int c = 0; c < 512; ++c) {
                    const float xv = xr[c];
                    float4 wv4 = *(const float4*)(wr + (size_t)c * 16);
                    acc[0] = fmaf(xv, wv4.x, acc[0]);
                    acc[1] = fmaf(xv, wv4.y, acc[1]);
                    acc[2] = fmaf(xv, wv4.z, acc[2]);
                    acc[3] = fmaf(xv, wv4.w, acc[3]);
                }
            }
        }
#pragma unroll
        for (int i = 0; i < 4; ++i) h0[px][j * 4 + i] = fmaxf(acc[i], 0.f);
    }

    {
        const int o = tid & 63, p = tid >> 6;
        const float* gx = xb + 65 * 512 + p * 1792;
        float s = 0.f;
        for (int gi = 0; gi < 1792; ++gi)
            s = fmaf(gx[gi], g1w[(size_t)(p * 1792 + gi) * 64 + o], s);
        gpart[p][o] = s;
    }
    __syncthreads();

    if (tid < 16) {
        float s = sp_b[tid];
#pragma unroll
        for (int p = 0; p < 16; ++p) s += part[p][tid];
        comb[tid] = fmaxf(s, 0.f);
    }

    {
        const int px = tid >> 2, j = tid & 3;
        const int py = px >> 3, pxx = px & 7;
        float acc[8];
#pragma unroll
        for (int i = 0; i < 8; ++i) acc[i] = c1b[j * 8 + i];
        for (int ky = 0; ky < 3; ++ky) {
            const int yy = py + ky - 1;
            if (yy < 0 || yy > 7) continue;
            for (int kx = 0; kx < 3; ++kx) {
                const int xx2 = pxx + kx - 1;
                if (xx2 < 0 || xx2 > 7) continue;
                const float* hr = &h0[yy * 8 + xx2][0];
                const float* wr = c1w + (size_t)(ky * 3 + kx) * 16 * 32 + j * 8;
#pragma unroll
                for (int c = 0; c < 16; ++c) {
                    const float hv = hr[c];
#pragma unroll
                    for (int i = 0; i < 8; ++i)
                        acc[i] = fmaf(hv, wr[c * 32 + i], acc[i]);
                }
            }
        }
#pragma unroll
        for (int i = 0; i < 8; ++i) out2[px][j * 8 + i] = fmaxf(acc[i], 0.f);
    }
    __syncthreads();

    if (tid < 64) {
        float s = g1b[tid];
#pragma unroll
        for (int p = 0; p < 4; ++p) s += gpart[p][tid];
        gpart[0][tid] = fmaxf(s, 0.f);
    }
    {
        const int co = tid & 31, ch = tid >> 5;
        float s = 0.f;
#pragma unroll
        for (int p = ch * 8; p < ch * 8 + 8; ++p) s += out2[p][co];
        red[ch][co] = s;
    }
    __syncthreads();

    if (tid < 32) {
        float t = 0.f;
#pragma unroll
        for (int c2 = 0; c2 < 8; ++c2) t += red[c2][tid];
        comb[16 + tid] = t * (1.f / 64.f);
    }
    if (tid >= 64 && tid < 96) {
        const int o = tid - 64;
        float s = g2b[o];
#pragma unroll
        for (int c = 0; c < 64; ++c)
            s = fmaf(gpart[0][c], g2w[c * 32 + o], s);
        comb[48 + o] = fmaxf(s, 0.f);
    }
    __syncthreads();

    if (tid < 128) {
        float s = sumb[tid];
#pragma unroll
        for (int c = 0; c < 80; ++c)
            s = fmaf(comb[c], sumw[(size_t)c * 128 + tid], s);
        psS[tid] = silu_f(s);
    }
    __syncthreads();

#pragma unroll
    for (int r = 0; r < 4; ++r) {
        const int o = tid + 256 * r;          // h*128 + i
        const int h = o >> 7, i = o & 127;
        float s = headb[o];
        const float* wr = headw + (size_t)h * 128 * 128 + i;
        float s0 = 0.f, s1 = 0.f, s2 = 0.f, s3 = 0.f;
#pragma unroll
        for (int c = 0; c < 128; c += 4) {
            s0 = fmaf(psS[c + 0], wr[(size_t)(c + 0) * 128], s0);
            s1 = fmaf(psS[c + 1], wr[(size_t)(c + 1) * 128], s1);
            s2 = fmaf(psS[c + 2], wr[(size_t)(c + 2) * 128], s2);
            s3 = fmaf(psS[c + 3], wr[(size_t)(c + 3) * 128], s3);
        }
        s += (s0 + s1) + (s2 + s3);
        hsF[(size_t)b * 1024 + o] = silu_f(s);
    }
}

// ---------------------------------------------------------------------------
// lgemm: C[4096,6241](bf16) = A[4096,128](f32) @ sproj[128,6241]. Tiled 64x64.
// ---------------------------------------------------------------------------
__global__ __launch_bounds__(256) void lgemm_k(
    const float* __restrict__ A, const float* __restrict__ W,
    __hip_bfloat16* __restrict__ C)
{
    __shared__ __attribute__((aligned(16))) float As[16][64];
    __shared__ __attribute__((aligned(16))) float Bs[16][64];

    const int tid = threadIdx.x;
    const int tx = tid & 15, ty = tid >> 4;
    const int row0 = blockIdx.y * 64, col0 = blockIdx.x * 64;
    const int lr = tid >> 2, lk = (tid & 3) * 4;
    const int bkk = tid >> 4, bc = (tid & 15) * 4;

    float acc[4][4];
#pragma unroll
    for (int i = 0; i < 4; ++i)
#pragma unroll
        for (int j = 0; j < 4; ++j) acc[i][j] = 0.f;

    for (int k0 = 0; k0 < 128; k0 += 16) {
        float4 av = *(const float4*)(A + (size_t)(row0 + lr) * 128 + k0 + lk);
        float4 bv;
        const float* wp = W + (size_t)(k0 + bkk) * 6241 + col0 + bc;
        const int cb = col0 + bc;
        bv.x = (cb + 0 < 6241) ? wp[0] : 0.f;
        bv.y = (cb + 1 < 6241) ? wp[1] : 0.f;
        bv.z = (cb + 2 < 6241) ? wp[2] : 0.f;
        bv.w = (cb + 3 < 6241) ? wp[3] : 0.f;

        __syncthreads();
        As[lk + 0][lr] = av.x; As[lk + 1][lr] = av.y;
        As[lk + 2][lr] = av.z; As[lk + 3][lr] = av.w;
        *(float4*)&Bs[bkk][bc] = bv;
        __syncthreads();

#pragma unroll
        for (int kk = 0; kk < 16; ++kk) {
            float4 a4 = *(const float4*)&As[kk][ty * 4];
            float4 b4 = *(const float4*)&Bs[kk][tx * 4];
            float a[4] = {a4.x, a4.y, a4.z, a4.w};
            float bb[4] = {b4.x, b4.y, b4.z, b4.w};
#pragma unroll
            for (int i = 0; i < 4; ++i)
#pragma unroll
                for (int j = 0; j < 4; ++j)
                    acc[i][j] = fmaf(a[i], bb[j], acc[i][j]);
        }
    }

#pragma unroll
    for (int i = 0; i < 4; ++i) {
        const int r = row0 + ty * 4 + i;
#pragma unroll
        for (int j = 0; j < 4; ++j) {
            const int c = col0 + tx * 4 + j;
            if (c < 6241)
                C[(size_t)r * 6241 + c] = __float2bfloat16(acc[i][j]);
        }
    }
}

// ---------------------------------------------------------------------------
// attn_half_k: one block per (b,h), b in [b0, b0+512). 512 threads.
//   phase1: QKV head-slices (LDS-staged x, coalesced global weights)
//   phase3: scores = QK^T/8 + precomputed logits (bf16)  -> scLg
//   phase4: softmax per row  (V stays in regs; V->LDS into Q's dead region)
//   phase5: PV -> OUT_BF16
// LDS 68.5 KB -> 2 blocks/CU.
// ---------------------------------------------------------------------------
__global__ __launch_bounds__(512, 4) void attn_half_k(
    const float* __restrict__ xq, const float* __restrict__ xkv,
    const float* __restrict__ wq, const float* __restrict__ wk,
    const float* __restrict__ wv,
    const __hip_bfloat16* __restrict__ lgB,
    __hip_bfloat16* __restrict__ outB, int b0)
{
    const int bh = blockIdx.x;
    const int bl = bh >> 3, h = bh & 7;
    const int b = b0 + bl;
    const int tid = threadIdx.x;
    const int lane = tid & 63, w = tid >> 6;

    // bufA: qS (stride 68, 79 rows) then reused as vST (stride 84, 64 rows)
    __shared__ __attribute__((aligned(16))) float bufA[5376];
    __shared__ __attribute__((aligned(16))) float kS[79][68];
    __shared__ __attribute__((aligned(16))) float scLg[79][80];  // xS alias

    float* xS = &scLg[0][0];   // stride 64, 79 rows (phase 1 staging)

    const float* xqb = xq + (size_t)b * LDX;
    const float* xkb = xkv + (size_t)b * LDX;
    const int wcol = h * 64 + lane;
    const bool w7ok = (w + 72) < 79;

    // ---------------- phase 1A: Q ----------------
    float qacc[10];
#pragma unroll
    for (int k = 0; k < 10; ++k) qacc[k] = 0.f;

    for (int k0 = 0; k0 < 512; k0 += 64) {
        __syncthreads();
        for (int i = tid; i < 79 * 16; i += 512) {
            const int r = i >> 4, c4 = (i & 15) << 2;
            *(float4*)&xS[r * 64 + c4] =
                *(const float4*)&xqb[(size_t)r * 512 + k0 + c4];
        }
        __syncthreads();
        const float* wp = wq + (size_t)k0 * 512 + wcol;
#pragma unroll 4
        for (int c0 = 0; c0 < 64; c0 += 4) {
            const float w0 = wp[(size_t)(c0 + 0) * 512];
            const float w1 = wp[(size_t)(c0 + 1) * 512];
            const float w2 = wp[(size_t)(c0 + 2) * 512];
            const float w3 = wp[(size_t)(c0 + 3) * 512];
#pragma unroll
            for (int k = 0; k < 9; ++k) {
                const float4 xv = *(const float4*)&xS[(w + 8 * k) * 64 + c0];
                qacc[k] = fmaf(xv.x, w0, qacc[k]);
                qacc[k] = fmaf(xv.y, w1, qacc[k]);
                qacc[k] = fmaf(xv.z, w2, qacc[k]);
                qacc[k] = fmaf(xv.w, w3, qacc[k]);
            }
            if (w7ok) {
                const float4 xv = *(const float4*)&xS[(w + 72) * 64 + c0];
                qacc[9] = fmaf(xv.x, w0, qacc[9]);
                qacc[9] = fmaf(xv.y, w1, qacc[9]);
                qacc[9] = fmaf(xv.z, w2, qacc[9]);
                qacc[9] = fmaf(xv.w, w3, qacc[9]);
            }
        }
    }
#pragma unroll
    for (int k = 0; k < 9; ++k) bufA[(w + 8 * k) * 68 + lane] = qacc[k];
    if (w7ok) bufA[(w + 72) * 68 + lane] = qacc[9];

    // ---------------- phase 1B: K, V (V kept in regs) ----------------
    float kacc[10], vacc[10];
#pragma unroll
    for (int k = 0; k < 10; ++k) { kacc[k] = 0.f; vacc[k] = 0.f; }

    for (int k0 = 0; k0 < 512; k0 += 64) {
        __syncthreads();
        for (int i = tid; i < 79 * 16; i += 512) {
            const int r = i >> 4, c4 = (i & 15) << 2;
            *(float4*)&xS[r * 64 + c4] =
                *(const float4*)&xkb[(size_t)r * 512 + k0 + c4];
        }
        __syncthreads();
        const float* wpk = wk + (size_t)k0 * 512 + wcol;
        const float* wpv = wv + (size_t)k0 * 512 + wcol;
#pragma unroll 2
        for (int c0 = 0; c0 < 64; c0 += 4) {
            const float a0 = wpk[(size_t)(c0 + 0) * 512];
            const float a1 = wpk[(size_t)(c0 + 1) * 512];
            const float a2 = wpk[(size_t)(c0 + 2) * 512];
            const float a3 = wpk[(size_t)(c0 + 3) * 512];
            const float b0v = wpv[(size_t)(c0 + 0) * 512];
            const float b1v = wpv[(size_t)(c0 + 1) * 512];
            const float b2v = wpv[(size_t)(c0 + 2) * 512];
            const float b3v = wpv[(size_t)(c0 + 3) * 512];
#pragma unroll
            for (int k = 0; k < 9; ++k) {
                const float4 xv = *(const float4*)&xS[(w + 8 * k) * 64 + c0];
                kacc[k] = fmaf(xv.x, a0, kacc[k]);
                kacc[k] = fmaf(xv.y, a1, kacc[k]);
                kacc[k] = fmaf(xv.z, a2, kacc[k]);
                kacc[k] = fmaf(xv.w, a3, kacc[k]);
                vacc[k] = fmaf(xv.x, b0v, vacc[k]);
                vacc[k] = fmaf(xv.y, b1v, vacc[k]);
                vacc[k] = fmaf(xv.z, b2v, vacc[k]);
                vacc[k] = fmaf(xv.w, b3v, vacc[k]);
            }
            if (w7ok) {
                const float4 xv = *(const float4*)&xS[(w + 72) * 64 + c0];
                kacc[9] = fmaf(xv.x, a0, kacc[9]);
                kacc[9] = fmaf(xv.y, a1, kacc[9]);
                kacc[9] = fmaf(xv.z, a2, kacc[9]);
                kacc[9] = fmaf(xv.w, a3, kacc[9]);
                vacc[9] = fmaf(xv.x, b0v, vacc[9]);
                vacc[9] = fmaf(xv.y, b1v, vacc[9]);
                vacc[9] = fmaf(xv.z, b2v, vacc[9]);
                vacc[9] = fmaf(xv.w, b3v, vacc[9]);
            }
        }
    }
#pragma unroll
    for (int k = 0; k < 9; ++k) kS[w + 8 * k][lane] = kacc[k];
    if (w7ok) kS[w + 72][lane] = kacc[9];
    __syncthreads();   // qS(bufA), kS ready; scLg(xS) now reusable

    // ---------------- phase 3: scores + precomputed logits ----------------
    const __hip_bfloat16* lgp = lgB + (size_t)(bl * 8 + h) * 6241;
    for (int idx = tid; idx < 6241; idx += 512) {
        const int t = idx / 79, T = idx - t * 79;
        float qx = 0.f, qy = 0.f, qz = 0.f, qw2 = 0.f;
#pragma unroll
        for (int d4 = 0; d4 < 64; d4 += 4) {
            const float4 qv = *(const float4*)&bufA[t * 68 + d4];
            const float4 kv = *(const float4*)&kS[T][d4];
            qx = fmaf(qv.x, kv.x, qx);
            qy = fmaf(qv.y, kv.y, qy);
            qz = fmaf(qv.z, kv.z, qz);
            qw2 = fmaf(qv.w, kv.w, qw2);
        }
        const float qk = (qx + qy) + (qz + qw2);
        scLg[t][T] = qk * 0.125f + __bfloat162float(lgp[idx]);
    }
    __syncthreads();   // all qS reads done -> bufA free for vST

    // vST fill (stride 84) + softmax, then one barrier
#pragma unroll
    for (int k = 0; k < 9; ++k) bufA[lane * 84 + (w + 8 * k)] = vacc[k];
    if (w7ok) bufA[lane * 84 + (w + 72)] = vacc[9];

    for (int t = w; t < 79; t += 8) {
        const float v1 = scLg[t][lane];
        const float v2 = (lane < 15) ? scLg[t][lane + 64] : -3.0e38f;
        float m = fmaxf(v1, v2);
#pragma unroll
        for (int off = 32; off; off >>= 1)
            m = fmaxf(m, __shfl_xor(m, off));
        float e1 = __expf(v1 - m);
        float e2 = (lane < 15) ? __expf(v2 - m) : 0.f;
        float z = e1 + e2;
#pragma unroll
        for (int off = 32; off; off >>= 1)
            z += __shfl_xor(z, off);
        const float rz = 1.f / z;
        scLg[t][lane] = e1 * rz;
        if (lane < 15) scLg[t][lane + 64] = e2 * rz;
    }
    __syncthreads();

    // ---------------- phase 5: PV -> OUT_BF16 ----------------
#pragma unroll
    for (int k = 0; k < 10; ++k) {
        const int t = w + 8 * k;
        if (t < 79) {
            float ox = 0.f, oy = 0.f, oz = 0.f, ow = 0.f;
#pragma unroll
            for (int T4 = 0; T4 < 76; T4 += 4) {
                const float4 p = *(const float4*)&scLg[t][T4];
                const float4 vv = *(const float4*)&bufA[lane * 84 + T4];
                ox = fmaf(p.x, vv.x, ox);
                oy = fmaf(p.y, vv.y, oy);
                oz = fmaf(p.z, vv.z, oz);
                ow = fmaf(p.w, vv.w, ow);
            }
            float o = (ox + oy) + (oz + ow);
            o = fmaf(scLg[t][76], bufA[lane * 84 + 76], o);
            o = fmaf(scLg[t][77], bufA[lane * 84 + 77], o);
            o = fmaf(scLg[t][78], bufA[lane * 84 + 78], o);
            outB[((size_t)b * 79 + t) * 512 + h * 64 + lane] = __float2bfloat16(o);
        }
    }
}

// ---------------------------------------------------------------------------
// gemm_out_k: C[r,:] = A_bf16[r,:] @ wo, rows r in [M0,M1). Tiled 64x64.
// In-place over d_out via the halving ladder (see kernel_launch).
// ---------------------------------------------------------------------------
__global__ __launch_bounds__(256) void gemm_out_k(
    const unsigned short* __restrict__ A, const float* __restrict__ W,
    float* __restrict__ C, int M0, int M1)
{
    __shared__ __attribute__((aligned(16))) float As[16][64];
    __shared__ __attribute__((aligned(16))) float Bs[16][64];

    const int tid = threadIdx.x;
    const int tx = tid & 15, ty = tid >> 4;
    const int row0 = M0 + blockIdx.y * 64, col0 = blockIdx.x * 64;
    const int lr = tid >> 2, lk = (tid & 3) * 4;
    const int bkk = tid >> 4, bc = (tid & 15) * 4;

    int ar = row0 + lr; if (ar > M1 - 1) ar = M1 - 1;

    float acc[4][4];
#pragma unroll
    for (int i = 0; i < 4; ++i)
#pragma unroll
        for (int j = 0; j < 4; ++j) acc[i][j] = 0.f;

    for (int k0 = 0; k0 < 512; k0 += 16) {
        const uint2 u = *(const uint2*)(A + (size_t)ar * 512 + k0 + lk);
        float a0 = __uint_as_float((u.x & 0xffffu) << 16);
        float a1 = __uint_as_float(u.x & 0xffff0000u);
        float a2 = __uint_as_float((u.y & 0xffffu) << 16);
        float a3 = __uint_as_float(u.y & 0xffff0000u);
        float4 bv = *(const float4*)&W[(size_t)(k0 + bkk) * 512 + col0 + bc];

        __syncthreads();
        As[lk + 0][lr] = a0; As[lk + 1][lr] = a1;
        As[lk + 2][lr] = a2; As[lk + 3][lr] = a3;
        *(float4*)&Bs[bkk][bc] = bv;
        __syncthreads();

#pragma unroll
        for (int kk = 0; kk < 16; ++kk) {
            float4 a4 = *(const float4*)&As[kk][ty * 4];
            float4 b4 = *(const float4*)&Bs[kk][tx * 4];
            float a[4] = {a4.x, a4.y, a4.z, a4.w};
            float bb[4] = {b4.x, b4.y, b4.z, b4.w};
#pragma unroll
            for (int i = 0; i < 4; ++i)
#pragma unroll
                for (int j = 0; j < 4; ++j)
                    acc[i][j] = fmaf(a[i], bb[j], acc[i][j]);
        }
    }

#pragma unroll
    for (int i = 0; i < 4; ++i) {
        const int r = row0 + ty * 4 + i;
        if (r < M1) {
#pragma unroll
            for (int j = 0; j < 4; ++j)
                C[(size_t)r * 512 + col0 + tx * 4 + j] = acc[i][j];
        }
    }
}

// ---------------------------------------------------------------------------
extern "C" void kernel_launch(void* const* d_in, const int* in_sizes, int n_in,
                              void* d_out, int out_size, void* d_ws, size_t ws_size,
                              hipStream_t stream) {
    const float* xq    = (const float*)d_in[0];
    const float* xkv   = (const float*)d_in[1];
    const float* wq    = (const float*)d_in[2];
    const float* wk    = (const float*)d_in[3];
    const float* wv    = (const float*)d_in[4];
    const float* wo    = (const float*)d_in[5];
    const float* sp_w  = (const float*)d_in[6];
    const float* sp_b  = (const float*)d_in[7];
    const float* c0w   = (const float*)d_in[8];
    const float* c0b   = (const float*)d_in[9];
    const float* c1w   = (const float*)d_in[10];
    const float* c1b   = (const float*)d_in[11];
    const float* g1w   = (const float*)d_in[12];
    const float* g1b   = (const float*)d_in[13];
    const float* g2w   = (const float*)d_in[14];
    const float* g2b   = (const float*)d_in[15];
    const float* sumw  = (const float*)d_in[16];
    const float* sumb  = (const float*)d_in[17];
    const float* headw = (const float*)d_in[18];
    const float* headb = (const float*)d_in[19];
    const float* sproj = (const float*)d_in[20];
    float* out = (float*)d_out;

    // d_ws unusable in this harness (R1-R3 faulted on first touch; R4+ pass
    // with zero workspace). All intermediates live inside d_out (layout top).
    (void)d_ws; (void)ws_size; (void)in_sizes; (void)n_in; (void)out_size;

    __hip_bfloat16* outB = (__hip_bfloat16*)out;
    __hip_bfloat16* lgB  = (__hip_bfloat16*)(out + LG_OFF);
    float* hsF = out + HS_OFF;

    smolgen_k<<<B_, 256, 0, stream>>>(xq, sp_w, sp_b, c0w, c0b, c1w, c1b,
                                      g1w, g1b, g2w, g2b, sumw, sumb,
                                      headw, headb, hsF);

    for (int half = 0; half < 2; ++half) {
        const float* Ahs = hsF + (size_t)half * 4096 * 128;
        lgemm_k<<<dim3(98, 64), 256, 0, stream>>>(Ahs, sproj, lgB);
        attn_half_k<<<4096, 512, 0, stream>>>(xq, xkv, wq, wk, wv,
                                              lgB, outB, half * 512);
    }

    // In-place output projection: halving ladder. Pass [lo,hi) writes fp32
    // rows [lo,hi) (floats [512lo,512hi)), overwriting bf16 rows [2lo,2hi);
    // lo=ceil(hi/2) => 2lo>=hi => those rows were read by earlier passes.
    int hi = B_ * S_;
    while (hi > 0) {
        int lo = (hi + 1) >> 1;
        if (lo == hi) lo = hi - 1;
        gemm_out_k<<<dim3(8, (hi - lo + 63) / 64), 256, 0, stream>>>(
            (const unsigned short*)outB, wo, out, lo, hi);
        hi = lo;
    }
}

// Round 7
// 4594.334 us; speedup vs baseline: 8.7063x; 1.1357x over previous
//
#include <hip/hip_runtime.h>
#include <hip/hip_bf16.h>

#define B_   1024
#define S_   79
#define E_   512
#define H_   8
#define D_   64
#define LDX  (S_*E_)      // 40448

// d_out float layout (total 41,418,752 floats):
//   [0        : 20709376)  OUT_BF16: attn output, 80896x512 bf16
//   [20709376 : 33490944)  LG_BF16 : half-batch logits, 4096x6241 bf16
//   [33490944 : 34539520)  HS_F32  : smolgen hs, 8192x128 fp32
#define LG_OFF  20709376u
#define HS_OFF  33490944u

typedef __attribute__((ext_vector_type(8))) short short8v;   // 8 bf16
typedef __attribute__((ext_vector_type(4))) short short4v;
typedef __attribute__((ext_vector_type(4))) float f32x4;

__device__ __forceinline__ float silu_f(float s) {
    return s / (1.f + __expf(-s));
}

// RNE fp32 -> bf16 split: x ~= hi + lo (both bf16), exact residual path.
__device__ __forceinline__ void bsplit(float x, unsigned short& h,
                                       unsigned short& l) {
    unsigned u = __float_as_uint(x);
    unsigned hr = (u + 0x7fffu + ((u >> 16) & 1u)) >> 16;
    h = (unsigned short)hr;
    float r = x - __uint_as_float(hr << 16);
    unsigned u2 = __float_as_uint(r);
    l = (unsigned short)((u2 + 0x7fffu + ((u2 >> 16) & 1u)) >> 16);
}

// ---------------------------------------------------------------------------
// smolgen_k: one block per batch. Full smolgen chain -> hs[b*1024 + h*128+i]
// ---------------------------------------------------------------------------
__global__ __launch_bounds__(256) void smolgen_k(
    const float* __restrict__ xq,
    const float* __restrict__ sp_w, const float* __restrict__ sp_b,
    const float* __restrict__ c0w, const float* __restrict__ c0b,
    const float* __restrict__ c1w, const float* __restrict__ c1b,
    const float* __restrict__ g1w, const float* __restrict__ g1b,
    const float* __restrict__ g2w, const float* __restrict__ g2b,
    const float* __restrict__ sumw, const float* __restrict__ sumb,
    const float* __restrict__ headw, const float* __restrict__ headb,
    float* __restrict__ hsF)
{
    const int b = blockIdx.x, tid = threadIdx.x;
    __shared__ __attribute__((aligned(16))) float h0[64][16];
    __shared__ __attribute__((aligned(16))) float out2[64][32];
    __shared__ float red[8][32];
    __shared__ float part[16][16];
    __shared__ float gpart[4][64];
    __shared__ float comb[80];
    __shared__ float psS[128];

    const float* xb = xq + (size_t)b * LDX;

    {
        const int o = tid & 15, p = tid >> 4;
        float s = 0.f;
        for (int c = p * 32; c < p * 32 + 32; ++c)
            s = fmaf(xb[c], sp_w[(size_t)c * 16 + o], s);
        part[p][o] = s;
    }

    {
        const int px = tid >> 2, j = tid & 3;
        const int py = px >> 3, pxx = px & 7;
        float acc[4];
#pragma unroll
        for (int i = 0; i < 4; ++i) acc[i] = c0b[j * 4 + i];
        for (int ky = 0; ky < 3; ++ky) {
            const int yy = py + ky - 1;
            if (yy < 0 || yy > 7) continue;
            for (int kx = 0; kx < 3; ++kx) {
                const int xx2 = pxx + kx - 1;
                if (xx2 < 0 || xx2 > 7) continue;
                const float* xr = xb + (size_t)(1 + yy * 8 + xx2) * 512;
                const float* wr = c0w + (size_t)(ky * 3 + kx) * 512 * 16 + j * 4;
                for (int c = 0; c < 512; ++c) {
                    const float xv = xr[c];
                    float4 wv4 = *(const float4*)(wr + (size_t)c * 16);
                    acc[0] = fmaf(xv, wv4.x, acc[0]);
                    acc[1] = fmaf(xv, wv4.y, acc[1]);
                    acc[2] = fmaf(xv, wv4.z, acc[2]);
                    acc[3] = fmaf(xv, wv4.w, acc[3]);
                }
            }
        }
#pragma unroll
        for (int i = 0; i < 4; ++i) h0[px][j * 4 + i] = fmaxf(acc[i], 0.f);
    }

    {
        const int o = tid & 63, p = tid >> 6;
        const float* gx = xb + 65 * 512 + p * 1792;
        float s = 0.f;
        for (int gi = 0; gi < 1792; ++gi)
            s = fmaf(gx[gi], g1w[(size_t)(p * 1792 + gi) * 64 + o], s);
        gpart[p][o] = s;
    }
    __syncthreads();

    if (tid < 16) {
        float s = sp_b[tid];
#pragma unroll
        for (int p = 0; p < 16; ++p) s += part[p][tid];
        comb[tid] = fmaxf(s, 0.f);
    }

    {
        const int px = tid >> 2, j = tid & 3;
        const int py = px >> 3, pxx = px & 7;
        float acc[8];
#pragma unroll
        for (int i = 0; i < 8; ++i) acc[i] = c1b[j * 8 + i];
        for (int ky = 0; ky < 3; ++ky) {
            const int yy = py + ky - 1;
            if (yy < 0 || yy > 7) continue;
            for (int kx = 0; kx < 3; ++kx) {
                const int xx2 = pxx + kx - 1;
                if (xx2 < 0 || xx2 > 7) continue;
                const float* hr = &h0[yy * 8 + xx2][0];
                const float* wr = c1w + (size_t)(ky * 3 + kx) * 16 * 32 + j * 8;
#pragma unroll
                for (int c = 0; c < 16; ++c) {
                    const float hv = hr[c];
#pragma unroll
                    for (int i = 0; i < 8; ++i)
                        acc[i] = fmaf(hv, wr[c * 32 + i], acc[i]);
                }
            }
        }
#pragma unroll
        for (int i = 0; i < 8; ++i) out2[px][j * 8 + i] = fmaxf(acc[i], 0.f);
    }
    __syncthreads();

    if (tid < 64) {
        float s = g1b[tid];
#pragma unroll
        for (int p = 0; p < 4; ++p) s += gpart[p][tid];
        gpart[0][tid] = fmaxf(s, 0.f);
    }
    {
        const int co = tid & 31, ch = tid >> 5;
        float s = 0.f;
#pragma unroll
        for (int p = ch * 8; p < ch * 8 + 8; ++p) s += out2[p][co];
        red[ch][co] = s;
    }
    __syncthreads();

    if (tid < 32) {
        float t = 0.f;
#pragma unroll
        for (int c2 = 0; c2 < 8; ++c2) t += red[c2][tid];
        comb[16 + tid] = t * (1.f / 64.f);
    }
    if (tid >= 64 && tid < 96) {
        const int o = tid - 64;
        float s = g2b[o];
#pragma unroll
        for (int c = 0; c < 64; ++c)
            s = fmaf(gpart[0][c], g2w[c * 32 + o], s);
        comb[48 + o] = fmaxf(s, 0.f);
    }
    __syncthreads();

    if (tid < 128) {
        float s = sumb[tid];
#pragma unroll
        for (int c = 0; c < 80; ++c)
            s = fmaf(comb[c], sumw[(size_t)c * 128 + tid], s);
        psS[tid] = silu_f(s);
    }
    __syncthreads();

#pragma unroll
    for (int r = 0; r < 4; ++r) {
        const int o = tid + 256 * r;          // h*128 + i
        const int h = o >> 7, i = o & 127;
        float s = headb[o];
        const float* wr = headw + (size_t)h * 128 * 128 + i;
        float s0 = 0.f, s1 = 0.f, s2 = 0.f, s3 = 0.f;
#pragma unroll
        for (int c = 0; c < 128; c += 4) {
            s0 = fmaf(psS[c + 0], wr[(size_t)(c + 0) * 128], s0);
            s1 = fmaf(psS[c + 1], wr[(size_t)(c + 1) * 128], s1);
            s2 = fmaf(psS[c + 2], wr[(size_t)(c + 2) * 128], s2);
            s3 = fmaf(psS[c + 3], wr[(size_t)(c + 3) * 128], s3);
        }
        s += (s0 + s1) + (s2 + s3);
        hsF[(size_t)b * 1024 + o] = silu_f(s);
    }
}

// ---------------------------------------------------------------------------
// lgemm: C[4096,6241](bf16) = A[4096,128](f32) @ sproj[128,6241]. Tiled 64x64.
// ---------------------------------------------------------------------------
__global__ __launch_bounds__(256) void lgemm_k(
    const float* __restrict__ A, const float* __restrict__ W,
    __hip_bfloat16* __restrict__ C)
{
    __shared__ __attribute__((aligned(16))) float As[16][64];
    __shared__ __attribute__((aligned(16))) float Bs[16][64];

    const int tid = threadIdx.x;
    const int tx = tid & 15, ty = tid >> 4;
    const int row0 = blockIdx.y * 64, col0 = blockIdx.x * 64;
    const int lr = tid >> 2, lk = (tid & 3) * 4;
    const int bkk = tid >> 4, bc = (tid & 15) * 4;

    float acc[4][4];
#pragma unroll
    for (int i = 0; i < 4; ++i)
#pragma unroll
        for (int j = 0; j < 4; ++j) acc[i][j] = 0.f;

    for (int k0 = 0; k0 < 128; k0 += 16) {
        float4 av = *(const float4*)(A + (size_t)(row0 + lr) * 128 + k0 + lk);
        float4 bv;
        const float* wp = W + (size_t)(k0 + bkk) * 6241 + col0 + bc;
        const int cb = col0 + bc;
        bv.x = (cb + 0 < 6241) ? wp[0] : 0.f;
        bv.y = (cb + 1 < 6241) ? wp[1] : 0.f;
        bv.z = (cb + 2 < 6241) ? wp[2] : 0.f;
        bv.w = (cb + 3 < 6241) ? wp[3] : 0.f;

        __syncthreads();
        As[lk + 0][lr] = av.x; As[lk + 1][lr] = av.y;
        As[lk + 2][lr] = av.z; As[lk + 3][lr] = av.w;
        *(float4*)&Bs[bkk][bc] = bv;
        __syncthreads();

#pragma unroll
        for (int kk = 0; kk < 16; ++kk) {
            float4 a4 = *(const float4*)&As[kk][ty * 4];
            float4 b4 = *(const float4*)&Bs[kk][tx * 4];
            float a[4] = {a4.x, a4.y, a4.z, a4.w};
            float bb[4] = {b4.x, b4.y, b4.z, b4.w};
#pragma unroll
            for (int i = 0; i < 4; ++i)
#pragma unroll
                for (int j = 0; j < 4; ++j)
                    acc[i][j] = fmaf(a[i], bb[j], acc[i][j]);
        }
    }

#pragma unroll
    for (int i = 0; i < 4; ++i) {
        const int r = row0 + ty * 4 + i;
#pragma unroll
        for (int j = 0; j < 4; ++j) {
            const int c = col0 + tx * 4 + j;
            if (c < 6241)
                C[(size_t)r * 6241 + c] = __float2bfloat16(acc[i][j]);
        }
    }
}

// ---------------------------------------------------------------------------
// attn_half_k v3: one block per (b,h), 512 threads (8 waves).
//   phase1: QKV head-slices via split-bf16 MFMA (16 K-chunks of 32)
//           x = xhi+xlo, w = whi+wlo; acc += Ah*Bh + Ah*Bl + Al*Bh (fp32 acc)
//   phase3: scores = QK^T/8 + precomputed logits (bf16)
//   phase4: softmax per row  (V in regs through phase3; vST into qS region)
//   phase5: PV -> OUT_BF16
// LDS 68800 B -> 2 blocks/CU.
// ---------------------------------------------------------------------------
#define QS_OFF  0u        // float, stride 68, rows 0..78   (also vST later)
#define KS_OFF  21760u    // float, stride 68, rows 0..78
#define SC_OFF  43520u    // float, stride 80, rows 0..78
// staging (ushort offsets into LDS): x hi/lo 80x40, w hi/lo 64x40 per matrix
#define XH_U   0u
#define XL_U   3200u
#define W0H_U  6400u
#define W0L_U  8960u
#define W1H_U  11520u
#define W1L_U  14080u     // end 16640 ushorts = 33280 B < 43520 (qS+kS region)

__global__ __launch_bounds__(512, 4) void attn_half_k(
    const float* __restrict__ xq, const float* __restrict__ xkv,
    const float* __restrict__ wq, const float* __restrict__ wk,
    const float* __restrict__ wv,
    const __hip_bfloat16* __restrict__ lgB,
    __hip_bfloat16* __restrict__ outB, int b0)
{
    const int bh = blockIdx.x;
    const int bl = bh >> 3, h = bh & 7;
    const int b = b0 + bl;
    const int tid = threadIdx.x;
    const int lane = tid & 63, w = tid >> 6;

    __shared__ __attribute__((aligned(16))) unsigned char Lds[68800];
    unsigned short* L16 = (unsigned short*)Lds;
    float* qSf = (float*)(Lds + QS_OFF);
    float* kSf = (float*)(Lds + KS_OFF);
    float* scLg = (float*)(Lds + SC_OFF);
    float* vSTf = (float*)(Lds + QS_OFF);   // after phase3

    const float* xqb = xq + (size_t)b * LDX;
    const float* xkb = xkv + (size_t)b * LDX;

    // ---------------- phase 1: QKV via split-bf16 MFMA ----------------
    const int Lr = lane & 15, Lg = lane >> 4;
    const int ntw = w & 3;                 // wave's N-tile (col0 = ntw*16)
    const int mtw = w >> 2;                // first M-tile = mtw, then +2
    const int nTiles = (w < 4) ? 3 : 2;
    const int cB = ntw * 16 + Lr;          // B fragment column
    const int kgB = Lg ^ ((cB >> 3) & 3);  // swizzled k-group for B reads
    const unsigned bOff = cB * 40 + kgB * 8;

    f32x4 accQ[3], accK[3], accV[3];
#pragma unroll
    for (int i = 0; i < 3; ++i) {
        accQ[i] = (f32x4){0.f, 0.f, 0.f, 0.f};
        accK[i] = (f32x4){0.f, 0.f, 0.f, 0.f};
        accV[i] = (f32x4){0.f, 0.f, 0.f, 0.f};
    }

    for (int ch = 0; ch < 16; ++ch) {
        const int k0 = ch * 32;

        // ---- sub-pass A: stage xq + wq, mfma Q ----
        __syncthreads();
        for (int i = tid; i < 640; i += 512) {            // x: 80r x 8 f4
            const int r = i >> 3, k4 = (i & 7) << 2;
            float4 xv = {0.f, 0.f, 0.f, 0.f};
            if (r < 79) xv = *(const float4*)&xqb[(size_t)r * 512 + k0 + k4];
            unsigned short hh[4], ll[4];
            bsplit(xv.x, hh[0], ll[0]); bsplit(xv.y, hh[1], ll[1]);
            bsplit(xv.z, hh[2], ll[2]); bsplit(xv.w, hh[3], ll[3]);
            *(short4v*)&L16[XH_U + r * 40 + k4] =
                (short4v){(short)hh[0], (short)hh[1], (short)hh[2], (short)hh[3]};
            *(short4v*)&L16[XL_U + r * 40 + k4] =
                (short4v){(short)ll[0], (short)ll[1], (short)ll[2], (short)ll[3]};
        }
        for (int i = tid; i < 2048; i += 512) {           // wq: 32k x 64c
            const int c = i & 63, kk = i >> 6;
            float wvv = wq[(size_t)(k0 + kk) * 512 + h * 64 + c];
            unsigned short hh, ll;
            bsplit(wvv, hh, ll);
            const int kks = (kk & 7) | ((((kk >> 3) ^ ((c >> 3) & 3))) << 3);
            L16[W0H_U + c * 40 + kks] = hh;
            L16[W0L_U + c * 40 + kks] = ll;
        }
        __syncthreads();
        {
            short8v bhq = *(const short8v*)&L16[W0H_U + bOff];
            short8v blq = *(const short8v*)&L16[W0L_U + bOff];
#pragma unroll
            for (int i = 0; i < 3; ++i) {
                if (i < nTiles) {
                    const int ar = (mtw + 2 * i) * 16 + Lr;
                    short8v ah = *(const short8v*)&L16[XH_U + ar * 40 + Lg * 8];
                    short8v al = *(const short8v*)&L16[XL_U + ar * 40 + Lg * 8];
                    accQ[i] = __builtin_amdgcn_mfma_f32_16x16x32_bf16(
                        ah, bhq, accQ[i], 0, 0, 0);
                    accQ[i] = __builtin_amdgcn_mfma_f32_16x16x32_bf16(
                        ah, blq, accQ[i], 0, 0, 0);
                    accQ[i] = __builtin_amdgcn_mfma_f32_16x16x32_bf16(
                        al, bhq, accQ[i], 0, 0, 0);
                }
            }
        }

        // ---- sub-pass B: stage xkv + wk + wv, mfma K,V ----
        __syncthreads();
        for (int i = tid; i < 640; i += 512) {
            const int r = i >> 3, k4 = (i & 7) << 2;
            float4 xv = {0.f, 0.f, 0.f, 0.f};
            if (r < 79) xv = *(const float4*)&xkb[(size_t)r * 512 + k0 + k4];
            unsigned short hh[4], ll[4];
            bsplit(xv.x, hh[0], ll[0]); bsplit(xv.y, hh[1], ll[1]);
            bsplit(xv.z, hh[2], ll[2]); bsplit(xv.w, hh[3], ll[3]);
            *(short4v*)&L16[XH_U + r * 40 + k4] =
                (short4v){(short)hh[0], (short)hh[1], (short)hh[2], (short)hh[3]};
            *(short4v*)&L16[XL_U + r * 40 + k4] =
                (short4v){(short)ll[0], (short)ll[1], (short)ll[2], (short)ll[3]};
        }
        for (int i = tid; i < 4096; i += 512) {           // wk then wv
            const int c = i & 63, kk = (i >> 6) & 31, m = i >> 11;
            const float* wp = m ? wv : wk;
            float wvv = wp[(size_t)(k0 + kk) * 512 + h * 64 + c];
            unsigned short hh, ll;
            bsplit(wvv, hh, ll);
            const int kks = (kk & 7) | ((((kk >> 3) ^ ((c >> 3) & 3))) << 3);
            const unsigned base_h = m ? W1H_U : W0H_U;
            const unsigned base_l = m ? W1L_U : W0L_U;
            L16[base_h + c * 40 + kks] = hh;
            L16[base_l + c * 40 + kks] = ll;
        }
        __syncthreads();
        {
            short8v bhk = *(const short8v*)&L16[W0H_U + bOff];
            short8v blk = *(const short8v*)&L16[W0L_U + bOff];
            short8v bhv = *(const short8v*)&L16[W1H_U + bOff];
            short8v blv = *(const short8v*)&L16[W1L_U + bOff];
#pragma unroll
            for (int i = 0; i < 3; ++i) {
                if (i < nTiles) {
                    const int ar = (mtw + 2 * i) * 16 + Lr;
                    short8v ah = *(const short8v*)&L16[XH_U + ar * 40 + Lg * 8];
                    short8v al = *(const short8v*)&L16[XL_U + ar * 40 + Lg * 8];
                    accK[i] = __builtin_amdgcn_mfma_f32_16x16x32_bf16(
                        ah, bhk, accK[i], 0, 0, 0);
                    accK[i] = __builtin_amdgcn_mfma_f32_16x16x32_bf16(
                        ah, blk, accK[i], 0, 0, 0);
                    accK[i] = __builtin_amdgcn_mfma_f32_16x16x32_bf16(
                        al, bhk, accK[i], 0, 0, 0);
                    accV[i] = __builtin_amdgcn_mfma_f32_16x16x32_bf16(
                        ah, bhv, accV[i], 0, 0, 0);
                    accV[i] = __builtin_amdgcn_mfma_f32_16x16x32_bf16(
                        ah, blv, accV[i], 0, 0, 0);
                    accV[i] = __builtin_amdgcn_mfma_f32_16x16x32_bf16(
                        al, bhv, accV[i], 0, 0, 0);
                }
            }
        }
    }
    __syncthreads();   // staging dead; write q,k into same region

    // C layout: row = (lane>>4)*4 + reg, col = lane&15 (within tile)
#pragma unroll
    for (int i = 0; i < 3; ++i) {
        if (i < nTiles) {
            const int rb = (mtw + 2 * i) * 16 + Lg * 4;
            const int cc = ntw * 16 + Lr;
#pragma unroll
            for (int r = 0; r < 4; ++r) {
                const int row = rb + r;
                if (row < 79) {
                    qSf[row * 68 + cc] = accQ[i][r];
                    kSf[row * 68 + cc] = accK[i][r];
                }
            }
        }
    }
    __syncthreads();

    // ---------------- phase 3: scores + precomputed logits ----------------
    const __hip_bfloat16* lgp = lgB + (size_t)(bl * 8 + h) * 6241;
    for (int idx = tid; idx < 6241; idx += 512) {
        const int t = idx / 79, T = idx - t * 79;
        float qx = 0.f, qy = 0.f, qz = 0.f, qw2 = 0.f;
#pragma unroll
        for (int d4 = 0; d4 < 64; d4 += 4) {
            const float4 qv = *(const float4*)&qSf[t * 68 + d4];
            const float4 kv = *(const float4*)&kSf[T * 68 + d4];
            qx = fmaf(qv.x, kv.x, qx);
            qy = fmaf(qv.y, kv.y, qy);
            qz = fmaf(qv.z, kv.z, qz);
            qw2 = fmaf(qv.w, kv.w, qw2);
        }
        const float qk = (qx + qy) + (qz + qw2);
        scLg[t * 80 + T] = qk * 0.125f + __bfloat162float(lgp[idx]);
    }
    __syncthreads();   // qS reads done -> region0 free for vST

    // vST fill from accV regs (vST[d][T], stride 84) + softmax
#pragma unroll
    for (int i = 0; i < 3; ++i) {
        if (i < nTiles) {
            const int rb = (mtw + 2 * i) * 16 + Lg * 4;
            const int cc = ntw * 16 + Lr;
#pragma unroll
            for (int r = 0; r < 4; ++r) {
                const int row = rb + r;      // T index
                if (row < 79) vSTf[cc * 84 + row] = accV[i][r];
            }
        }
    }

    for (int t = w; t < 79; t += 8) {
        const float v1 = scLg[t * 80 + lane];
        const float v2 = (lane < 15) ? scLg[t * 80 + lane + 64] : -3.0e38f;
        float m = fmaxf(v1, v2);
#pragma unroll
        for (int off = 32; off; off >>= 1)
            m = fmaxf(m, __shfl_xor(m, off));
        float e1 = __expf(v1 - m);
        float e2 = (lane < 15) ? __expf(v2 - m) : 0.f;
        float z = e1 + e2;
#pragma unroll
        for (int off = 32; off; off >>= 1)
            z += __shfl_xor(z, off);
        const float rz = 1.f / z;
        scLg[t * 80 + lane] = e1 * rz;
        if (lane < 15) scLg[t * 80 + lane + 64] = e2 * rz;
    }
    __syncthreads();

    // ---------------- phase 5: PV -> OUT_BF16 ----------------
#pragma unroll
    for (int k = 0; k < 10; ++k) {
        const int t = w + 8 * k;
        if (t < 79) {
            float ox = 0.f, oy = 0.f, oz = 0.f, ow = 0.f;
#pragma unroll
            for (int T4 = 0; T4 < 76; T4 += 4) {
                const float4 p = *(const float4*)&scLg[t * 80 + T4];
                const float4 vv = *(const float4*)&vSTf[lane * 84 + T4];
                ox = fmaf(p.x, vv.x, ox);
                oy = fmaf(p.y, vv.y, oy);
                oz = fmaf(p.z, vv.z, oz);
                ow = fmaf(p.w, vv.w, ow);
            }
            float o = (ox + oy) + (oz + ow);
            o = fmaf(scLg[t * 80 + 76], vSTf[lane * 84 + 76], o);
            o = fmaf(scLg[t * 80 + 77], vSTf[lane * 84 + 77], o);
            o = fmaf(scLg[t * 80 + 78], vSTf[lane * 84 + 78], o);
            outB[((size_t)b * 79 + t) * 512 + h * 64 + lane] = __float2bfloat16(o);
        }
    }
}

// ---------------------------------------------------------------------------
// gemm_out_k: C[r,:] = A_bf16[r,:] @ wo, rows r in [M0,M1). Tiled 64x64.
// In-place over d_out via the halving ladder (see kernel_launch).
// ---------------------------------------------------------------------------
__global__ __launch_bounds__(256) void gemm_out_k(
    const unsigned short* __restrict__ A, const float* __restrict__ W,
    float* __restrict__ C, int M0, int M1)
{
    __shared__ __attribute__((aligned(16))) float As[16][64];
    __shared__ __attribute__((aligned(16))) float Bs[16][64];

    const int tid = threadIdx.x;
    const int tx = tid & 15, ty = tid >> 4;
    const int row0 = M0 + blockIdx.y * 64, col0 = blockIdx.x * 64;
    const int lr = tid >> 2, lk = (tid & 3) * 4;
    const int bkk = tid >> 4, bc = (tid & 15) * 4;

    int ar = row0 + lr; if (ar > M1 - 1) ar = M1 - 1;

    float acc[4][4];
#pragma unroll
    for (int i = 0; i < 4; ++i)
#pragma unroll
        for (int j = 0; j < 4; ++j) acc[i][j] = 0.f;

    for (int k0 = 0; k0 < 512; k0 += 16) {
        const uint2 u = *(const uint2*)(A + (size_t)ar * 512 + k0 + lk);
        float a0 = __uint_as_float((u.x & 0xffffu) << 16);
        float a1 = __uint_as_float(u.x & 0xffff0000u);
        float a2 = __uint_as_float((u.y & 0xffffu) << 16);
        float a3 = __uint_as_float(u.y & 0xffff0000u);
        float4 bv = *(const float4*)&W[(size_t)(k0 + bkk) * 512 + col0 + bc];

        __syncthreads();
        As[lk + 0][lr] = a0; As[lk + 1][lr] = a1;
        As[lk + 2][lr] = a2; As[lk + 3][lr] = a3;
        *(float4*)&Bs[bkk][bc] = bv;
        __syncthreads();

#pragma unroll
        for (int kk = 0; kk < 16; ++kk) {
            float4 a4 = *(const float4*)&As[kk][ty * 4];
            float4 b4 = *(const float4*)&Bs[kk][tx * 4];
            float a[4] = {a4.x, a4.y, a4.z, a4.w};
            float bb[4] = {b4.x, b4.y, b4.z, b4.w};
#pragma unroll
            for (int i = 0; i < 4; ++i)
#pragma unroll
                for (int j = 0; j < 4; ++j)
                    acc[i][j] = fmaf(a[i], bb[j], acc[i][j]);
        }
    }

#pragma unroll
    for (int i = 0; i < 4; ++i) {
        const int r = row0 + ty * 4 + i;
        if (r < M1) {
#pragma unroll
            for (int j = 0; j < 4; ++j)
                C[(size_t)r * 512 + col0 + tx * 4 + j] = acc[i][j];
        }
    }
}

// ---------------------------------------------------------------------------
extern "C" void kernel_launch(void* const* d_in, const int* in_sizes, int n_in,
                              void* d_out, int out_size, void* d_ws, size_t ws_size,
                              hipStream_t stream) {
    const float* xq    = (const float*)d_in[0];
    const float* xkv   = (const float*)d_in[1];
    const float* wq    = (const float*)d_in[2];
    const float* wk    = (const float*)d_in[3];
    const float* wv    = (const float*)d_in[4];
    const float* wo    = (const float*)d_in[5];
    const float* sp_w  = (const float*)d_in[6];
    const float* sp_b  = (const float*)d_in[7];
    const float* c0w   = (const float*)d_in[8];
    const float* c0b   = (const float*)d_in[9];
    const float* c1w   = (const float*)d_in[10];
    const float* c1b   = (const float*)d_in[11];
    const float* g1w   = (const float*)d_in[12];
    const float* g1b   = (const float*)d_in[13];
    const float* g2w   = (const float*)d_in[14];
    const float* g2b   = (const float*)d_in[15];
    const float* sumw  = (const float*)d_in[16];
    const float* sumb  = (const float*)d_in[17];
    const float* headw = (const float*)d_in[18];
    const float* headb = (const float*)d_in[19];
    const float* sproj = (const float*)d_in[20];
    float* out = (float*)d_out;

    // d_ws unusable in this harness (R1-R3 faulted on first touch; R4+ pass
    // with zero workspace). All intermediates live inside d_out (layout top).
    (void)d_ws; (void)ws_size; (void)in_sizes; (void)n_in; (void)out_size;

    __hip_bfloat16* outB = (__hip_bfloat16*)out;
    __hip_bfloat16* lgB  = (__hip_bfloat16*)(out + LG_OFF);
    float* hsF = out + HS_OFF;

    smolgen_k<<<B_, 256, 0, stream>>>(xq, sp_w, sp_b, c0w, c0b, c1w, c1b,
                                      g1w, g1b, g2w, g2b, sumw, sumb,
                                      headw, headb, hsF);

    for (int half = 0; half < 2; ++half) {
        const float* Ahs = hsF + (size_t)half * 4096 * 128;
        lgemm_k<<<dim3(98, 64), 256, 0, stream>>>(Ahs, sproj, lgB);
        attn_half_k<<<4096, 512, 0, stream>>>(xq, xkv, wq, wk, wv,
                                              lgB, outB, half * 512);
    }

    // In-place output projection: halving ladder. Pass [lo,hi) writes fp32
    // rows [lo,hi), overwriting bf16 rows [2lo,2hi); lo=ceil(hi/2) => safe.
    int hi = B_ * S_;
    while (hi > 0) {
        int lo = (hi + 1) >> 1;
        if (lo == hi) lo = hi - 1;
        gemm_out_k<<<dim3(8, (hi - lo + 63) / 64), 256, 0, stream>>>(
            (const unsigned short*)outB, wo, out, lo, hi);
        hi = lo;
    }
}

// Round 8
// 3875.117 us; speedup vs baseline: 10.3222x; 1.1856x over previous
//
#include <hip/hip_runtime.h>
#include <hip/hip_bf16.h>

#define B_   1024
#define S_   79
#define E_   512
#define H_   8
#define D_   64
#define LDX  (S_*E_)      // 40448
#define NROW 80896        // B_*S_

// d_out float layout (total 41,418,752 floats):
//   [0        : 12781568)  LG_BF16 : half-batch logits, 4096x6241 bf16
//   [12781568 : 13830144)  HS_F32  : smolgen hs, 8192x128 fp32
//   [13830144 : 14616576)  WSP     : wq/wk/wv bf16 hi/lo splits (ushorts)
//   [20709376 : 41418752)  AO_BF16 : attn output, 80896x512 bf16 (top half)
// gemm_out overwrites everything with fp32 output via ascending ladder.
#define HS_OFF  12781568u
#define WSP_OFF 13830144u
#define AO_OFF  20709376u

typedef __attribute__((ext_vector_type(8))) short short8v;   // 8 bf16
typedef __attribute__((ext_vector_type(4))) short short4v;
typedef __attribute__((ext_vector_type(4))) float f32x4;

__device__ __forceinline__ float silu_f(float s) {
    return s / (1.f + __expf(-s));
}

// RNE fp32 -> bf16 split: x ~= hi + lo (both bf16).
__device__ __forceinline__ void bsplit(float x, unsigned short& h,
                                       unsigned short& l) {
    unsigned u = __float_as_uint(x);
    unsigned hr = (u + 0x7fffu + ((u >> 16) & 1u)) >> 16;
    h = (unsigned short)hr;
    float r = x - __uint_as_float(hr << 16);
    unsigned u2 = __float_as_uint(r);
    l = (unsigned short)((u2 + 0x7fffu + ((u2 >> 16) & 1u)) >> 16);
}

// ---------------------------------------------------------------------------
// presplit_k: wq/wk/wv -> bf16 hi/lo in B-fragment layout:
//   wsp[m*524288 + (k>>5)*32768 + col*64 + {hi:0|lo:32} + (k&31)]
// Fragment read = 16B at col*64 + Lg*8 (+32 for lo). One-time, 786K threads.
// ---------------------------------------------------------------------------
__global__ __launch_bounds__(256) void presplit_k(
    const float* __restrict__ wq, const float* __restrict__ wk,
    const float* __restrict__ wv, unsigned short* __restrict__ wsp)
{
    const int idx = blockIdx.x * 256 + threadIdx.x;   // < 786432
    const int m = idx >> 18;
    const int r = idx & 262143;
    const int k = r >> 9, c = r & 511;
    const float* w = (m == 0) ? wq : (m == 1) ? wk : wv;
    unsigned short hh, ll;
    bsplit(w[(size_t)k * 512 + c], hh, ll);
    const size_t base = (size_t)m * 524288 + (size_t)(k >> 5) * 32768
                      + (size_t)c * 64 + (k & 31);
    wsp[base]      = hh;
    wsp[base + 32] = ll;
}

// ---------------------------------------------------------------------------
// smolgen_k: one block per batch. Full smolgen chain -> hs[b*1024 + h*128+i]
// ---------------------------------------------------------------------------
__global__ __launch_bounds__(256) void smolgen_k(
    const float* __restrict__ xq,
    const float* __restrict__ sp_w, const float* __restrict__ sp_b,
    const float* __restrict__ c0w, const float* __restrict__ c0b,
    const float* __restrict__ c1w, const float* __restrict__ c1b,
    const float* __restrict__ g1w, const float* __restrict__ g1b,
    const float* __restrict__ g2w, const float* __restrict__ g2b,
    const float* __restrict__ sumw, const float* __restrict__ sumb,
    const float* __restrict__ headw, const float* __restrict__ headb,
    float* __restrict__ hsF)
{
    const int b = blockIdx.x, tid = threadIdx.x;
    __shared__ __attribute__((aligned(16))) float h0[64][16];
    __shared__ __attribute__((aligned(16))) float out2[64][32];
    __shared__ float red[8][32];
    __shared__ float part[16][16];
    __shared__ float gpart[4][64];
    __shared__ float comb[80];
    __shared__ float psS[128];

    const float* xb = xq + (size_t)b * LDX;

    {
        const int o = tid & 15, p = tid >> 4;
        float s = 0.f;
        for (int c = p * 32; c < p * 32 + 32; ++c)
            s = fmaf(xb[c], sp_w[(size_t)c * 16 + o], s);
        part[p][o] = s;
    }

    {
        const int px = tid >> 2, j = tid & 3;
        const int py = px >> 3, pxx = px & 7;
        float acc[4];
#pragma unroll
        for (int i = 0; i < 4; ++i) acc[i] = c0b[j * 4 + i];
        for (int ky = 0; ky < 3; ++ky) {
            const int yy = py + ky - 1;
            if (yy < 0 || yy > 7) continue;
            for (int kx = 0; kx < 3; ++kx) {
                const int xx2 = pxx + kx - 1;
                if (xx2 < 0 || xx2 > 7) continue;
                const float* xr = xb + (size_t)(1 + yy * 8 + xx2) * 512;
                const float* wr = c0w + (size_t)(ky * 3 + kx) * 512 * 16 + j * 4;
                for (int c = 0; c < 512; ++c) {
                    const float xv = xr[c];
                    float4 wv4 = *(const float4*)(wr + (size_t)c * 16);
                    acc[0] = fmaf(xv, wv4.x, acc[0]);
                    acc[1] = fmaf(xv, wv4.y, acc[1]);
                    acc[2] = fmaf(xv, wv4.z, acc[2]);
                    acc[3] = fmaf(xv, wv4.w, acc[3]);
                }
            }
        }
#pragma unroll
        for (int i = 0; i < 4; ++i) h0[px][j * 4 + i] = fmaxf(acc[i], 0.f);
    }

    {
        const int o = tid & 63, p = tid >> 6;
        const float* gx = xb + 65 * 512 + p * 1792;
        float s = 0.f;
        for (int gi = 0; gi < 1792; ++gi)
            s = fmaf(gx[gi], g1w[(size_t)(p * 1792 + gi) * 64 + o], s);
        gpart[p][o] = s;
    }
    __syncthreads();

    if (tid < 16) {
        float s = sp_b[tid];
#pragma unroll
        for (int p = 0; p < 16; ++p) s += part[p][tid];
        comb[tid] = fmaxf(s, 0.f);
    }

    {
        const int px = tid >> 2, j = tid & 3;
        const int py = px >> 3, pxx = px & 7;
        float acc[8];
#pragma unroll
        for (int i = 0; i < 8; ++i) acc[i] = c1b[j * 8 + i];
        for (int ky = 0; ky < 3; ++ky) {
            const int yy = py + ky - 1;
            if (yy < 0 || yy > 7) continue;
            for (int kx = 0; kx < 3; ++kx) {
                const int xx2 = pxx + kx - 1;
                if (xx2 < 0 || xx2 > 7) continue;
                const float* hr = &h0[yy * 8 + xx2][0];
                const float* wr = c1w + (size_t)(ky * 3 + kx) * 16 * 32 + j * 8;
#pragma unroll
                for (int c = 0; c < 16; ++c) {
                    const float hv = hr[c];
#pragma unroll
                    for (int i = 0; i < 8; ++i)
                        acc[i] = fmaf(hv, wr[c * 32 + i], acc[i]);
                }
            }
        }
#pragma unroll
        for (int i = 0; i < 8; ++i) out2[px][j * 8 + i] = fmaxf(acc[i], 0.f);
    }
    __syncthreads();

    if (tid < 64) {
        float s = g1b[tid];
#pragma unroll
        for (int p = 0; p < 4; ++p) s += gpart[p][tid];
        gpart[0][tid] = fmaxf(s, 0.f);
    }
    {
        const int co = tid & 31, ch = tid >> 5;
        float s = 0.f;
#pragma unroll
        for (int p = ch * 8; p < ch * 8 + 8; ++p) s += out2[p][co];
        red[ch][co] = s;
    }
    __syncthreads();

    if (tid < 32) {
        float t = 0.f;
#pragma unroll
        for (int c2 = 0; c2 < 8; ++c2) t += red[c2][tid];
        comb[16 + tid] = t * (1.f / 64.f);
    }
    if (tid >= 64 && tid < 96) {
        const int o = tid - 64;
        float s = g2b[o];
#pragma unroll
        for (int c = 0; c < 64; ++c)
            s = fmaf(gpart[0][c], g2w[c * 32 + o], s);
        comb[48 + o] = fmaxf(s, 0.f);
    }
    __syncthreads();

    if (tid < 128) {
        float s = sumb[tid];
#pragma unroll
        for (int c = 0; c < 80; ++c)
            s = fmaf(comb[c], sumw[(size_t)c * 128 + tid], s);
        psS[tid] = silu_f(s);
    }
    __syncthreads();

#pragma unroll
    for (int r = 0; r < 4; ++r) {
        const int o = tid + 256 * r;          // h*128 + i
        const int h = o >> 7, i = o & 127;
        float s = headb[o];
        const float* wr = headw + (size_t)h * 128 * 128 + i;
        float s0 = 0.f, s1 = 0.f, s2 = 0.f, s3 = 0.f;
#pragma unroll
        for (int c = 0; c < 128; c += 4) {
            s0 = fmaf(psS[c + 0], wr[(size_t)(c + 0) * 128], s0);
            s1 = fmaf(psS[c + 1], wr[(size_t)(c + 1) * 128], s1);
            s2 = fmaf(psS[c + 2], wr[(size_t)(c + 2) * 128], s2);
            s3 = fmaf(psS[c + 3], wr[(size_t)(c + 3) * 128], s3);
        }
        s += (s0 + s1) + (s2 + s3);
        hsF[(size_t)b * 1024 + o] = silu_f(s);
    }
}

// ---------------------------------------------------------------------------
// lgemm: C[4096,6241](bf16) = A[4096,128](f32) @ sproj[128,6241]. Tiled 64x64.
// ---------------------------------------------------------------------------
__global__ __launch_bounds__(256) void lgemm_k(
    const float* __restrict__ A, const float* __restrict__ W,
    __hip_bfloat16* __restrict__ C)
{
    __shared__ __attribute__((aligned(16))) float As[16][64];
    __shared__ __attribute__((aligned(16))) float Bs[16][64];

    const int tid = threadIdx.x;
    const int tx = tid & 15, ty = tid >> 4;
    const int row0 = blockIdx.y * 64, col0 = blockIdx.x * 64;
    const int lr = tid >> 2, lk = (tid & 3) * 4;
    const int bkk = tid >> 4, bc = (tid & 15) * 4;

    float acc[4][4];
#pragma unroll
    for (int i = 0; i < 4; ++i)
#pragma unroll
        for (int j = 0; j < 4; ++j) acc[i][j] = 0.f;

    for (int k0 = 0; k0 < 128; k0 += 16) {
        float4 av = *(const float4*)(A + (size_t)(row0 + lr) * 128 + k0 + lk);
        float4 bv;
        const float* wp = W + (size_t)(k0 + bkk) * 6241 + col0 + bc;
        const int cb = col0 + bc;
        bv.x = (cb + 0 < 6241) ? wp[0] : 0.f;
        bv.y = (cb + 1 < 6241) ? wp[1] : 0.f;
        bv.z = (cb + 2 < 6241) ? wp[2] : 0.f;
        bv.w = (cb + 3 < 6241) ? wp[3] : 0.f;

        __syncthreads();
        As[lk + 0][lr] = av.x; As[lk + 1][lr] = av.y;
        As[lk + 2][lr] = av.z; As[lk + 3][lr] = av.w;
        *(float4*)&Bs[bkk][bc] = bv;
        __syncthreads();

#pragma unroll
        for (int kk = 0; kk < 16; ++kk) {
            float4 a4 = *(const float4*)&As[kk][ty * 4];
            float4 b4 = *(const float4*)&Bs[kk][tx * 4];
            float a[4] = {a4.x, a4.y, a4.z, a4.w};
            float bb[4] = {b4.x, b4.y, b4.z, b4.w};
#pragma unroll
            for (int i = 0; i < 4; ++i)
#pragma unroll
                for (int j = 0; j < 4; ++j)
                    acc[i][j] = fmaf(a[i], bb[j], acc[i][j]);
        }
    }

#pragma unroll
    for (int i = 0; i < 4; ++i) {
        const int r = row0 + ty * 4 + i;
#pragma unroll
        for (int j = 0; j < 4; ++j) {
            const int c = col0 + tx * 4 + j;
            if (c < 6241)
                C[(size_t)r * 6241 + c] = __float2bfloat16(acc[i][j]);
        }
    }
}

// ---------------------------------------------------------------------------
// attn_half_k v4: one block per (b,h), 512 threads (8 waves).
// phase1: QKV via split-bf16 MFMA; B-frags loaded directly from global wsp
// (pre-split, L2-resident) — no weight staging, no weight bank conflicts.
// phases 3-5 as in R7 (validated).
// ---------------------------------------------------------------------------
#define QS_OFF  0u
#define KS_OFF  21760u
#define SC_OFF  43520u
#define XH_U   0u
#define XL_U   3200u

__global__ __launch_bounds__(512, 4) void attn_half_k(
    const float* __restrict__ xq, const float* __restrict__ xkv,
    const unsigned short* __restrict__ wsp,
    const __hip_bfloat16* __restrict__ lgB,
    __hip_bfloat16* __restrict__ outB, int b0)
{
    const int bh = blockIdx.x;
    const int bl = bh >> 3, h = bh & 7;
    const int b = b0 + bl;
    const int tid = threadIdx.x;
    const int lane = tid & 63, w = tid >> 6;

    __shared__ __attribute__((aligned(16))) unsigned char Lds[68800];
    unsigned short* L16 = (unsigned short*)Lds;
    float* qSf = (float*)(Lds + QS_OFF);
    float* kSf = (float*)(Lds + KS_OFF);
    float* scLg = (float*)(Lds + SC_OFF);
    float* vSTf = (float*)(Lds + QS_OFF);   // after phase3

    const float* xqb = xq + (size_t)b * LDX;
    const float* xkb = xkv + (size_t)b * LDX;

    const int Lr = lane & 15, Lg = lane >> 4;
    const int ntw = w & 3;
    const int mtw = w >> 2;
    const int nTiles = (w < 4) ? 3 : 2;
    const int cB = ntw * 16 + Lr;              // local col 0..63
    const size_t wCol = (size_t)(h * 64 + cB) * 64 + Lg * 8;

    f32x4 accQ[3], accK[3], accV[3];
#pragma unroll
    for (int i = 0; i < 3; ++i) {
        accQ[i] = (f32x4){0.f, 0.f, 0.f, 0.f};
        accK[i] = (f32x4){0.f, 0.f, 0.f, 0.f};
        accV[i] = (f32x4){0.f, 0.f, 0.f, 0.f};
    }

    for (int ch = 0; ch < 16; ++ch) {
        const int k0 = ch * 32;
        const size_t wOff = (size_t)ch * 32768 + wCol;

        // ---- sub-pass A: stage xq, mfma Q (B-frags from global) ----
        short8v bhq = *(const short8v*)&wsp[wOff];
        short8v blq = *(const short8v*)&wsp[wOff + 32];
        __syncthreads();
        for (int i = tid; i < 640; i += 512) {
            const int r = i >> 3, k4 = (i & 7) << 2;
            float4 xv = {0.f, 0.f, 0.f, 0.f};
            if (r < 79) xv = *(const float4*)&xqb[(size_t)r * 512 + k0 + k4];
            unsigned short hh[4], ll[4];
            bsplit(xv.x, hh[0], ll[0]); bsplit(xv.y, hh[1], ll[1]);
            bsplit(xv.z, hh[2], ll[2]); bsplit(xv.w, hh[3], ll[3]);
            *(short4v*)&L16[XH_U + r * 40 + k4] =
                (short4v){(short)hh[0], (short)hh[1], (short)hh[2], (short)hh[3]};
            *(short4v*)&L16[XL_U + r * 40 + k4] =
                (short4v){(short)ll[0], (short)ll[1], (short)ll[2], (short)ll[3]};
        }
        __syncthreads();
#pragma unroll
        for (int i = 0; i < 3; ++i) {
            if (i < nTiles) {
                const int ar = (mtw + 2 * i) * 16 + Lr;
                short8v ah = *(const short8v*)&L16[XH_U + ar * 40 + Lg * 8];
                short8v al = *(const short8v*)&L16[XL_U + ar * 40 + Lg * 8];
                accQ[i] = __builtin_amdgcn_mfma_f32_16x16x32_bf16(
                    ah, bhq, accQ[i], 0, 0, 0);
                accQ[i] = __builtin_amdgcn_mfma_f32_16x16x32_bf16(
                    ah, blq, accQ[i], 0, 0, 0);
                accQ[i] = __builtin_amdgcn_mfma_f32_16x16x32_bf16(
                    al, bhq, accQ[i], 0, 0, 0);
            }
        }

        // ---- sub-pass B: stage xkv, mfma K,V ----
        short8v bhk = *(const short8v*)&wsp[524288 + wOff];
        short8v blk = *(const short8v*)&wsp[524288 + wOff + 32];
        short8v bhv = *(const short8v*)&wsp[1048576 + wOff];
        short8v blv = *(const short8v*)&wsp[1048576 + wOff + 32];
        __syncthreads();
        for (int i = tid; i < 640; i += 512) {
            const int r = i >> 3, k4 = (i & 7) << 2;
            float4 xv = {0.f, 0.f, 0.f, 0.f};
            if (r < 79) xv = *(const float4*)&xkb[(size_t)r * 512 + k0 + k4];
            unsigned short hh[4], ll[4];
            bsplit(xv.x, hh[0], ll[0]); bsplit(xv.y, hh[1], ll[1]);
            bsplit(xv.z, hh[2], ll[2]); bsplit(xv.w, hh[3], ll[3]);
            *(short4v*)&L16[XH_U + r * 40 + k4] =
                (short4v){(short)hh[0], (short)hh[1], (short)hh[2], (short)hh[3]};
            *(short4v*)&L16[XL_U + r * 40 + k4] =
                (short4v){(short)ll[0], (short)ll[1], (short)ll[2], (short)ll[3]};
        }
        __syncthreads();
#pragma unroll
        for (int i = 0; i < 3; ++i) {
            if (i < nTiles) {
                const int ar = (mtw + 2 * i) * 16 + Lr;
                short8v ah = *(const short8v*)&L16[XH_U + ar * 40 + Lg * 8];
                short8v al = *(const short8v*)&L16[XL_U + ar * 40 + Lg * 8];
                accK[i] = __builtin_amdgcn_mfma_f32_16x16x32_bf16(
                    ah, bhk, accK[i], 0, 0, 0);
                accK[i] = __builtin_amdgcn_mfma_f32_16x16x32_bf16(
                    ah, blk, accK[i], 0, 0, 0);
                accK[i] = __builtin_amdgcn_mfma_f32_16x16x32_bf16(
                    al, bhk, accK[i], 0, 0, 0);
                accV[i] = __builtin_amdgcn_mfma_f32_16x16x32_bf16(
                    ah, bhv, accV[i], 0, 0, 0);
                accV[i] = __builtin_amdgcn_mfma_f32_16x16x32_bf16(
                    ah, blv, accV[i], 0, 0, 0);
                accV[i] = __builtin_amdgcn_mfma_f32_16x16x32_bf16(
                    al, bhv, accV[i], 0, 0, 0);
            }
        }
    }
    __syncthreads();   // staging dead; write q,k into same region

    // C layout: row = Lg*4 + reg, col = Lr (validated R7)
#pragma unroll
    for (int i = 0; i < 3; ++i) {
        if (i < nTiles) {
            const int rb = (mtw + 2 * i) * 16 + Lg * 4;
            const int cc = ntw * 16 + Lr;
#pragma unroll
            for (int r = 0; r < 4; ++r) {
                const int row = rb + r;
                if (row < 79) {
                    qSf[row * 68 + cc] = accQ[i][r];
                    kSf[row * 68 + cc] = accK[i][r];
                }
            }
        }
    }
    __syncthreads();

    // ---------------- phase 3: scores + precomputed logits ----------------
    const __hip_bfloat16* lgp = lgB + (size_t)(bl * 8 + h) * 6241;
    for (int idx = tid; idx < 6241; idx += 512) {
        const int t = idx / 79, T = idx - t * 79;
        float qx = 0.f, qy = 0.f, qz = 0.f, qw2 = 0.f;
#pragma unroll
        for (int d4 = 0; d4 < 64; d4 += 4) {
            const float4 qv = *(const float4*)&qSf[t * 68 + d4];
            const float4 kv = *(const float4*)&kSf[T * 68 + d4];
            qx = fmaf(qv.x, kv.x, qx);
            qy = fmaf(qv.y, kv.y, qy);
            qz = fmaf(qv.z, kv.z, qz);
            qw2 = fmaf(qv.w, kv.w, qw2);
        }
        const float qk = (qx + qy) + (qz + qw2);
        scLg[t * 80 + T] = qk * 0.125f + __bfloat162float(lgp[idx]);
    }
    __syncthreads();   // qS reads done -> region0 free for vST

#pragma unroll
    for (int i = 0; i < 3; ++i) {
        if (i < nTiles) {
            const int rb = (mtw + 2 * i) * 16 + Lg * 4;
            const int cc = ntw * 16 + Lr;
#pragma unroll
            for (int r = 0; r < 4; ++r) {
                const int row = rb + r;      // T index
                if (row < 79) vSTf[cc * 84 + row] = accV[i][r];
            }
        }
    }

    for (int t = w; t < 79; t += 8) {
        const float v1 = scLg[t * 80 + lane];
        const float v2 = (lane < 15) ? scLg[t * 80 + lane + 64] : -3.0e38f;
        float m = fmaxf(v1, v2);
#pragma unroll
        for (int off = 32; off; off >>= 1)
            m = fmaxf(m, __shfl_xor(m, off));
        float e1 = __expf(v1 - m);
        float e2 = (lane < 15) ? __expf(v2 - m) : 0.f;
        float z = e1 + e2;
#pragma unroll
        for (int off = 32; off; off >>= 1)
            z += __shfl_xor(z, off);
        const float rz = 1.f / z;
        scLg[t * 80 + lane] = e1 * rz;
        if (lane < 15) scLg[t * 80 + lane + 64] = e2 * rz;
    }
    __syncthreads();

    // ---------------- phase 5: PV -> AO_BF16 ----------------
#pragma unroll
    for (int k = 0; k < 10; ++k) {
        const int t = w + 8 * k;
        if (t < 79) {
            float ox = 0.f, oy = 0.f, oz = 0.f, ow = 0.f;
#pragma unroll
            for (int T4 = 0; T4 < 76; T4 += 4) {
                const float4 p = *(const float4*)&scLg[t * 80 + T4];
                const float4 vv = *(const float4*)&vSTf[lane * 84 + T4];
                ox = fmaf(p.x, vv.x, ox);
                oy = fmaf(p.y, vv.y, oy);
                oz = fmaf(p.z, vv.z, oz);
                ow = fmaf(p.w, vv.w, ow);
            }
            float o = (ox + oy) + (oz + ow);
            o = fmaf(scLg[t * 80 + 76], vSTf[lane * 84 + 76], o);
            o = fmaf(scLg[t * 80 + 77], vSTf[lane * 84 + 77], o);
            o = fmaf(scLg[t * 80 + 78], vSTf[lane * 84 + 78], o);
            outB[((size_t)b * 79 + t) * 512 + h * 64 + lane] = __float2bfloat16(o);
        }
    }
}

// ---------------------------------------------------------------------------
// gemm_out_mfma_k: C[r,:] = A_bf16[r,:] @ wo,  rows r in [M0,M1).
// Block = 128 rows x 32 cols, 4 waves (2M-groups x 2N-tiles).
// wo col-slice split hi/lo into LDS once per block; A staged per K-chunk.
// Writes happen ONLY in the epilogue (after all A reads) — this is what makes
// the in-place ascending ladder's final self-overwriting block safe.
// ---------------------------------------------------------------------------
__device__ __forceinline__ int swzA(int r, int g) {
    return g ^ (r & 3) ^ ((r >> 4) & 3);
}

__global__ __launch_bounds__(256) void gemm_out_mfma_k(
    const unsigned short* __restrict__ A, const float* __restrict__ wo,
    float* __restrict__ C, int M0, int M1)
{
    __shared__ unsigned short WoS[32768];          // [16ch][32c][hi32|lo32]
    __shared__ __attribute__((aligned(16))) unsigned short As[128 * 40];

    const int tid = threadIdx.x;
    const int c0 = blockIdx.x * 32;
    const int row0 = M0 + blockIdx.y * 128;
    const int lane = tid & 63, w = tid >> 6;
    const int Lr = lane & 15, Lg = lane >> 4;
    const int nt = w >> 1, mg = w & 1;
    const int cB = nt * 16 + Lr;

    // stage wo slice hi/lo (once per block), group-swizzled
    for (int i = tid; i < 16384; i += 256) {
        const int c = i & 31, k = i >> 5;
        unsigned short hh, ll;
        bsplit(wo[(size_t)k * 512 + c0 + c], hh, ll);
        const int ch = k >> 5, g = (k >> 3) & 3, e = k & 7;
        const int gs = g ^ (c & 3);
        WoS[ch * 2048 + c * 64 + (gs << 3) + e] = hh;
        WoS[ch * 2048 + c * 64 + 32 + (gs << 3) + e] = ll;
    }

    f32x4 acc[4];
#pragma unroll
    for (int i = 0; i < 4; ++i) acc[i] = (f32x4){0.f, 0.f, 0.f, 0.f};

    for (int ch = 0; ch < 16; ++ch) {
        const int k0 = ch * 32;
        __syncthreads();
        for (int i = tid; i < 512; i += 256) {
            const int r = i >> 2, g = i & 3;
            int ar = row0 + r; if (ar > M1 - 1) ar = M1 - 1;
            *(short8v*)&As[r * 40 + swzA(r, g) * 8] =
                *(const short8v*)&A[(size_t)ar * 512 + k0 + g * 8];
        }
        __syncthreads();
        const int wbase = ch * 2048 + cB * 64 + ((Lg ^ (cB & 3)) << 3);
        short8v bh = *(const short8v*)&WoS[wbase];
        short8v bl = *(const short8v*)&WoS[wbase + 32];
#pragma unroll
        for (int mt = 0; mt < 4; ++mt) {
            const int ar = mg * 64 + mt * 16 + Lr;
            short8v a = *(const short8v*)&As[ar * 40 + swzA(ar, Lg) * 8];
            acc[mt] = __builtin_amdgcn_mfma_f32_16x16x32_bf16(a, bh, acc[mt], 0, 0, 0);
            acc[mt] = __builtin_amdgcn_mfma_f32_16x16x32_bf16(a, bl, acc[mt], 0, 0, 0);
        }
    }

    // epilogue (all reads done)
#pragma unroll
    for (int mt = 0; mt < 4; ++mt) {
        const int rb = row0 + mg * 64 + mt * 16 + Lg * 4;
#pragma unroll
        for (int r = 0; r < 4; ++r) {
            const int row = rb + r;
            if (row < M1)
                C[(size_t)row * 512 + c0 + nt * 16 + Lr] = acc[mt][r];
        }
    }
}

// ---------------------------------------------------------------------------
extern "C" void kernel_launch(void* const* d_in, const int* in_sizes, int n_in,
                              void* d_out, int out_size, void* d_ws, size_t ws_size,
                              hipStream_t stream) {
    const float* xq    = (const float*)d_in[0];
    const float* xkv   = (const float*)d_in[1];
    const float* wq    = (const float*)d_in[2];
    const float* wk    = (const float*)d_in[3];
    const float* wv    = (const float*)d_in[4];
    const float* wo    = (const float*)d_in[5];
    const float* sp_w  = (const float*)d_in[6];
    const float* sp_b  = (const float*)d_in[7];
    const float* c0w   = (const float*)d_in[8];
    const float* c0b   = (const float*)d_in[9];
    const float* c1w   = (const float*)d_in[10];
    const float* c1b   = (const float*)d_in[11];
    const float* g1w   = (const float*)d_in[12];
    const float* g1b   = (const float*)d_in[13];
    const float* g2w   = (const float*)d_in[14];
    const float* g2b   = (const float*)d_in[15];
    const float* sumw  = (const float*)d_in[16];
    const float* sumb  = (const float*)d_in[17];
    const float* headw = (const float*)d_in[18];
    const float* headb = (const float*)d_in[19];
    const float* sproj = (const float*)d_in[20];
    float* out = (float*)d_out;

    // d_ws unusable in this harness (R1-R3 faulted on first touch; R4+ pass
    // with zero workspace). All intermediates live inside d_out.
    (void)d_ws; (void)ws_size; (void)in_sizes; (void)n_in; (void)out_size;

    __hip_bfloat16* lgB  = (__hip_bfloat16*)out;
    float* hsF           = out + HS_OFF;
    unsigned short* wsp  = (unsigned short*)(out + WSP_OFF);
    __hip_bfloat16* outB = (__hip_bfloat16*)(out + AO_OFF);

    presplit_k<<<3072, 256, 0, stream>>>(wq, wk, wv, wsp);
    smolgen_k<<<B_, 256, 0, stream>>>(xq, sp_w, sp_b, c0w, c0b, c1w, c1b,
                                      g1w, g1b, g2w, g2b, sumw, sumb,
                                      headw, headb, hsF);

    for (int half = 0; half < 2; ++half) {
        const float* Ahs = hsF + (size_t)half * 4096 * 128;
        lgemm_k<<<dim3(98, 64), 256, 0, stream>>>(Ahs, sproj, lgB);
        attn_half_k<<<4096, 512, 0, stream>>>(xq, xkv, wsp, lgB, outB,
                                              half * 512);
    }

    // In-place output projection, ascending doubling ladder.
    // Pass [lo,hi) writes fp32 rows [lo,hi) (floats [512lo,512hi)), which
    // destroys AO bf16 rows [2lo-80896, 2hi-80896) — exactly the previous
    // pass's reads. Final pass [80768,80896) self-overwrites its own 128-row
    // block only in the epilogue (after all its A reads). Pass 0 writes the
    // bottom half (LG/HS/WSP — all consumed) and destroys no AO.
    auto pass = [&](int lo, int hi) {
        gemm_out_mfma_k<<<dim3(16, (hi - lo + 127) / 128), 256, 0, stream>>>(
            (const unsigned short*)outB, wo, out, lo, hi);
    };
    pass(0, 40448);
    int lo = 40448;
    while (lo < NROW) {
        int hi = (NROW + lo) / 2;
        if (hi > 80768) hi = (lo < 80768) ? 80768 : NROW;
        pass(lo, hi);
        lo = hi;
    }
}

// Round 9
// 3477.639 us; speedup vs baseline: 11.5020x; 1.1143x over previous
//
#include <hip/hip_runtime.h>
#include <hip/hip_bf16.h>

#define B_   1024
#define S_   79
#define E_   512
#define H_   8
#define D_   64
#define LDX  (S_*E_)      // 40448
#define NROW 80896        // B_*S_

// d_out float layout (total 41,418,752 floats):
//   [0        : 12781568)  LG_BF16 : half-batch logits, 4096x6241 bf16
//   [12781568 : 13830144)  HS_F32  : smolgen hs, 8192x128 fp32
//   [13830144 : 14616576)  WSP     : wq/wk/wv bf16 hi/lo splits (ushorts)
//   [20709376 : 41418752)  AO_BF16 : attn output, 80896x512 bf16 (top half)
// gemm_out overwrites everything with fp32 output via ascending ladder.
#define HS_OFF  12781568u
#define WSP_OFF 13830144u
#define AO_OFF  20709376u

typedef __attribute__((ext_vector_type(8))) short short8v;   // 8 bf16
typedef __attribute__((ext_vector_type(4))) short short4v;
typedef __attribute__((ext_vector_type(4))) float f32x4;

__device__ __forceinline__ float silu_f(float s) {
    return s / (1.f + __expf(-s));
}

// RNE fp32 -> bf16 split: x ~= hi + lo (both bf16).
__device__ __forceinline__ void bsplit(float x, unsigned short& h,
                                       unsigned short& l) {
    unsigned u = __float_as_uint(x);
    unsigned hr = (u + 0x7fffu + ((u >> 16) & 1u)) >> 16;
    h = (unsigned short)hr;
    float r = x - __uint_as_float(hr << 16);
    unsigned u2 = __float_as_uint(r);
    l = (unsigned short)((u2 + 0x7fffu + ((u2 >> 16) & 1u)) >> 16);
}

// ---------------------------------------------------------------------------
// presplit_k: wq/wk/wv -> bf16 hi/lo in B-fragment layout:
//   wsp[m*524288 + (k>>5)*32768 + col*64 + {hi:0|lo:32} + (k&31)]
// ---------------------------------------------------------------------------
__global__ __launch_bounds__(256) void presplit_k(
    const float* __restrict__ wq, const float* __restrict__ wk,
    const float* __restrict__ wv, unsigned short* __restrict__ wsp)
{
    const int idx = blockIdx.x * 256 + threadIdx.x;   // < 786432
    const int m = idx >> 18;
    const int r = idx & 262143;
    const int k = r >> 9, c = r & 511;
    const float* w = (m == 0) ? wq : (m == 1) ? wk : wv;
    unsigned short hh, ll;
    bsplit(w[(size_t)k * 512 + c], hh, ll);
    const size_t base = (size_t)m * 524288 + (size_t)(k >> 5) * 32768
                      + (size_t)c * 64 + (k & 31);
    wsp[base]      = hh;
    wsp[base + 32] = ll;
}

// ---------------------------------------------------------------------------
// smolgen_k: one block per batch, 256 threads, ~123 KB LDS (1 block/CU).
// conv0 is LDS-staged: per 128-wide k-chunk, stage board x (64x130) and all
// 9 taps' weights (9x128x16), then FMA entirely from LDS.
// ---------------------------------------------------------------------------
__global__ __launch_bounds__(256) void smolgen_k(
    const float* __restrict__ xq,
    const float* __restrict__ sp_w, const float* __restrict__ sp_b,
    const float* __restrict__ c0w, const float* __restrict__ c0b,
    const float* __restrict__ c1w, const float* __restrict__ c1b,
    const float* __restrict__ g1w, const float* __restrict__ g1b,
    const float* __restrict__ g2w, const float* __restrict__ g2b,
    const float* __restrict__ sumw, const float* __restrict__ sumb,
    const float* __restrict__ headw, const float* __restrict__ headb,
    float* __restrict__ hsF)
{
    const int b = blockIdx.x, tid = threadIdx.x;
    __shared__ __attribute__((aligned(16))) float xS[64][130];   // 33.3 KB
    __shared__ __attribute__((aligned(16))) float wS[9][128][16];// 73.7 KB
    __shared__ __attribute__((aligned(16))) float h0[64][16];
    __shared__ __attribute__((aligned(16))) float out2[64][32];
    __shared__ float red[8][32];
    __shared__ float part[16][16];
    __shared__ float gpart[4][64];
    __shared__ float comb[80];
    __shared__ float psS[128];

    const float* xb = xq + (size_t)b * LDX;

    // ---------------- conv0 (LDS-staged) ----------------
    const int px = tid >> 2, j = tid & 3;
    const int py = px >> 3, pxx = px & 7;
    float acc0[4];
#pragma unroll
    for (int i = 0; i < 4; ++i) acc0[i] = c0b[j * 4 + i];

    for (int kc = 0; kc < 512; kc += 128) {
        __syncthreads();
        for (int i = tid; i < 2048; i += 256) {       // x: 64 r x 32 f4
            const int r = i >> 5, c4 = (i & 31) << 2;
            *(float4*)&xS[r][c4] =
                *(const float4*)&xb[(size_t)(1 + r) * 512 + kc + c4];
        }
        for (int i = tid; i < 4608; i += 256) {       // w: 9 x 128 x 4 f4
            const int tap = i / 512, rem = i - tap * 512;
            const int c = rem >> 2, co4 = (rem & 3) << 2;
            *(float4*)&wS[tap][c][co4] =
                *(const float4*)&c0w[(size_t)(tap * 512 + kc + c) * 16 + co4];
        }
        __syncthreads();
        for (int ky = 0; ky < 3; ++ky) {
            const int yy = py + ky - 1;
            if (yy < 0 || yy > 7) continue;
            for (int kx = 0; kx < 3; ++kx) {
                const int xx2 = pxx + kx - 1;
                if (xx2 < 0 || xx2 > 7) continue;
                const float* xr = &xS[yy * 8 + xx2][0];
                const float* wr = &wS[ky * 3 + kx][0][j * 4];
#pragma unroll 4
                for (int c = 0; c < 128; ++c) {
                    const float xv = xr[c];
                    const float4 w4 = *(const float4*)&wr[c * 16];
                    acc0[0] = fmaf(xv, w4.x, acc0[0]);
                    acc0[1] = fmaf(xv, w4.y, acc0[1]);
                    acc0[2] = fmaf(xv, w4.z, acc0[2]);
                    acc0[3] = fmaf(xv, w4.w, acc0[3]);
                }
            }
        }
    }
#pragma unroll
    for (int i = 0; i < 4; ++i) h0[px][j * 4 + i] = fmaxf(acc0[i], 0.f);

    // ---------------- special + g1 partials (global) ----------------
    {
        const int o = tid & 15, p = tid >> 4;
        float s = 0.f;
        for (int c = p * 32; c < p * 32 + 32; ++c)
            s = fmaf(xb[c], sp_w[(size_t)c * 16 + o], s);
        part[p][o] = s;
    }
    {
        const int o = tid & 63, p = tid >> 6;
        const float* gx = xb + 65 * 512 + p * 1792;
        float s = 0.f;
        for (int gi = 0; gi < 1792; ++gi)
            s = fmaf(gx[gi], g1w[(size_t)(p * 1792 + gi) * 64 + o], s);
        gpart[p][o] = s;
    }
    __syncthreads();

    if (tid < 16) {
        float s = sp_b[tid];
#pragma unroll
        for (int p = 0; p < 16; ++p) s += part[p][tid];
        comb[tid] = fmaxf(s, 0.f);
    }

    // conv1
    {
        float acc[8];
#pragma unroll
        for (int i = 0; i < 8; ++i) acc[i] = c1b[j * 8 + i];
        for (int ky = 0; ky < 3; ++ky) {
            const int yy = py + ky - 1;
            if (yy < 0 || yy > 7) continue;
            for (int kx = 0; kx < 3; ++kx) {
                const int xx2 = pxx + kx - 1;
                if (xx2 < 0 || xx2 > 7) continue;
                const float* hr = &h0[yy * 8 + xx2][0];
                const float* wr = c1w + (size_t)(ky * 3 + kx) * 16 * 32 + j * 8;
#pragma unroll
                for (int c = 0; c < 16; ++c) {
                    const float hv = hr[c];
#pragma unroll
                    for (int i = 0; i < 8; ++i)
                        acc[i] = fmaf(hv, wr[c * 32 + i], acc[i]);
                }
            }
        }
#pragma unroll
        for (int i = 0; i < 8; ++i) out2[px][j * 8 + i] = fmaxf(acc[i], 0.f);
    }
    __syncthreads();

    if (tid < 64) {
        float s = g1b[tid];
#pragma unroll
        for (int p = 0; p < 4; ++p) s += gpart[p][tid];
        gpart[0][tid] = fmaxf(s, 0.f);
    }
    {
        const int co = tid & 31, ch = tid >> 5;
        float s = 0.f;
#pragma unroll
        for (int p = ch * 8; p < ch * 8 + 8; ++p) s += out2[p][co];
        red[ch][co] = s;
    }
    __syncthreads();

    if (tid < 32) {
        float t = 0.f;
#pragma unroll
        for (int c2 = 0; c2 < 8; ++c2) t += red[c2][tid];
        comb[16 + tid] = t * (1.f / 64.f);
    }
    if (tid >= 64 && tid < 96) {
        const int o = tid - 64;
        float s = g2b[o];
#pragma unroll
        for (int c = 0; c < 64; ++c)
            s = fmaf(gpart[0][c], g2w[c * 32 + o], s);
        comb[48 + o] = fmaxf(s, 0.f);
    }
    __syncthreads();

    if (tid < 128) {
        float s = sumb[tid];
#pragma unroll
        for (int c = 0; c < 80; ++c)
            s = fmaf(comb[c], sumw[(size_t)c * 128 + tid], s);
        psS[tid] = silu_f(s);
    }
    __syncthreads();

#pragma unroll
    for (int r = 0; r < 4; ++r) {
        const int o = tid + 256 * r;          // h*128 + i
        const int h = o >> 7, i = o & 127;
        float s = headb[o];
        const float* wr = headw + (size_t)h * 128 * 128 + i;
        float s0 = 0.f, s1 = 0.f, s2 = 0.f, s3 = 0.f;
#pragma unroll
        for (int c = 0; c < 128; c += 4) {
            s0 = fmaf(psS[c + 0], wr[(size_t)(c + 0) * 128], s0);
            s1 = fmaf(psS[c + 1], wr[(size_t)(c + 1) * 128], s1);
            s2 = fmaf(psS[c + 2], wr[(size_t)(c + 2) * 128], s2);
            s3 = fmaf(psS[c + 3], wr[(size_t)(c + 3) * 128], s3);
        }
        s += (s0 + s1) + (s2 + s3);
        hsF[(size_t)b * 1024 + o] = silu_f(s);
    }
}

// ---------------------------------------------------------------------------
// lgemm: C[4096,6241](bf16) = A[4096,128](f32) @ sproj[128,6241]. Tiled 64x64.
// ---------------------------------------------------------------------------
__global__ __launch_bounds__(256) void lgemm_k(
    const float* __restrict__ A, const float* __restrict__ W,
    __hip_bfloat16* __restrict__ C)
{
    __shared__ __attribute__((aligned(16))) float As[16][64];
    __shared__ __attribute__((aligned(16))) float Bs[16][64];

    const int tid = threadIdx.x;
    const int tx = tid & 15, ty = tid >> 4;
    const int row0 = blockIdx.y * 64, col0 = blockIdx.x * 64;
    const int lr = tid >> 2, lk = (tid & 3) * 4;
    const int bkk = tid >> 4, bc = (tid & 15) * 4;

    float acc[4][4];
#pragma unroll
    for (int i = 0; i < 4; ++i)
#pragma unroll
        for (int j = 0; j < 4; ++j) acc[i][j] = 0.f;

    for (int k0 = 0; k0 < 128; k0 += 16) {
        float4 av = *(const float4*)(A + (size_t)(row0 + lr) * 128 + k0 + lk);
        float4 bv;
        const float* wp = W + (size_t)(k0 + bkk) * 6241 + col0 + bc;
        const int cb = col0 + bc;
        bv.x = (cb + 0 < 6241) ? wp[0] : 0.f;
        bv.y = (cb + 1 < 6241) ? wp[1] : 0.f;
        bv.z = (cb + 2 < 6241) ? wp[2] : 0.f;
        bv.w = (cb + 3 < 6241) ? wp[3] : 0.f;

        __syncthreads();
        As[lk + 0][lr] = av.x; As[lk + 1][lr] = av.y;
        As[lk + 2][lr] = av.z; As[lk + 3][lr] = av.w;
        *(float4*)&Bs[bkk][bc] = bv;
        __syncthreads();

#pragma unroll
        for (int kk = 0; kk < 16; ++kk) {
            float4 a4 = *(const float4*)&As[kk][ty * 4];
            float4 b4 = *(const float4*)&Bs[kk][tx * 4];
            float a[4] = {a4.x, a4.y, a4.z, a4.w};
            float bb[4] = {b4.x, b4.y, b4.z, b4.w};
#pragma unroll
            for (int i = 0; i < 4; ++i)
#pragma unroll
                for (int j = 0; j < 4; ++j)
                    acc[i][j] = fmaf(a[i], bb[j], acc[i][j]);
        }
    }

#pragma unroll
    for (int i = 0; i < 4; ++i) {
        const int r = row0 + ty * 4 + i;
#pragma unroll
        for (int j = 0; j < 4; ++j) {
            const int c = col0 + tx * 4 + j;
            if (c < 6241)
                C[(size_t)r * 6241 + c] = __float2bfloat16(acc[i][j]);
        }
    }
}

// ---------------------------------------------------------------------------
// attn_half_k v5: one block per (b,h), 512 threads.
// XCD-locality: bl = bh & 511, h = bh >> 9 -> all 8 head-blocks of a batch
// share bh%8 (512%8==0) -> same XCD L2 -> x fetched once per XCD.
// Merged q/kv staging: one barrier pair per K-chunk.
// ---------------------------------------------------------------------------
#define QS_OFF  0u
#define KS_OFF  21760u
#define SC_OFF  43520u
#define XHq 0u
#define XLq 3200u
#define XHk 6400u
#define XLk 9600u

__global__ __launch_bounds__(512, 4) void attn_half_k(
    const float* __restrict__ xq, const float* __restrict__ xkv,
    const unsigned short* __restrict__ wsp,
    const __hip_bfloat16* __restrict__ lgB,
    __hip_bfloat16* __restrict__ outB, int b0)
{
    const int bh = blockIdx.x;
    const int bl = bh & 511, h = bh >> 9;      // XCD-locality swizzle
    const int b = b0 + bl;
    const int tid = threadIdx.x;
    const int lane = tid & 63, w = tid >> 6;

    __shared__ __attribute__((aligned(16))) unsigned char Lds[68800];
    unsigned short* L16 = (unsigned short*)Lds;
    float* qSf = (float*)(Lds + QS_OFF);
    float* kSf = (float*)(Lds + KS_OFF);
    float* scLg = (float*)(Lds + SC_OFF);
    float* vSTf = (float*)(Lds + QS_OFF);   // after phase3

    const float* xqb = xq + (size_t)b * LDX;
    const float* xkb = xkv + (size_t)b * LDX;

    const int Lr = lane & 15, Lg = lane >> 4;
    const int ntw = w & 3;
    const int mtw = w >> 2;
    const int nTiles = (w < 4) ? 3 : 2;
    const int cB = ntw * 16 + Lr;              // local col 0..63
    const size_t wCol = (size_t)(h * 64 + cB) * 64 + Lg * 8;

    f32x4 accQ[3], accK[3], accV[3];
#pragma unroll
    for (int i = 0; i < 3; ++i) {
        accQ[i] = (f32x4){0.f, 0.f, 0.f, 0.f};
        accK[i] = (f32x4){0.f, 0.f, 0.f, 0.f};
        accV[i] = (f32x4){0.f, 0.f, 0.f, 0.f};
    }

    for (int ch = 0; ch < 16; ++ch) {
        const int k0 = ch * 32;
        const size_t wOff = (size_t)ch * 32768 + wCol;
        short8v bhq = *(const short8v*)&wsp[wOff];
        short8v blq = *(const short8v*)&wsp[wOff + 32];
        short8v bhk = *(const short8v*)&wsp[524288 + wOff];
        short8v blk = *(const short8v*)&wsp[524288 + wOff + 32];
        short8v bhv = *(const short8v*)&wsp[1048576 + wOff];
        short8v blv = *(const short8v*)&wsp[1048576 + wOff + 32];

        __syncthreads();
        for (int i = tid; i < 1280; i += 512) {
            const int s = (i >= 640);
            const int jj = i - s * 640;
            const int r = jj >> 3, k4 = (jj & 7) << 2;
            const float* src = s ? xkb : xqb;
            float4 xv = {0.f, 0.f, 0.f, 0.f};
            if (r < 79) xv = *(const float4*)&src[(size_t)r * 512 + k0 + k4];
            unsigned short hh[4], ll[4];
            bsplit(xv.x, hh[0], ll[0]); bsplit(xv.y, hh[1], ll[1]);
            bsplit(xv.z, hh[2], ll[2]); bsplit(xv.w, hh[3], ll[3]);
            const unsigned bh_ = s ? XHk : XHq;
            const unsigned bl_ = s ? XLk : XLq;
            *(short4v*)&L16[bh_ + r * 40 + k4] =
                (short4v){(short)hh[0], (short)hh[1], (short)hh[2], (short)hh[3]};
            *(short4v*)&L16[bl_ + r * 40 + k4] =
                (short4v){(short)ll[0], (short)ll[1], (short)ll[2], (short)ll[3]};
        }
        __syncthreads();

#pragma unroll
        for (int i = 0; i < 3; ++i) {
            if (i < nTiles) {
                const int ar = (mtw + 2 * i) * 16 + Lr;
                short8v aqh = *(const short8v*)&L16[XHq + ar * 40 + Lg * 8];
                short8v aql = *(const short8v*)&L16[XLq + ar * 40 + Lg * 8];
                accQ[i] = __builtin_amdgcn_mfma_f32_16x16x32_bf16(
                    aqh, bhq, accQ[i], 0, 0, 0);
                accQ[i] = __builtin_amdgcn_mfma_f32_16x16x32_bf16(
                    aqh, blq, accQ[i], 0, 0, 0);
                accQ[i] = __builtin_amdgcn_mfma_f32_16x16x32_bf16(
                    aql, bhq, accQ[i], 0, 0, 0);
                short8v akh = *(const short8v*)&L16[XHk + ar * 40 + Lg * 8];
                short8v akl = *(const short8v*)&L16[XLk + ar * 40 + Lg * 8];
                accK[i] = __builtin_amdgcn_mfma_f32_16x16x32_bf16(
                    akh, bhk, accK[i], 0, 0, 0);
                accK[i] = __builtin_amdgcn_mfma_f32_16x16x32_bf16(
                    akh, blk, accK[i], 0, 0, 0);
                accK[i] = __builtin_amdgcn_mfma_f32_16x16x32_bf16(
                    akl, bhk, accK[i], 0, 0, 0);
                accV[i] = __builtin_amdgcn_mfma_f32_16x16x32_bf16(
                    akh, bhv, accV[i], 0, 0, 0);
                accV[i] = __builtin_amdgcn_mfma_f32_16x16x32_bf16(
                    akh, blv, accV[i], 0, 0, 0);
                accV[i] = __builtin_amdgcn_mfma_f32_16x16x32_bf16(
                    akl, bhv, accV[i], 0, 0, 0);
            }
        }
    }
    __syncthreads();   // staging dead; write q,k into same region

    // C layout: row = Lg*4 + reg, col = Lr (validated R7)
#pragma unroll
    for (int i = 0; i < 3; ++i) {
        if (i < nTiles) {
            const int rb = (mtw + 2 * i) * 16 + Lg * 4;
            const int cc = ntw * 16 + Lr;
#pragma unroll
            for (int r = 0; r < 4; ++r) {
                const int row = rb + r;
                if (row < 79) {
                    qSf[row * 68 + cc] = accQ[i][r];
                    kSf[row * 68 + cc] = accK[i][r];
                }
            }
        }
    }
    __syncthreads();

    // ---------------- phase 3: scores + precomputed logits ----------------
    const __hip_bfloat16* lgp = lgB + (size_t)(bl * 8 + h) * 6241;
    for (int idx = tid; idx < 6241; idx += 512) {
        const int t = idx / 79, T = idx - t * 79;
        float qx = 0.f, qy = 0.f, qz = 0.f, qw2 = 0.f;
#pragma unroll
        for (int d4 = 0; d4 < 64; d4 += 4) {
            const float4 qv = *(const float4*)&qSf[t * 68 + d4];
            const float4 kv = *(const float4*)&kSf[T * 68 + d4];
            qx = fmaf(qv.x, kv.x, qx);
            qy = fmaf(qv.y, kv.y, qy);
            qz = fmaf(qv.z, kv.z, qz);
            qw2 = fmaf(qv.w, kv.w, qw2);
        }
        const float qk = (qx + qy) + (qz + qw2);
        scLg[t * 80 + T] = qk * 0.125f + __bfloat162float(lgp[idx]);
    }
    __syncthreads();   // qS reads done -> region0 free for vST

#pragma unroll
    for (int i = 0; i < 3; ++i) {
        if (i < nTiles) {
            const int rb = (mtw + 2 * i) * 16 + Lg * 4;
            const int cc = ntw * 16 + Lr;
#pragma unroll
            for (int r = 0; r < 4; ++r) {
                const int row = rb + r;      // T index
                if (row < 79) vSTf[cc * 84 + row] = accV[i][r];
            }
        }
    }

    for (int t = w; t < 79; t += 8) {
        const float v1 = scLg[t * 80 + lane];
        const float v2 = (lane < 15) ? scLg[t * 80 + lane + 64] : -3.0e38f;
        float m = fmaxf(v1, v2);
#pragma unroll
        for (int off = 32; off; off >>= 1)
            m = fmaxf(m, __shfl_xor(m, off));
        float e1 = __expf(v1 - m);
        float e2 = (lane < 15) ? __expf(v2 - m) : 0.f;
        float z = e1 + e2;
#pragma unroll
        for (int off = 32; off; off >>= 1)
            z += __shfl_xor(z, off);
        const float rz = 1.f / z;
        scLg[t * 80 + lane] = e1 * rz;
        if (lane < 15) scLg[t * 80 + lane + 64] = e2 * rz;
    }
    __syncthreads();

    // ---------------- phase 5: PV -> AO_BF16 ----------------
#pragma unroll
    for (int k = 0; k < 10; ++k) {
        const int t = w + 8 * k;
        if (t < 79) {
            float ox = 0.f, oy = 0.f, oz = 0.f, ow = 0.f;
#pragma unroll
            for (int T4 = 0; T4 < 76; T4 += 4) {
                const float4 p = *(const float4*)&scLg[t * 80 + T4];
                const float4 vv = *(const float4*)&vSTf[lane * 84 + T4];
                ox = fmaf(p.x, vv.x, ox);
                oy = fmaf(p.y, vv.y, oy);
                oz = fmaf(p.z, vv.z, oz);
                ow = fmaf(p.w, vv.w, ow);
            }
            float o = (ox + oy) + (oz + ow);
            o = fmaf(scLg[t * 80 + 76], vSTf[lane * 84 + 76], o);
            o = fmaf(scLg[t * 80 + 77], vSTf[lane * 84 + 77], o);
            o = fmaf(scLg[t * 80 + 78], vSTf[lane * 84 + 78], o);
            outB[((size_t)b * 79 + t) * 512 + h * 64 + lane] = __float2bfloat16(o);
        }
    }
}

// ---------------------------------------------------------------------------
// gemm_out_mfma_k: C[r,:] = A_bf16[r,:] @ wo, rows r in [M0,M1).
// Block = 128 rows x 32 cols, 4 waves. wo B-frags loaded per-lane from GLOBAL
// (L2-hot, 1 MB) + in-register bsplit -> LDS = As only (10 KB, high occ).
// Flat swizzled grid: nryP (mult of 8) row-blocks per column-slice -> all
// 16 column-blocks of a row-group land on XCD ry%8 (A-read locality).
// Writes only in epilogue (in-place ladder safety).
// ---------------------------------------------------------------------------
__device__ __forceinline__ int swzA(int r, int g) {
    return g ^ (r & 3) ^ ((r >> 4) & 3);
}

__global__ __launch_bounds__(256) void gemm_out_mfma_k(
    const unsigned short* __restrict__ A, const float* __restrict__ wo,
    float* __restrict__ C, int M0, int M1, int nryP)
{
    __shared__ __attribute__((aligned(16))) unsigned short As[128 * 40];

    const int nry = (M1 - M0 + 127) >> 7;
    const int cx = blockIdx.x / nryP, ry = blockIdx.x % nryP;
    if (ry >= nry) return;

    const int tid = threadIdx.x;
    const int c0 = cx * 32;
    const int row0 = M0 + ry * 128;
    const int lane = tid & 63, w = tid >> 6;
    const int Lr = lane & 15, Lg = lane >> 4;
    const int nt = w >> 1, mg = w & 1;
    const int cB = nt * 16 + Lr;

    f32x4 acc[4];
#pragma unroll
    for (int i = 0; i < 4; ++i) acc[i] = (f32x4){0.f, 0.f, 0.f, 0.f};

    for (int ch = 0; ch < 16; ++ch) {
        const int k0 = ch * 32;
        // wo B-fragment: 8 strided global floats + bsplit (L2-hot)
        const float* wop = wo + (size_t)(k0 + Lg * 8) * 512 + c0 + cB;
        unsigned short bhh[8], bll[8];
#pragma unroll
        for (int e = 0; e < 8; ++e)
            bsplit(wop[(size_t)e * 512], bhh[e], bll[e]);
        short8v bh = (short8v){(short)bhh[0], (short)bhh[1], (short)bhh[2],
                               (short)bhh[3], (short)bhh[4], (short)bhh[5],
                               (short)bhh[6], (short)bhh[7]};
        short8v bl = (short8v){(short)bll[0], (short)bll[1], (short)bll[2],
                               (short)bll[3], (short)bll[4], (short)bll[5],
                               (short)bll[6], (short)bll[7]};

        __syncthreads();
        for (int i = tid; i < 512; i += 256) {
            const int r = i >> 2, g = i & 3;
            int ar = row0 + r; if (ar > M1 - 1) ar = M1 - 1;
            *(short8v*)&As[r * 40 + swzA(r, g) * 8] =
                *(const short8v*)&A[(size_t)ar * 512 + k0 + g * 8];
        }
        __syncthreads();
#pragma unroll
        for (int mt = 0; mt < 4; ++mt) {
            const int ar = mg * 64 + mt * 16 + Lr;
            short8v a = *(const short8v*)&As[ar * 40 + swzA(ar, Lg) * 8];
            acc[mt] = __builtin_amdgcn_mfma_f32_16x16x32_bf16(a, bh, acc[mt], 0, 0, 0);
            acc[mt] = __builtin_amdgcn_mfma_f32_16x16x32_bf16(a, bl, acc[mt], 0, 0, 0);
        }
    }

    // epilogue (all reads done)
#pragma unroll
    for (int mt = 0; mt < 4; ++mt) {
        const int rb = row0 + mg * 64 + mt * 16 + Lg * 4;
#pragma unroll
        for (int r = 0; r < 4; ++r) {
            const int row = rb + r;
            if (row < M1)
                C[(size_t)row * 512 + c0 + nt * 16 + Lr] = acc[mt][r];
        }
    }
}

// ---------------------------------------------------------------------------
extern "C" void kernel_launch(void* const* d_in, const int* in_sizes, int n_in,
                              void* d_out, int out_size, void* d_ws, size_t ws_size,
                              hipStream_t stream) {
    const float* xq    = (const float*)d_in[0];
    const float* xkv   = (const float*)d_in[1];
    const float* wq    = (const float*)d_in[2];
    const float* wk    = (const float*)d_in[3];
    const float* wv    = (const float*)d_in[4];
    const float* wo    = (const float*)d_in[5];
    const float* sp_w  = (const float*)d_in[6];
    const float* sp_b  = (const float*)d_in[7];
    const float* c0w   = (const float*)d_in[8];
    const float* c0b   = (const float*)d_in[9];
    const float* c1w   = (const float*)d_in[10];
    const float* c1b   = (const float*)d_in[11];
    const float* g1w   = (const float*)d_in[12];
    const float* g1b   = (const float*)d_in[13];
    const float* g2w   = (const float*)d_in[14];
    const float* g2b   = (const float*)d_in[15];
    const float* sumw  = (const float*)d_in[16];
    const float* sumb  = (const float*)d_in[17];
    const float* headw = (const float*)d_in[18];
    const float* headb = (const float*)d_in[19];
    const float* sproj = (const float*)d_in[20];
    float* out = (float*)d_out;

    // d_ws unusable in this harness (R1-R3 faulted on first touch; R4+ pass
    // with zero workspace). All intermediates live inside d_out.
    (void)d_ws; (void)ws_size; (void)in_sizes; (void)n_in; (void)out_size;

    __hip_bfloat16* lgB  = (__hip_bfloat16*)out;
    float* hsF           = out + HS_OFF;
    unsigned short* wsp  = (unsigned short*)(out + WSP_OFF);
    __hip_bfloat16* outB = (__hip_bfloat16*)(out + AO_OFF);

    presplit_k<<<3072, 256, 0, stream>>>(wq, wk, wv, wsp);
    smolgen_k<<<B_, 256, 0, stream>>>(xq, sp_w, sp_b, c0w, c0b, c1w, c1b,
                                      g1w, g1b, g2w, g2b, sumw, sumb,
                                      headw, headb, hsF);

    for (int half = 0; half < 2; ++half) {
        const float* Ahs = hsF + (size_t)half * 4096 * 128;
        lgemm_k<<<dim3(98, 64), 256, 0, stream>>>(Ahs, sproj, lgB);
        attn_half_k<<<4096, 512, 0, stream>>>(xq, xkv, wsp, lgB, outB,
                                              half * 512);
    }

    // In-place output projection, ascending doubling ladder (R8-validated).
    auto pass = [&](int lo, int hi) {
        const int nry = (hi - lo + 127) / 128;
        const int nryP = (nry + 7) & ~7;
        gemm_out_mfma_k<<<dim3(16 * nryP), 256, 0, stream>>>(
            (const unsigned short*)outB, wo, out, lo, hi, nryP);
    };
    pass(0, 40448);
    int lo = 40448;
    while (lo < NROW) {
        int hi = (NROW + lo) / 2;
        if (hi > 80768) hi = (lo < 80768) ? 80768 : NROW;
        pass(lo, hi);
        lo = hi;
    }
}

// Round 10
// 2906.109 us; speedup vs baseline: 13.7640x; 1.1967x over previous
//
#include <hip/hip_runtime.h>
#include <hip/hip_bf16.h>

#define B_   1024
#define S_   79
#define E_   512
#define H_   8
#define D_   64
#define LDX  (S_*E_)      // 40448
#define NROW 80896        // B_*S_

// d_out float layout (total 41,418,752 floats):
//   [0        : 12781568)  LG_BF16 : half-batch logits, 4096x6241 bf16
//   [12781568 : 13830144)  HS_F32  : smolgen hs, 8192x128 fp32
//   [13830144 : 14616576)  WSP     : wq/wk/wv bf16 hi/lo splits (ushorts)
//   [14616576 : 14649344)  BS_F32  : conv board-sum, 1024x32 fp32
//   [20709376 : 41418752)  AO_BF16 : attn output, 80896x512 bf16 (top half)
// gemm_out overwrites everything with fp32 output via ascending ladder.
#define HS_OFF  12781568u
#define WSP_OFF 13830144u
#define BS_OFF  14616576u
#define AO_OFF  20709376u

typedef __attribute__((ext_vector_type(8))) short short8v;   // 8 bf16
typedef __attribute__((ext_vector_type(4))) short short4v;
typedef __attribute__((ext_vector_type(4))) float f32x4;

__device__ __forceinline__ float silu_f(float s) {
    return s / (1.f + __expf(-s));
}

// RNE fp32 -> bf16 split: x ~= hi + lo (both bf16).
__device__ __forceinline__ void bsplit(float x, unsigned short& h,
                                       unsigned short& l) {
    unsigned u = __float_as_uint(x);
    unsigned hr = (u + 0x7fffu + ((u >> 16) & 1u)) >> 16;
    h = (unsigned short)hr;
    float r = x - __uint_as_float(hr << 16);
    unsigned u2 = __float_as_uint(r);
    l = (unsigned short)((u2 + 0x7fffu + ((u2 >> 16) & 1u)) >> 16);
}

// ---------------------------------------------------------------------------
// presplit_k: wq/wk/wv -> bf16 hi/lo in B-fragment layout (R8-validated).
// ---------------------------------------------------------------------------
__global__ __launch_bounds__(256) void presplit_k(
    const float* __restrict__ wq, const float* __restrict__ wk,
    const float* __restrict__ wv, unsigned short* __restrict__ wsp)
{
    const int idx = blockIdx.x * 256 + threadIdx.x;   // < 786432
    const int m = idx >> 18;
    const int r = idx & 262143;
    const int k = r >> 9, c = r & 511;
    const float* w = (m == 0) ? wq : (m == 1) ? wk : wv;
    unsigned short hh, ll;
    bsplit(w[(size_t)k * 512 + c], hh, ll);
    const size_t base = (size_t)m * 524288 + (size_t)(k >> 5) * 32768
                      + (size_t)c * 64 + (k & 31);
    wsp[base]      = hh;
    wsp[base + 32] = ll;
}

// ---------------------------------------------------------------------------
// conv01_k: conv0 + conv1 + mean, one block per batch, 31 KB LDS
// (4 blocks/CU co-resident -> 16 waves/CU). x and c0w staged per 32-wide
// k-chunk; conv1 buffers overlay dead conv0 staging. Writes bsum [1024][32].
// ---------------------------------------------------------------------------
__global__ __launch_bounds__(256) void conv01_k(
    const float* __restrict__ xq,
    const float* __restrict__ c0w, const float* __restrict__ c0b,
    const float* __restrict__ c1w, const float* __restrict__ c1b,
    float* __restrict__ bsum)
{
    const int b = blockIdx.x, tid = threadIdx.x;
    __shared__ __attribute__((aligned(16))) float LB[6720];
    __shared__ __attribute__((aligned(16))) float h0[64][16];
    float (*xS)[33]      = (float (*)[33])LB;            // [64][33] conv0
    float (*wS)[32][16]  = (float (*)[32][16])(LB + 2112); // [9][32][16]
    float (*out2)[32]    = (float (*)[32])LB;            // [64][32] conv1
    float (*red)[32]     = (float (*)[32])(LB + 2048);   // [8][32]

    const float* xb = xq + (size_t)b * LDX;
    const int px = tid >> 2, j = tid & 3;
    const int py = px >> 3, pxx = px & 7;

    float acc0[4];
#pragma unroll
    for (int i = 0; i < 4; ++i) acc0[i] = c0b[j * 4 + i];

    for (int kc = 0; kc < 512; kc += 32) {
        __syncthreads();
        for (int i = tid; i < 512; i += 256) {           // x: 64 r x 8 f4
            const int r = i >> 3, c4 = (i & 7) << 2;
            *(float4*)&xS[r][c4] =
                *(const float4*)&xb[(size_t)(1 + r) * 512 + kc + c4];
        }
        for (int i = tid; i < 1152; i += 256) {          // w: 9 x 32 x 4 f4
            const int tap = i / 128, rem = i - tap * 128;
            const int c = rem >> 2, co4 = (rem & 3) << 2;
            *(float4*)&wS[tap][c][co4] =
                *(const float4*)&c0w[(size_t)(tap * 512 + kc + c) * 16 + co4];
        }
        __syncthreads();
        for (int ky = 0; ky < 3; ++ky) {
            const int yy = py + ky - 1;
            if (yy < 0 || yy > 7) continue;
            for (int kx = 0; kx < 3; ++kx) {
                const int xx2 = pxx + kx - 1;
                if (xx2 < 0 || xx2 > 7) continue;
                const float* xr = &xS[yy * 8 + xx2][0];
                const float* wr = &wS[ky * 3 + kx][0][j * 4];
#pragma unroll 8
                for (int c = 0; c < 32; ++c) {
                    const float xv = xr[c];
                    const float4 w4 = *(const float4*)&wr[c * 16];
                    acc0[0] = fmaf(xv, w4.x, acc0[0]);
                    acc0[1] = fmaf(xv, w4.y, acc0[1]);
                    acc0[2] = fmaf(xv, w4.z, acc0[2]);
                    acc0[3] = fmaf(xv, w4.w, acc0[3]);
                }
            }
        }
    }
#pragma unroll
    for (int i = 0; i < 4; ++i) h0[px][j * 4 + i] = fmaxf(acc0[i], 0.f);
    __syncthreads();   // h0 visible; xS/wS dead -> out2/red may overlay

    // conv1 (16->32) from LDS h0
    {
        float acc[8];
#pragma unroll
        for (int i = 0; i < 8; ++i) acc[i] = c1b[j * 8 + i];
        for (int ky = 0; ky < 3; ++ky) {
            const int yy = py + ky - 1;
            if (yy < 0 || yy > 7) continue;
            for (int kx = 0; kx < 3; ++kx) {
                const int xx2 = pxx + kx - 1;
                if (xx2 < 0 || xx2 > 7) continue;
                const float* hr = &h0[yy * 8 + xx2][0];
                const float* wr = c1w + (size_t)(ky * 3 + kx) * 16 * 32 + j * 8;
#pragma unroll
                for (int c = 0; c < 16; ++c) {
                    const float hv = hr[c];
#pragma unroll
                    for (int i = 0; i < 8; ++i)
                        acc[i] = fmaf(hv, wr[c * 32 + i], acc[i]);
                }
            }
        }
#pragma unroll
        for (int i = 0; i < 8; ++i) out2[px][j * 8 + i] = fmaxf(acc[i], 0.f);
    }
    __syncthreads();

    {
        const int co = tid & 31, ch = tid >> 5;
        float s = 0.f;
#pragma unroll
        for (int p = ch * 8; p < ch * 8 + 8; ++p) s += out2[p][co];
        red[ch][co] = s;
    }
    __syncthreads();
    if (tid < 32) {
        float t = 0.f;
#pragma unroll
        for (int c2 = 0; c2 < 8; ++c2) t += red[c2][tid];
        bsum[(size_t)b * 32 + tid] = t * (1.f / 64.f);
    }
}

// ---------------------------------------------------------------------------
// smolgen_rest_k: special, g1 (4-chain ILP), g2, ps, hs. ~3 KB LDS.
// ---------------------------------------------------------------------------
__global__ __launch_bounds__(256) void smolgen_rest_k(
    const float* __restrict__ xq,
    const float* __restrict__ sp_w, const float* __restrict__ sp_b,
    const float* __restrict__ g1w, const float* __restrict__ g1b,
    const float* __restrict__ g2w, const float* __restrict__ g2b,
    const float* __restrict__ sumw, const float* __restrict__ sumb,
    const float* __restrict__ headw, const float* __restrict__ headb,
    const float* __restrict__ bsum, float* __restrict__ hsF)
{
    const int b = blockIdx.x, tid = threadIdx.x;
    __shared__ float part[16][16];
    __shared__ float gpart[4][64];
    __shared__ float comb[80];
    __shared__ float psS[128];

    const float* xb = xq + (size_t)b * LDX;

    // special partials
    {
        const int o = tid & 15, p = tid >> 4;
        float s = 0.f;
        for (int c = p * 32; c < p * 32 + 32; ++c)
            s = fmaf(xb[c], sp_w[(size_t)c * 16 + o], s);
        part[p][o] = s;
    }
    // g1 partials, 4 independent chains
    {
        const int o = tid & 63, p = tid >> 6;
        const float* gx = xb + 65 * 512 + p * 1792;
        const float* gw = g1w + (size_t)(p * 1792) * 64 + o;
        float s0 = 0.f, s1 = 0.f, s2 = 0.f, s3 = 0.f;
        for (int gi = 0; gi < 1792; gi += 4) {
            s0 = fmaf(gx[gi + 0], gw[(size_t)(gi + 0) * 64], s0);
            s1 = fmaf(gx[gi + 1], gw[(size_t)(gi + 1) * 64], s1);
            s2 = fmaf(gx[gi + 2], gw[(size_t)(gi + 2) * 64], s2);
            s3 = fmaf(gx[gi + 3], gw[(size_t)(gi + 3) * 64], s3);
        }
        gpart[p][o] = (s0 + s1) + (s2 + s3);
    }
    __syncthreads();

    if (tid < 16) {
        float s = sp_b[tid];
#pragma unroll
        for (int p = 0; p < 16; ++p) s += part[p][tid];
        comb[tid] = fmaxf(s, 0.f);
    }
    if (tid >= 32 && tid < 64)
        comb[16 + (tid - 32)] = bsum[(size_t)b * 32 + (tid - 32)];
    if (tid < 64) {
        float s = g1b[tid];
#pragma unroll
        for (int p = 0; p < 4; ++p) s += gpart[p][tid];
        gpart[0][tid] = fmaxf(s, 0.f);
    }
    __syncthreads();

    if (tid >= 64 && tid < 96) {
        const int o = tid - 64;
        float s = g2b[o];
#pragma unroll
        for (int c = 0; c < 64; ++c)
            s = fmaf(gpart[0][c], g2w[c * 32 + o], s);
        comb[48 + o] = fmaxf(s, 0.f);
    }
    __syncthreads();

    if (tid < 128) {
        float s = sumb[tid];
#pragma unroll
        for (int c = 0; c < 80; ++c)
            s = fmaf(comb[c], sumw[(size_t)c * 128 + tid], s);
        psS[tid] = silu_f(s);
    }
    __syncthreads();

#pragma unroll
    for (int r = 0; r < 4; ++r) {
        const int o = tid + 256 * r;          // h*128 + i
        const int h = o >> 7, i = o & 127;
        float s = headb[o];
        const float* wr = headw + (size_t)h * 128 * 128 + i;
        float s0 = 0.f, s1 = 0.f, s2 = 0.f, s3 = 0.f;
#pragma unroll
        for (int c = 0; c < 128; c += 4) {
            s0 = fmaf(psS[c + 0], wr[(size_t)(c + 0) * 128], s0);
            s1 = fmaf(psS[c + 1], wr[(size_t)(c + 1) * 128], s1);
            s2 = fmaf(psS[c + 2], wr[(size_t)(c + 2) * 128], s2);
            s3 = fmaf(psS[c + 3], wr[(size_t)(c + 3) * 128], s3);
        }
        s += (s0 + s1) + (s2 + s3);
        hsF[(size_t)b * 1024 + o] = silu_f(s);
    }
}

// ---------------------------------------------------------------------------
// lgemm: C[4096,6241](bf16) = A[4096,128](f32) @ sproj[128,6241]. Tiled 64x64.
// ---------------------------------------------------------------------------
__global__ __launch_bounds__(256) void lgemm_k(
    const float* __restrict__ A, const float* __restrict__ W,
    __hip_bfloat16* __restrict__ C)
{
    __shared__ __attribute__((aligned(16))) float As[16][64];
    __shared__ __attribute__((aligned(16))) float Bs[16][64];

    const int tid = threadIdx.x;
    const int tx = tid & 15, ty = tid >> 4;
    const int row0 = blockIdx.y * 64, col0 = blockIdx.x * 64;
    const int lr = tid >> 2, lk = (tid & 3) * 4;
    const int bkk = tid >> 4, bc = (tid & 15) * 4;

    float acc[4][4];
#pragma unroll
    for (int i = 0; i < 4; ++i)
#pragma unroll
        for (int j = 0; j < 4; ++j) acc[i][j] = 0.f;

    for (int k0 = 0; k0 < 128; k0 += 16) {
        float4 av = *(const float4*)(A + (size_t)(row0 + lr) * 128 + k0 + lk);
        float4 bv;
        const float* wp = W + (size_t)(k0 + bkk) * 6241 + col0 + bc;
        const int cb = col0 + bc;
        bv.x = (cb + 0 < 6241) ? wp[0] : 0.f;
        bv.y = (cb + 1 < 6241) ? wp[1] : 0.f;
        bv.z = (cb + 2 < 6241) ? wp[2] : 0.f;
        bv.w = (cb + 3 < 6241) ? wp[3] : 0.f;

        __syncthreads();
        As[lk + 0][lr] = av.x; As[lk + 1][lr] = av.y;
        As[lk + 2][lr] = av.z; As[lk + 3][lr] = av.w;
        *(float4*)&Bs[bkk][bc] = bv;
        __syncthreads();

#pragma unroll
        for (int kk = 0; kk < 16; ++kk) {
            float4 a4 = *(const float4*)&As[kk][ty * 4];
            float4 b4 = *(const float4*)&Bs[kk][tx * 4];
            float a[4] = {a4.x, a4.y, a4.z, a4.w};
            float bb[4] = {b4.x, b4.y, b4.z, b4.w};
#pragma unroll
            for (int i = 0; i < 4; ++i)
#pragma unroll
                for (int j = 0; j < 4; ++j)
                    acc[i][j] = fmaf(a[i], bb[j], acc[i][j]);
        }
    }

#pragma unroll
    for (int i = 0; i < 4; ++i) {
        const int r = row0 + ty * 4 + i;
#pragma unroll
        for (int j = 0; j < 4; ++j) {
            const int c = col0 + tx * 4 + j;
            if (c < 6241)
                C[(size_t)r * 6241 + c] = __float2bfloat16(acc[i][j]);
        }
    }
}

// ---------------------------------------------------------------------------
// attn_half_k v5 (R9-validated): one block per (b,h), 512 threads,
// XCD-locality decode bl = bh & 511, h = bh >> 9.
// ---------------------------------------------------------------------------
#define QS_OFF  0u
#define KS_OFF  21760u
#define SC_OFF  43520u
#define XHq 0u
#define XLq 3200u
#define XHk 6400u
#define XLk 9600u

__global__ __launch_bounds__(512, 4) void attn_half_k(
    const float* __restrict__ xq, const float* __restrict__ xkv,
    const unsigned short* __restrict__ wsp,
    const __hip_bfloat16* __restrict__ lgB,
    __hip_bfloat16* __restrict__ outB, int b0)
{
    const int bh = blockIdx.x;
    const int bl = bh & 511, h = bh >> 9;      // XCD-locality swizzle
    const int b = b0 + bl;
    const int tid = threadIdx.x;
    const int lane = tid & 63, w = tid >> 6;

    __shared__ __attribute__((aligned(16))) unsigned char Lds[68800];
    unsigned short* L16 = (unsigned short*)Lds;
    float* qSf = (float*)(Lds + QS_OFF);
    float* kSf = (float*)(Lds + KS_OFF);
    float* scLg = (float*)(Lds + SC_OFF);
    float* vSTf = (float*)(Lds + QS_OFF);   // after phase3

    const float* xqb = xq + (size_t)b * LDX;
    const float* xkb = xkv + (size_t)b * LDX;

    const int Lr = lane & 15, Lg = lane >> 4;
    const int ntw = w & 3;
    const int mtw = w >> 2;
    const int nTiles = (w < 4) ? 3 : 2;
    const int cB = ntw * 16 + Lr;              // local col 0..63
    const size_t wCol = (size_t)(h * 64 + cB) * 64 + Lg * 8;

    f32x4 accQ[3], accK[3], accV[3];
#pragma unroll
    for (int i = 0; i < 3; ++i) {
        accQ[i] = (f32x4){0.f, 0.f, 0.f, 0.f};
        accK[i] = (f32x4){0.f, 0.f, 0.f, 0.f};
        accV[i] = (f32x4){0.f, 0.f, 0.f, 0.f};
    }

    for (int ch = 0; ch < 16; ++ch) {
        const int k0 = ch * 32;
        const size_t wOff = (size_t)ch * 32768 + wCol;
        short8v bhq = *(const short8v*)&wsp[wOff];
        short8v blq = *(const short8v*)&wsp[wOff + 32];
        short8v bhk = *(const short8v*)&wsp[524288 + wOff];
        short8v blk = *(const short8v*)&wsp[524288 + wOff + 32];
        short8v bhv = *(const short8v*)&wsp[1048576 + wOff];
        short8v blv = *(const short8v*)&wsp[1048576 + wOff + 32];

        __syncthreads();
        for (int i = tid; i < 1280; i += 512) {
            const int s = (i >= 640);
            const int jj = i - s * 640;
            const int r = jj >> 3, k4 = (jj & 7) << 2;
            const float* src = s ? xkb : xqb;
            float4 xv = {0.f, 0.f, 0.f, 0.f};
            if (r < 79) xv = *(const float4*)&src[(size_t)r * 512 + k0 + k4];
            unsigned short hh[4], ll[4];
            bsplit(xv.x, hh[0], ll[0]); bsplit(xv.y, hh[1], ll[1]);
            bsplit(xv.z, hh[2], ll[2]); bsplit(xv.w, hh[3], ll[3]);
            const unsigned bh_ = s ? XHk : XHq;
            const unsigned bl_ = s ? XLk : XLq;
            *(short4v*)&L16[bh_ + r * 40 + k4] =
                (short4v){(short)hh[0], (short)hh[1], (short)hh[2], (short)hh[3]};
            *(short4v*)&L16[bl_ + r * 40 + k4] =
                (short4v){(short)ll[0], (short)ll[1], (short)ll[2], (short)ll[3]};
        }
        __syncthreads();

#pragma unroll
        for (int i = 0; i < 3; ++i) {
            if (i < nTiles) {
                const int ar = (mtw + 2 * i) * 16 + Lr;
                short8v aqh = *(const short8v*)&L16[XHq + ar * 40 + Lg * 8];
                short8v aql = *(const short8v*)&L16[XLq + ar * 40 + Lg * 8];
                accQ[i] = __builtin_amdgcn_mfma_f32_16x16x32_bf16(
                    aqh, bhq, accQ[i], 0, 0, 0);
                accQ[i] = __builtin_amdgcn_mfma_f32_16x16x32_bf16(
                    aqh, blq, accQ[i], 0, 0, 0);
                accQ[i] = __builtin_amdgcn_mfma_f32_16x16x32_bf16(
                    aql, bhq, accQ[i], 0, 0, 0);
                short8v akh = *(const short8v*)&L16[XHk + ar * 40 + Lg * 8];
                short8v akl = *(const short8v*)&L16[XLk + ar * 40 + Lg * 8];
                accK[i] = __builtin_amdgcn_mfma_f32_16x16x32_bf16(
                    akh, bhk, accK[i], 0, 0, 0);
                accK[i] = __builtin_amdgcn_mfma_f32_16x16x32_bf16(
                    akh, blk, accK[i], 0, 0, 0);
                accK[i] = __builtin_amdgcn_mfma_f32_16x16x32_bf16(
                    akl, bhk, accK[i], 0, 0, 0);
                accV[i] = __builtin_amdgcn_mfma_f32_16x16x32_bf16(
                    akh, bhv, accV[i], 0, 0, 0);
                accV[i] = __builtin_amdgcn_mfma_f32_16x16x32_bf16(
                    akh, blv, accV[i], 0, 0, 0);
                accV[i] = __builtin_amdgcn_mfma_f32_16x16x32_bf16(
                    akl, bhv, accV[i], 0, 0, 0);
            }
        }
    }
    __syncthreads();   // staging dead; write q,k into same region

    // C layout: row = Lg*4 + reg, col = Lr (validated R7)
#pragma unroll
    for (int i = 0; i < 3; ++i) {
        if (i < nTiles) {
            const int rb = (mtw + 2 * i) * 16 + Lg * 4;
            const int cc = ntw * 16 + Lr;
#pragma unroll
            for (int r = 0; r < 4; ++r) {
                const int row = rb + r;
                if (row < 79) {
                    qSf[row * 68 + cc] = accQ[i][r];
                    kSf[row * 68 + cc] = accK[i][r];
                }
            }
        }
    }
    __syncthreads();

    // ---------------- phase 3: scores + precomputed logits ----------------
    const __hip_bfloat16* lgp = lgB + (size_t)(bl * 8 + h) * 6241;
    for (int idx = tid; idx < 6241; idx += 512) {
        const int t = idx / 79, T = idx - t * 79;
        float qx = 0.f, qy = 0.f, qz = 0.f, qw2 = 0.f;
#pragma unroll
        for (int d4 = 0; d4 < 64; d4 += 4) {
            const float4 qv = *(const float4*)&qSf[t * 68 + d4];
            const float4 kv = *(const float4*)&kSf[T * 68 + d4];
            qx = fmaf(qv.x, kv.x, qx);
            qy = fmaf(qv.y, kv.y, qy);
            qz = fmaf(qv.z, kv.z, qz);
            qw2 = fmaf(qv.w, kv.w, qw2);
        }
        const float qk = (qx + qy) + (qz + qw2);
        scLg[t * 80 + T] = qk * 0.125f + __bfloat162float(lgp[idx]);
    }
    __syncthreads();   // qS reads done -> region0 free for vST

#pragma unroll
    for (int i = 0; i < 3; ++i) {
        if (i < nTiles) {
            const int rb = (mtw + 2 * i) * 16 + Lg * 4;
            const int cc = ntw * 16 + Lr;
#pragma unroll
            for (int r = 0; r < 4; ++r) {
                const int row = rb + r;      // T index
                if (row < 79) vSTf[cc * 84 + row] = accV[i][r];
            }
        }
    }

    for (int t = w; t < 79; t += 8) {
        const float v1 = scLg[t * 80 + lane];
        const float v2 = (lane < 15) ? scLg[t * 80 + lane + 64] : -3.0e38f;
        float m = fmaxf(v1, v2);
#pragma unroll
        for (int off = 32; off; off >>= 1)
            m = fmaxf(m, __shfl_xor(m, off));
        float e1 = __expf(v1 - m);
        float e2 = (lane < 15) ? __expf(v2 - m) : 0.f;
        float z = e1 + e2;
#pragma unroll
        for (int off = 32; off; off >>= 1)
            z += __shfl_xor(z, off);
        const float rz = 1.f / z;
        scLg[t * 80 + lane] = e1 * rz;
        if (lane < 15) scLg[t * 80 + lane + 64] = e2 * rz;
    }
    __syncthreads();

    // ---------------- phase 5: PV -> AO_BF16 ----------------
#pragma unroll
    for (int k = 0; k < 10; ++k) {
        const int t = w + 8 * k;
        if (t < 79) {
            float ox = 0.f, oy = 0.f, oz = 0.f, ow = 0.f;
#pragma unroll
            for (int T4 = 0; T4 < 76; T4 += 4) {
                const float4 p = *(const float4*)&scLg[t * 80 + T4];
                const float4 vv = *(const float4*)&vSTf[lane * 84 + T4];
                ox = fmaf(p.x, vv.x, ox);
                oy = fmaf(p.y, vv.y, oy);
                oz = fmaf(p.z, vv.z, oz);
                ow = fmaf(p.w, vv.w, ow);
            }
            float o = (ox + oy) + (oz + ow);
            o = fmaf(scLg[t * 80 + 76], vSTf[lane * 84 + 76], o);
            o = fmaf(scLg[t * 80 + 77], vSTf[lane * 84 + 77], o);
            o = fmaf(scLg[t * 80 + 78], vSTf[lane * 84 + 78], o);
            outB[((size_t)b * 79 + t) * 512 + h * 64 + lane] = __float2bfloat16(o);
        }
    }
}

// ---------------------------------------------------------------------------
// gemm_out_mfma_k (R9-validated): C[r,:] = A_bf16[r,:] @ wo, rows [M0,M1).
// ---------------------------------------------------------------------------
__device__ __forceinline__ int swzA(int r, int g) {
    return g ^ (r & 3) ^ ((r >> 4) & 3);
}

__global__ __launch_bounds__(256) void gemm_out_mfma_k(
    const unsigned short* __restrict__ A, const float* __restrict__ wo,
    float* __restrict__ C, int M0, int M1, int nryP)
{
    __shared__ __attribute__((aligned(16))) unsigned short As[128 * 40];

    const int nry = (M1 - M0 + 127) >> 7;
    const int cx = blockIdx.x / nryP, ry = blockIdx.x % nryP;
    if (ry >= nry) return;

    const int tid = threadIdx.x;
    const int c0 = cx * 32;
    const int row0 = M0 + ry * 128;
    const int lane = tid & 63, w = tid >> 6;
    const int Lr = lane & 15, Lg = lane >> 4;
    const int nt = w >> 1, mg = w & 1;
    const int cB = nt * 16 + Lr;

    f32x4 acc[4];
#pragma unroll
    for (int i = 0; i < 4; ++i) acc[i] = (f32x4){0.f, 0.f, 0.f, 0.f};

    for (int ch = 0; ch < 16; ++ch) {
        const int k0 = ch * 32;
        const float* wop = wo + (size_t)(k0 + Lg * 8) * 512 + c0 + cB;
        unsigned short bhh[8], bll[8];
#pragma unroll
        for (int e = 0; e < 8; ++e)
            bsplit(wop[(size_t)e * 512], bhh[e], bll[e]);
        short8v bh = (short8v){(short)bhh[0], (short)bhh[1], (short)bhh[2],
                               (short)bhh[3], (short)bhh[4], (short)bhh[5],
                               (short)bhh[6], (short)bhh[7]};
        short8v bl = (short8v){(short)bll[0], (short)bll[1], (short)bll[2],
                               (short)bll[3], (short)bll[4], (short)bll[5],
                               (short)bll[6], (short)bll[7]};

        __syncthreads();
        for (int i = tid; i < 512; i += 256) {
            const int r = i >> 2, g = i & 3;
            int ar = row0 + r; if (ar > M1 - 1) ar = M1 - 1;
            *(short8v*)&As[r * 40 + swzA(r, g) * 8] =
                *(const short8v*)&A[(size_t)ar * 512 + k0 + g * 8];
        }
        __syncthreads();
#pragma unroll
        for (int mt = 0; mt < 4; ++mt) {
            const int ar = mg * 64 + mt * 16 + Lr;
            short8v a = *(const short8v*)&As[ar * 40 + swzA(ar, Lg) * 8];
            acc[mt] = __builtin_amdgcn_mfma_f32_16x16x32_bf16(a, bh, acc[mt], 0, 0, 0);
            acc[mt] = __builtin_amdgcn_mfma_f32_16x16x32_bf16(a, bl, acc[mt], 0, 0, 0);
        }
    }

    // epilogue (all reads done)
#pragma unroll
    for (int mt = 0; mt < 4; ++mt) {
        const int rb = row0 + mg * 64 + mt * 16 + Lg * 4;
#pragma unroll
        for (int r = 0; r < 4; ++r) {
            const int row = rb + r;
            if (row < M1)
                C[(size_t)row * 512 + c0 + nt * 16 + Lr] = acc[mt][r];
        }
    }
}

// ---------------------------------------------------------------------------
extern "C" void kernel_launch(void* const* d_in, const int* in_sizes, int n_in,
                              void* d_out, int out_size, void* d_ws, size_t ws_size,
                              hipStream_t stream) {
    const float* xq    = (const float*)d_in[0];
    const float* xkv   = (const float*)d_in[1];
    const float* wq    = (const float*)d_in[2];
    const float* wk    = (const float*)d_in[3];
    const float* wv    = (const float*)d_in[4];
    const float* wo    = (const float*)d_in[5];
    const float* sp_w  = (const float*)d_in[6];
    const float* sp_b  = (const float*)d_in[7];
    const float* c0w   = (const float*)d_in[8];
    const float* c0b   = (const float*)d_in[9];
    const float* c1w   = (const float*)d_in[10];
    const float* c1b   = (const float*)d_in[11];
    const float* g1w   = (const float*)d_in[12];
    const float* g1b   = (const float*)d_in[13];
    const float* g2w   = (const float*)d_in[14];
    const float* g2b   = (const float*)d_in[15];
    const float* sumw  = (const float*)d_in[16];
    const float* sumb  = (const float*)d_in[17];
    const float* headw = (const float*)d_in[18];
    const float* headb = (const float*)d_in[19];
    const float* sproj = (const float*)d_in[20];
    float* out = (float*)d_out;

    // d_ws unusable in this harness (R1-R3 faulted on first touch; R4+ pass
    // with zero workspace). All intermediates live inside d_out.
    (void)d_ws; (void)ws_size; (void)in_sizes; (void)n_in; (void)out_size;

    __hip_bfloat16* lgB  = (__hip_bfloat16*)out;
    float* hsF           = out + HS_OFF;
    unsigned short* wsp  = (unsigned short*)(out + WSP_OFF);
    float* bsF           = out + BS_OFF;
    __hip_bfloat16* outB = (__hip_bfloat16*)(out + AO_OFF);

    presplit_k<<<3072, 256, 0, stream>>>(wq, wk, wv, wsp);
    conv01_k<<<B_, 256, 0, stream>>>(xq, c0w, c0b, c1w, c1b, bsF);
    smolgen_rest_k<<<B_, 256, 0, stream>>>(xq, sp_w, sp_b, g1w, g1b,
                                           g2w, g2b, sumw, sumb,
                                           headw, headb, bsF, hsF);

    for (int half = 0; half < 2; ++half) {
        const float* Ahs = hsF + (size_t)half * 4096 * 128;
        lgemm_k<<<dim3(98, 64), 256, 0, stream>>>(Ahs, sproj, lgB);
        attn_half_k<<<4096, 512, 0, stream>>>(xq, xkv, wsp, lgB, outB,
                                              half * 512);
    }

    // In-place output projection, ascending doubling ladder (R8/R9-validated).
    auto pass = [&](int lo, int hi) {
        const int nry = (hi - lo + 127) / 128;
        const int nryP = (nry + 7) & ~7;
        gemm_out_mfma_k<<<dim3(16 * nryP), 256, 0, stream>>>(
            (const unsigned short*)outB, wo, out, lo, hi, nryP);
    };
    pass(0, 40448);
    int lo = 40448;
    while (lo < NROW) {
        int hi = (NROW + lo) / 2;
        if (hi > 80768) hi = (lo < 80768) ? 80768 : NROW;
        pass(lo, hi);
        lo = hi;
    }
}

// Round 11
// 1974.707 us; speedup vs baseline: 20.2560x; 1.4717x over previous
//
#include <hip/hip_runtime.h>
#include <hip/hip_bf16.h>

#define B_   1024
#define S_   79
#define E_   512
#define H_   8
#define D_   64
#define LDX  (S_*E_)      // 40448
#define NROW 80896        // B_*S_

// d_out float layout (total 41,418,752 floats):
//   [0        : 12781568)  LG_BF16 : half-batch logits, 4096x6241 bf16
//   [12781568 : 13830144)  HS_F32  : smolgen hs, 8192x128 fp32
//   [13830144 : 14616576)  WSP     : wq/wk/wv bf16 hi/lo splits (ushorts)
//   [14616576 : 14649344)  BS_F32  : conv board-sum, 1024x32 fp32
//   [20709376 : 41418752)  AO_BF16 : attn output, 80896x512 bf16 (top half)
// gemm_out overwrites everything with fp32 output via ascending ladder.
#define HS_OFF  12781568u
#define WSP_OFF 13830144u
#define BS_OFF  14616576u
#define AO_OFF  20709376u

typedef __attribute__((ext_vector_type(8))) short short8v;   // 8 bf16
typedef __attribute__((ext_vector_type(4))) short short4v;
typedef __attribute__((ext_vector_type(4))) float f32x4;

__device__ __forceinline__ float silu_f(float s) {
    return s / (1.f + __expf(-s));
}

// RNE fp32 -> bf16 split: x ~= hi + lo (both bf16).
__device__ __forceinline__ void bsplit(float x, unsigned short& h,
                                       unsigned short& l) {
    unsigned u = __float_as_uint(x);
    unsigned hr = (u + 0x7fffu + ((u >> 16) & 1u)) >> 16;
    h = (unsigned short)hr;
    float r = x - __uint_as_float(hr << 16);
    unsigned u2 = __float_as_uint(r);
    l = (unsigned short)((u2 + 0x7fffu + ((u2 >> 16) & 1u)) >> 16);
}

// ---------------------------------------------------------------------------
// presplit_k: wq/wk/wv -> bf16 hi/lo in B-fragment layout (R8-validated).
// ---------------------------------------------------------------------------
__global__ __launch_bounds__(256) void presplit_k(
    const float* __restrict__ wq, const float* __restrict__ wk,
    const float* __restrict__ wv, unsigned short* __restrict__ wsp)
{
    const int idx = blockIdx.x * 256 + threadIdx.x;   // < 786432
    const int m = idx >> 18;
    const int r = idx & 262143;
    const int k = r >> 9, c = r & 511;
    const float* w = (m == 0) ? wq : (m == 1) ? wk : wv;
    unsigned short hh, ll;
    bsplit(w[(size_t)k * 512 + c], hh, ll);
    const size_t base = (size_t)m * 524288 + (size_t)(k >> 5) * 32768
                      + (size_t)c * 64 + (k & 31);
    wsp[base]      = hh;
    wsp[base + 32] = ll;
}

// ---------------------------------------------------------------------------
// conv01_k (R10-validated): conv0 + conv1 + mean, 31 KB LDS, 4 blocks/CU.
// ---------------------------------------------------------------------------
__global__ __launch_bounds__(256) void conv01_k(
    const float* __restrict__ xq,
    const float* __restrict__ c0w, const float* __restrict__ c0b,
    const float* __restrict__ c1w, const float* __restrict__ c1b,
    float* __restrict__ bsum)
{
    const int b = blockIdx.x, tid = threadIdx.x;
    __shared__ __attribute__((aligned(16))) float LB[6720];
    __shared__ __attribute__((aligned(16))) float h0[64][16];
    float (*xS)[33]      = (float (*)[33])LB;
    float (*wS)[32][16]  = (float (*)[32][16])(LB + 2112);
    float (*out2)[32]    = (float (*)[32])LB;
    float (*red)[32]     = (float (*)[32])(LB + 2048);

    const float* xb = xq + (size_t)b * LDX;
    const int px = tid >> 2, j = tid & 3;
    const int py = px >> 3, pxx = px & 7;

    float acc0[4];
#pragma unroll
    for (int i = 0; i < 4; ++i) acc0[i] = c0b[j * 4 + i];

    for (int kc = 0; kc < 512; kc += 32) {
        __syncthreads();
        for (int i = tid; i < 512; i += 256) {
            const int r = i >> 3, c4 = (i & 7) << 2;
            *(float4*)&xS[r][c4] =
                *(const float4*)&xb[(size_t)(1 + r) * 512 + kc + c4];
        }
        for (int i = tid; i < 1152; i += 256) {
            const int tap = i / 128, rem = i - tap * 128;
            const int c = rem >> 2, co4 = (rem & 3) << 2;
            *(float4*)&wS[tap][c][co4] =
                *(const float4*)&c0w[(size_t)(tap * 512 + kc + c) * 16 + co4];
        }
        __syncthreads();
        for (int ky = 0; ky < 3; ++ky) {
            const int yy = py + ky - 1;
            if (yy < 0 || yy > 7) continue;
            for (int kx = 0; kx < 3; ++kx) {
                const int xx2 = pxx + kx - 1;
                if (xx2 < 0 || xx2 > 7) continue;
                const float* xr = &xS[yy * 8 + xx2][0];
                const float* wr = &wS[ky * 3 + kx][0][j * 4];
#pragma unroll 8
                for (int c = 0; c < 32; ++c) {
                    const float xv = xr[c];
                    const float4 w4 = *(const float4*)&wr[c * 16];
                    acc0[0] = fmaf(xv, w4.x, acc0[0]);
                    acc0[1] = fmaf(xv, w4.y, acc0[1]);
                    acc0[2] = fmaf(xv, w4.z, acc0[2]);
                    acc0[3] = fmaf(xv, w4.w, acc0[3]);
                }
            }
        }
    }
#pragma unroll
    for (int i = 0; i < 4; ++i) h0[px][j * 4 + i] = fmaxf(acc0[i], 0.f);
    __syncthreads();

    {
        float acc[8];
#pragma unroll
        for (int i = 0; i < 8; ++i) acc[i] = c1b[j * 8 + i];
        for (int ky = 0; ky < 3; ++ky) {
            const int yy = py + ky - 1;
            if (yy < 0 || yy > 7) continue;
            for (int kx = 0; kx < 3; ++kx) {
                const int xx2 = pxx + kx - 1;
                if (xx2 < 0 || xx2 > 7) continue;
                const float* hr = &h0[yy * 8 + xx2][0];
                const float* wr = c1w + (size_t)(ky * 3 + kx) * 16 * 32 + j * 8;
#pragma unroll
                for (int c = 0; c < 16; ++c) {
                    const float hv = hr[c];
#pragma unroll
                    for (int i = 0; i < 8; ++i)
                        acc[i] = fmaf(hv, wr[c * 32 + i], acc[i]);
                }
            }
        }
#pragma unroll
        for (int i = 0; i < 8; ++i) out2[px][j * 8 + i] = fmaxf(acc[i], 0.f);
    }
    __syncthreads();

    {
        const int co = tid & 31, ch = tid >> 5;
        float s = 0.f;
#pragma unroll
        for (int p = ch * 8; p < ch * 8 + 8; ++p) s += out2[p][co];
        red[ch][co] = s;
    }
    __syncthreads();
    if (tid < 32) {
        float t = 0.f;
#pragma unroll
        for (int c2 = 0; c2 < 8; ++c2) t += red[c2][tid];
        bsum[(size_t)b * 32 + tid] = t * (1.f / 64.f);
    }
}

// ---------------------------------------------------------------------------
// smolgen_rest_k (R10-validated): special, g1 (ILP), g2, ps, hs.
// ---------------------------------------------------------------------------
__global__ __launch_bounds__(256) void smolgen_rest_k(
    const float* __restrict__ xq,
    const float* __restrict__ sp_w, const float* __restrict__ sp_b,
    const float* __restrict__ g1w, const float* __restrict__ g1b,
    const float* __restrict__ g2w, const float* __restrict__ g2b,
    const float* __restrict__ sumw, const float* __restrict__ sumb,
    const float* __restrict__ headw, const float* __restrict__ headb,
    const float* __restrict__ bsum, float* __restrict__ hsF)
{
    const int b = blockIdx.x, tid = threadIdx.x;
    __shared__ float part[16][16];
    __shared__ float gpart[4][64];
    __shared__ float comb[80];
    __shared__ float psS[128];

    const float* xb = xq + (size_t)b * LDX;

    {
        const int o = tid & 15, p = tid >> 4;
        float s = 0.f;
        for (int c = p * 32; c < p * 32 + 32; ++c)
            s = fmaf(xb[c], sp_w[(size_t)c * 16 + o], s);
        part[p][o] = s;
    }
    {
        const int o = tid & 63, p = tid >> 6;
        const float* gx = xb + 65 * 512 + p * 1792;
        const float* gw = g1w + (size_t)(p * 1792) * 64 + o;
        float s0 = 0.f, s1 = 0.f, s2 = 0.f, s3 = 0.f;
        for (int gi = 0; gi < 1792; gi += 4) {
            s0 = fmaf(gx[gi + 0], gw[(size_t)(gi + 0) * 64], s0);
            s1 = fmaf(gx[gi + 1], gw[(size_t)(gi + 1) * 64], s1);
            s2 = fmaf(gx[gi + 2], gw[(size_t)(gi + 2) * 64], s2);
            s3 = fmaf(gx[gi + 3], gw[(size_t)(gi + 3) * 64], s3);
        }
        gpart[p][o] = (s0 + s1) + (s2 + s3);
    }
    __syncthreads();

    if (tid < 16) {
        float s = sp_b[tid];
#pragma unroll
        for (int p = 0; p < 16; ++p) s += part[p][tid];
        comb[tid] = fmaxf(s, 0.f);
    }
    if (tid >= 32 && tid < 64)
        comb[16 + (tid - 32)] = bsum[(size_t)b * 32 + (tid - 32)];
    if (tid < 64) {
        float s = g1b[tid];
#pragma unroll
        for (int p = 0; p < 4; ++p) s += gpart[p][tid];
        gpart[0][tid] = fmaxf(s, 0.f);
    }
    __syncthreads();

    if (tid >= 64 && tid < 96) {
        const int o = tid - 64;
        float s = g2b[o];
#pragma unroll
        for (int c = 0; c < 64; ++c)
            s = fmaf(gpart[0][c], g2w[c * 32 + o], s);
        comb[48 + o] = fmaxf(s, 0.f);
    }
    __syncthreads();

    if (tid < 128) {
        float s = sumb[tid];
#pragma unroll
        for (int c = 0; c < 80; ++c)
            s = fmaf(comb[c], sumw[(size_t)c * 128 + tid], s);
        psS[tid] = silu_f(s);
    }
    __syncthreads();

#pragma unroll
    for (int r = 0; r < 4; ++r) {
        const int o = tid + 256 * r;          // h*128 + i
        const int h = o >> 7, i = o & 127;
        float s = headb[o];
        const float* wr = headw + (size_t)h * 128 * 128 + i;
        float s0 = 0.f, s1 = 0.f, s2 = 0.f, s3 = 0.f;
#pragma unroll
        for (int c = 0; c < 128; c += 4) {
            s0 = fmaf(psS[c + 0], wr[(size_t)(c + 0) * 128], s0);
            s1 = fmaf(psS[c + 1], wr[(size_t)(c + 1) * 128], s1);
            s2 = fmaf(psS[c + 2], wr[(size_t)(c + 2) * 128], s2);
            s3 = fmaf(psS[c + 3], wr[(size_t)(c + 3) * 128], s3);
        }
        s += (s0 + s1) + (s2 + s3);
        hsF[(size_t)b * 1024 + o] = silu_f(s);
    }
}

// ---------------------------------------------------------------------------
// lgemm: C[4096,6241](bf16) = A[4096,128](f32) @ sproj[128,6241]. Tiled 64x64.
// ---------------------------------------------------------------------------
__global__ __launch_bounds__(256) void lgemm_k(
    const float* __restrict__ A, const float* __restrict__ W,
    __hip_bfloat16* __restrict__ C)
{
    __shared__ __attribute__((aligned(16))) float As[16][64];
    __shared__ __attribute__((aligned(16))) float Bs[16][64];

    const int tid = threadIdx.x;
    const int tx = tid & 15, ty = tid >> 4;
    const int row0 = blockIdx.y * 64, col0 = blockIdx.x * 64;
    const int lr = tid >> 2, lk = (tid & 3) * 4;
    const int bkk = tid >> 4, bc = (tid & 15) * 4;

    float acc[4][4];
#pragma unroll
    for (int i = 0; i < 4; ++i)
#pragma unroll
        for (int j = 0; j < 4; ++j) acc[i][j] = 0.f;

    for (int k0 = 0; k0 < 128; k0 += 16) {
        float4 av = *(const float4*)(A + (size_t)(row0 + lr) * 128 + k0 + lk);
        float4 bv;
        const float* wp = W + (size_t)(k0 + bkk) * 6241 + col0 + bc;
        const int cb = col0 + bc;
        bv.x = (cb + 0 < 6241) ? wp[0] : 0.f;
        bv.y = (cb + 1 < 6241) ? wp[1] : 0.f;
        bv.z = (cb + 2 < 6241) ? wp[2] : 0.f;
        bv.w = (cb + 3 < 6241) ? wp[3] : 0.f;

        __syncthreads();
        As[lk + 0][lr] = av.x; As[lk + 1][lr] = av.y;
        As[lk + 2][lr] = av.z; As[lk + 3][lr] = av.w;
        *(float4*)&Bs[bkk][bc] = bv;
        __syncthreads();

#pragma unroll
        for (int kk = 0; kk < 16; ++kk) {
            float4 a4 = *(const float4*)&As[kk][ty * 4];
            float4 b4 = *(const float4*)&Bs[kk][tx * 4];
            float a[4] = {a4.x, a4.y, a4.z, a4.w};
            float bb[4] = {b4.x, b4.y, b4.z, b4.w};
#pragma unroll
            for (int i = 0; i < 4; ++i)
#pragma unroll
                for (int j = 0; j < 4; ++j)
                    acc[i][j] = fmaf(a[i], bb[j], acc[i][j]);
        }
    }

#pragma unroll
    for (int i = 0; i < 4; ++i) {
        const int r = row0 + ty * 4 + i;
#pragma unroll
        for (int j = 0; j < 4; ++j) {
            const int c = col0 + tx * 4 + j;
            if (c < 6241)
                C[(size_t)r * 6241 + c] = __float2bfloat16(acc[i][j]);
        }
    }
}

// ---------------------------------------------------------------------------
// attn_half_k v6: one block per (b,h), 512 threads, LDS 72.96 KB (2 blk/CU).
//  P1: QKV split-bf16 MFMA with register-double-buffered x prefetch.
//      Epilogue: Q,K -> bf16 hi/lo LDS (stride 72); V stays in regs.
//  P2: scores via MFMA: A=Q rows, B=K rows (both contiguous-row frags),
//      3-pass hi/lo; +bf16 logits -> scLg (stride 84).
//  P3: softmax; P -> bf16 hi/lo (stride 104, cols 79..95 zeroed).
//  P4: V -> transposed bf16 hi/lo (stride 104, cols 79..95 zeroed);
//      PV via MFMA 3-pass; epilogue -> AO bf16.
// ---------------------------------------------------------------------------
#define XHq 0u
#define XLq 3200u
#define XHk 6400u
#define XLk 9600u

__global__ __launch_bounds__(512, 4) void attn_half_k(
    const float* __restrict__ xq, const float* __restrict__ xkv,
    const unsigned short* __restrict__ wsp,
    const __hip_bfloat16* __restrict__ lgB,
    __hip_bfloat16* __restrict__ outB, int b0)
{
    const int bh = blockIdx.x;
    const int bl = bh & 511, h = bh >> 9;      // XCD-locality swizzle
    const int b = b0 + bl;
    const int tid = threadIdx.x;
    const int lane = tid & 63, w = tid >> 6;

    __shared__ __attribute__((aligned(16))) unsigned char Lds[72960];
    unsigned short* L16 = (unsigned short*)Lds;               // P1 staging
    unsigned short* QH  = (unsigned short*)(Lds);             // [80][72]
    unsigned short* QL  = (unsigned short*)(Lds + 11520);
    unsigned short* KH  = (unsigned short*)(Lds + 23040);
    unsigned short* KL  = (unsigned short*)(Lds + 34560);
    float*          scLg = (float*)(Lds + 46080);             // [80][84]
    unsigned short* PH  = (unsigned short*)(Lds);             // [80][104]
    unsigned short* PL  = (unsigned short*)(Lds + 16640);
    unsigned short* VBH = (unsigned short*)(Lds + 46080);     // [64][104]
    unsigned short* VBL = (unsigned short*)(Lds + 59392);

    const float* xqb = xq + (size_t)b * LDX;
    const float* xkb = xkv + (size_t)b * LDX;

    const int Lr = lane & 15, Lg = lane >> 4;
    const int ntw = w & 3;
    const int mtw = w >> 2;
    const int nTiles = (w < 4) ? 3 : 2;
    const int cB = ntw * 16 + Lr;
    const size_t wCol = (size_t)(h * 64 + cB) * 64 + Lg * 8;

    f32x4 accQ[3], accK[3], accV[3];
#pragma unroll
    for (int i = 0; i < 3; ++i) {
        accQ[i] = (f32x4){0.f, 0.f, 0.f, 0.f};
        accK[i] = (f32x4){0.f, 0.f, 0.f, 0.f};
        accV[i] = (f32x4){0.f, 0.f, 0.f, 0.f};
    }

    auto LD = [&](int ch, float4 (&xb)[3]) {
        const int k0 = ch * 32;
#pragma unroll
        for (int it = 0; it < 3; ++it) {
            const int i = tid + (it << 9);
            if (i < 1280) {
                const int s = (i >= 640);
                const int jj = i - s * 640;
                const int r = jj >> 3, k4 = (jj & 7) << 2;
                const float* src = s ? xkb : xqb;
                xb[it] = (r < 79)
                    ? *(const float4*)&src[(size_t)r * 512 + k0 + k4]
                    : (float4){0.f, 0.f, 0.f, 0.f};
            }
        }
    };
    auto STG = [&](float4 (&xb)[3]) {
#pragma unroll
        for (int it = 0; it < 3; ++it) {
            const int i = tid + (it << 9);
            if (i < 1280) {
                const int s = (i >= 640);
                const int jj = i - s * 640;
                const int r = jj >> 3, k4 = (jj & 7) << 2;
                unsigned short hh[4], ll[4];
                bsplit(xb[it].x, hh[0], ll[0]);
                bsplit(xb[it].y, hh[1], ll[1]);
                bsplit(xb[it].z, hh[2], ll[2]);
                bsplit(xb[it].w, hh[3], ll[3]);
                const unsigned bh_ = s ? XHk : XHq;
                const unsigned bl_ = s ? XLk : XLq;
                *(short4v*)&L16[bh_ + r * 40 + k4] = (short4v){
                    (short)hh[0], (short)hh[1], (short)hh[2], (short)hh[3]};
                *(short4v*)&L16[bl_ + r * 40 + k4] = (short4v){
                    (short)ll[0], (short)ll[1], (short)ll[2], (short)ll[3]};
            }
        }
    };
    auto DO_CHUNK = [&](float4 (&xb)[3], int ch) {
        const size_t wOff = (size_t)ch * 32768 + wCol;
        short8v bhq = *(const short8v*)&wsp[wOff];
        short8v blq = *(const short8v*)&wsp[wOff + 32];
        short8v bhk = *(const short8v*)&wsp[524288 + wOff];
        short8v blk = *(const short8v*)&wsp[524288 + wOff + 32];
        short8v bhv = *(const short8v*)&wsp[1048576 + wOff];
        short8v blv = *(const short8v*)&wsp[1048576 + wOff + 32];
        __syncthreads();     // prev MFMA done reading staging
        STG(xb);
        __syncthreads();
#pragma unroll
        for (int i = 0; i < 3; ++i) {
            if (i < nTiles) {
                const int ar = (mtw + 2 * i) * 16 + Lr;
                short8v aqh = *(const short8v*)&L16[XHq + ar * 40 + Lg * 8];
                short8v aql = *(const short8v*)&L16[XLq + ar * 40 + Lg * 8];
                accQ[i] = __builtin_amdgcn_mfma_f32_16x16x32_bf16(
                    aqh, bhq, accQ[i], 0, 0, 0);
                accQ[i] = __builtin_amdgcn_mfma_f32_16x16x32_bf16(
                    aqh, blq, accQ[i], 0, 0, 0);
                accQ[i] = __builtin_amdgcn_mfma_f32_16x16x32_bf16(
                    aql, bhq, accQ[i], 0, 0, 0);
                short8v akh = *(const short8v*)&L16[XHk + ar * 40 + Lg * 8];
                short8v akl = *(const short8v*)&L16[XLk + ar * 40 + Lg * 8];
                accK[i] = __builtin_amdgcn_mfma_f32_16x16x32_bf16(
                    akh, bhk, accK[i], 0, 0, 0);
                accK[i] = __builtin_amdgcn_mfma_f32_16x16x32_bf16(
                    akh, blk, accK[i], 0, 0, 0);
                accK[i] = __builtin_amdgcn_mfma_f32_16x16x32_bf16(
                    akl, bhk, accK[i], 0, 0, 0);
                accV[i] = __builtin_amdgcn_mfma_f32_16x16x32_bf16(
                    akh, bhv, accV[i], 0, 0, 0);
                accV[i] = __builtin_amdgcn_mfma_f32_16x16x32_bf16(
                    akh, blv, accV[i], 0, 0, 0);
                accV[i] = __builtin_amdgcn_mfma_f32_16x16x32_bf16(
                    akl, bhv, accV[i], 0, 0, 0);
            }
        }
    };

    // ---------------- phase 1: QKV (pipelined) ----------------
    float4 xbufA[3], xbufB[3];
    LD(0, xbufA);
    for (int ch = 0; ch < 16; ch += 2) {
        LD(ch + 1, xbufB);
        DO_CHUNK(xbufA, ch);
        if (ch + 2 < 16) LD(ch + 2, xbufA);
        DO_CHUNK(xbufB, ch + 1);
    }
    __syncthreads();   // staging dead

    // epilogue: Q,K -> bf16 hi/lo (C layout: row = Lg*4+r, col = Lr)
#pragma unroll
    for (int i = 0; i < 3; ++i) {
        if (i < nTiles) {
            const int rb = (mtw + 2 * i) * 16 + Lg * 4;
            const int cc = ntw * 16 + Lr;
#pragma unroll
            for (int r = 0; r < 4; ++r) {
                const int row = rb + r;
                if (row < 79) {
                    unsigned short h_, l_;
                    bsplit(accQ[i][r], h_, l_);
                    QH[row * 72 + cc] = h_; QL[row * 72 + cc] = l_;
                    bsplit(accK[i][r], h_, l_);
                    KH[row * 72 + cc] = h_; KL[row * 72 + cc] = l_;
                }
            }
        }
    }
    __syncthreads();

    // ---------------- phase 2: scores via MFMA ----------------
    const __hip_bfloat16* lgp = lgB + (size_t)(bl * 8 + h) * 6241;
    for (int tt = w; tt < 25; tt += 8) {
        const int mt = tt / 5, nt = tt - mt * 5;
        const int aro = (mt * 16 + Lr) * 72;
        const int bro = (nt * 16 + Lr) * 72;
        f32x4 s = (f32x4){0.f, 0.f, 0.f, 0.f};
#pragma unroll
        for (int c = 0; c < 2; ++c) {
            const int ko = c * 32 + Lg * 8;
            short8v ah = *(const short8v*)&QH[aro + ko];
            short8v al = *(const short8v*)&QL[aro + ko];
            short8v bh2 = *(const short8v*)&KH[bro + ko];
            short8v bl2 = *(const short8v*)&KL[bro + ko];
            s = __builtin_amdgcn_mfma_f32_16x16x32_bf16(ah, bh2, s, 0, 0, 0);
            s = __builtin_amdgcn_mfma_f32_16x16x32_bf16(ah, bl2, s, 0, 0, 0);
            s = __builtin_amdgcn_mfma_f32_16x16x32_bf16(al, bh2, s, 0, 0, 0);
        }
        const int T = nt * 16 + Lr;
        const int t0 = mt * 16 + Lg * 4;
        if (T < 79) {
#pragma unroll
            for (int r = 0; r < 4; ++r) {
                const int t = t0 + r;
                if (t < 79)
                    scLg[t * 84 + T] = s[r] * 0.125f
                                     + __bfloat162float(lgp[t * 79 + T]);
            }
        }
    }
    __syncthreads();

    // ---------------- phase 3: softmax -> P bf16 hi/lo ----------------
    for (int t = w; t < 79; t += 8) {
        const float v1 = scLg[t * 84 + lane];
        const float v2 = (lane < 15) ? scLg[t * 84 + 64 + lane] : -3.0e38f;
        float m = fmaxf(v1, v2);
#pragma unroll
        for (int off = 32; off; off >>= 1)
            m = fmaxf(m, __shfl_xor(m, off));
        float e1 = __expf(v1 - m);
        float e2 = (lane < 15) ? __expf(v2 - m) : 0.f;
        float z = e1 + e2;
#pragma unroll
        for (int off = 32; off; off >>= 1)
            z += __shfl_xor(z, off);
        const float rz = 1.f / z;
        unsigned short h_, l_;
        bsplit(e1 * rz, h_, l_);
        PH[t * 104 + lane] = h_; PL[t * 104 + lane] = l_;
        if (lane < 15) {
            bsplit(e2 * rz, h_, l_);
            PH[t * 104 + 64 + lane] = h_; PL[t * 104 + 64 + lane] = l_;
        }
        if (lane >= 15 && lane < 40) {            // zero cols 79..103
            PH[t * 104 + 64 + lane] = 0; PL[t * 104 + 64 + lane] = 0;
        }
    }
    __syncthreads();   // scLg dead -> VB region usable

    // ---------------- phase 4a: V -> transposed bf16 hi/lo ----------------
#pragma unroll
    for (int i = 0; i < 3; ++i) {
        if (i < nTiles) {
            const int rb = (mtw + 2 * i) * 16 + Lg * 4;
            const int cc = ntw * 16 + Lr;
#pragma unroll
            for (int r = 0; r < 4; ++r) {
                const int row = rb + r;          // T index
                if (row < 79) {
                    unsigned short h_, l_;
                    bsplit(accV[i][r], h_, l_);
                    VBH[cc * 104 + row] = h_; VBL[cc * 104 + row] = l_;
                }
            }
        }
    }
    for (int i = tid; i < 64 * 17; i += 512) {    // zero cols 79..95
        const int d = i / 17, c = 79 + (i - d * 17);
        VBH[d * 104 + c] = 0; VBL[d * 104 + c] = 0;
    }
    __syncthreads();

    // ---------------- phase 4b: PV via MFMA -> AO ----------------
    for (int tt = w; tt < 20; tt += 8) {
        const int mt = tt >> 2, nt = tt & 3;
        const int aro = (mt * 16 + Lr) * 104;
        const int bro = (nt * 16 + Lr) * 104;
        f32x4 o = (f32x4){0.f, 0.f, 0.f, 0.f};
#pragma unroll
        for (int c = 0; c < 3; ++c) {
            const int To = c * 32 + Lg * 8;
            short8v pa = *(const short8v*)&PH[aro + To];
            short8v pb = *(const short8v*)&PL[aro + To];
            short8v vh = *(const short8v*)&VBH[bro + To];
            short8v vl = *(const short8v*)&VBL[bro + To];
            o = __builtin_amdgcn_mfma_f32_16x16x32_bf16(pa, vh, o, 0, 0, 0);
            o = __builtin_amdgcn_mfma_f32_16x16x32_bf16(pa, vl, o, 0, 0, 0);
            o = __builtin_amdgcn_mfma_f32_16x16x32_bf16(pb, vh, o, 0, 0, 0);
        }
        const int t0 = mt * 16 + Lg * 4;
        const int d = nt * 16 + Lr;
#pragma unroll
        for (int r = 0; r < 4; ++r) {
            const int t = t0 + r;
            if (t < 79)
                outB[((size_t)b * 79 + t) * 512 + h * 64 + d] =
                    __float2bfloat16(o[r]);
        }
    }
}

// ---------------------------------------------------------------------------
// gemm_out_mfma_k (R9/R10-validated structure; swizzle dropped — natural
// stride-5 bank groups are conflict-free, identity applied on both sides).
// ---------------------------------------------------------------------------
__global__ __launch_bounds__(256) void gemm_out_mfma_k(
    const unsigned short* __restrict__ A, const float* __restrict__ wo,
    float* __restrict__ C, int M0, int M1, int nryP)
{
    __shared__ __attribute__((aligned(16))) unsigned short As[128 * 40];

    const int nry = (M1 - M0 + 127) >> 7;
    const int cx = blockIdx.x / nryP, ry = blockIdx.x % nryP;
    if (ry >= nry) return;

    const int tid = threadIdx.x;
    const int c0 = cx * 32;
    const int row0 = M0 + ry * 128;
    const int lane = tid & 63, w = tid >> 6;
    const int Lr = lane & 15, Lg = lane >> 4;
    const int nt = w >> 1, mg = w & 1;
    const int cB = nt * 16 + Lr;

    f32x4 acc[4];
#pragma unroll
    for (int i = 0; i < 4; ++i) acc[i] = (f32x4){0.f, 0.f, 0.f, 0.f};

    for (int ch = 0; ch < 16; ++ch) {
        const int k0 = ch * 32;
        const float* wop = wo + (size_t)(k0 + Lg * 8) * 512 + c0 + cB;
        unsigned short bhh[8], bll[8];
#pragma unroll
        for (int e = 0; e < 8; ++e)
            bsplit(wop[(size_t)e * 512], bhh[e], bll[e]);
        short8v bh = (short8v){(short)bhh[0], (short)bhh[1], (short)bhh[2],
                               (short)bhh[3], (short)bhh[4], (short)bhh[5],
                               (short)bhh[6], (short)bhh[7]};
        short8v bl = (short8v){(short)bll[0], (short)bll[1], (short)bll[2],
                               (short)bll[3], (short)bll[4], (short)bll[5],
                               (short)bll[6], (short)bll[7]};

        __syncthreads();
        for (int i = tid; i < 512; i += 256) {
            const int r = i >> 2, g = i & 3;
            int ar = row0 + r; if (ar > M1 - 1) ar = M1 - 1;
            *(short8v*)&As[r * 40 + g * 8] =
                *(const short8v*)&A[(size_t)ar * 512 + k0 + g * 8];
        }
        __syncthreads();
#pragma unroll
        for (int mt = 0; mt < 4; ++mt) {
            const int ar = mg * 64 + mt * 16 + Lr;
            short8v a = *(const short8v*)&As[ar * 40 + Lg * 8];
            acc[mt] = __builtin_amdgcn_mfma_f32_16x16x32_bf16(a, bh, acc[mt], 0, 0, 0);
            acc[mt] = __builtin_amdgcn_mfma_f32_16x16x32_bf16(a, bl, acc[mt], 0, 0, 0);
        }
    }

    // epilogue (all reads done)
#pragma unroll
    for (int mt = 0; mt < 4; ++mt) {
        const int rb = row0 + mg * 64 + mt * 16 + Lg * 4;
#pragma unroll
        for (int r = 0; r < 4; ++r) {
            const int row = rb + r;
            if (row < M1)
                C[(size_t)row * 512 + c0 + nt * 16 + Lr] = acc[mt][r];
        }
    }
}

// ---------------------------------------------------------------------------
extern "C" void kernel_launch(void* const* d_in, const int* in_sizes, int n_in,
                              void* d_out, int out_size, void* d_ws, size_t ws_size,
                              hipStream_t stream) {
    const float* xq    = (const float*)d_in[0];
    const float* xkv   = (const float*)d_in[1];
    const float* wq    = (const float*)d_in[2];
    const float* wk    = (const float*)d_in[3];
    const float* wv    = (const float*)d_in[4];
    const float* wo    = (const float*)d_in[5];
    const float* sp_w  = (const float*)d_in[6];
    const float* sp_b  = (const float*)d_in[7];
    const float* c0w   = (const float*)d_in[8];
    const float* c0b   = (const float*)d_in[9];
    const float* c1w   = (const float*)d_in[10];
    const float* c1b   = (const float*)d_in[11];
    const float* g1w   = (const float*)d_in[12];
    const float* g1b   = (const float*)d_in[13];
    const float* g2w   = (const float*)d_in[14];
    const float* g2b   = (const float*)d_in[15];
    const float* sumw  = (const float*)d_in[16];
    const float* sumb  = (const float*)d_in[17];
    const float* headw = (const float*)d_in[18];
    const float* headb = (const float*)d_in[19];
    const float* sproj = (const float*)d_in[20];
    float* out = (float*)d_out;

    // d_ws unusable in this harness (R1-R3 faulted on first touch; R4+ pass
    // with zero workspace). All intermediates live inside d_out.
    (void)d_ws; (void)ws_size; (void)in_sizes; (void)n_in; (void)out_size;

    __hip_bfloat16* lgB  = (__hip_bfloat16*)out;
    float* hsF           = out + HS_OFF;
    unsigned short* wsp  = (unsigned short*)(out + WSP_OFF);
    float* bsF           = out + BS_OFF;
    __hip_bfloat16* outB = (__hip_bfloat16*)(out + AO_OFF);

    presplit_k<<<3072, 256, 0, stream>>>(wq, wk, wv, wsp);
    conv01_k<<<B_, 256, 0, stream>>>(xq, c0w, c0b, c1w, c1b, bsF);
    smolgen_rest_k<<<B_, 256, 0, stream>>>(xq, sp_w, sp_b, g1w, g1b,
                                           g2w, g2b, sumw, sumb,
                                           headw, headb, bsF, hsF);

    for (int half = 0; half < 2; ++half) {
        const float* Ahs = hsF + (size_t)half * 4096 * 128;
        lgemm_k<<<dim3(98, 64), 256, 0, stream>>>(Ahs, sproj, lgB);
        attn_half_k<<<4096, 512, 0, stream>>>(xq, xkv, wsp, lgB, outB,
                                              half * 512);
    }

    // In-place output projection, ascending doubling ladder (R8+-validated).
    auto pass = [&](int lo, int hi) {
        const int nry = (hi - lo + 127) / 128;
        const int nryP = (nry + 7) & ~7;
        gemm_out_mfma_k<<<dim3(16 * nryP), 256, 0, stream>>>(
            (const unsigned short*)outB, wo, out, lo, hi, nryP);
    };
    pass(0, 40448);
    int lo = 40448;
    while (lo < NROW) {
        int hi = (NROW + lo) / 2;
        if (hi > 80768) hi = (lo < 80768) ? 80768 : NROW;
        pass(lo, hi);
        lo = hi;
    }
}